// Round 3
// baseline (788.267 us; speedup 1.0000x reference)
//
#include <hip/hip_runtime.h>
#include <math.h>

#define NPX 1024  // H*W = 32*32

__device__ __forceinline__ float slog1p(float p) {
  // sign(p) * log1p(|p|)  (sign(0)=0 handled: log1p(0)=0)
  return copysignf(log1pf(fabsf(p)), p);
}

// ---------------------------------------------------------------------------
// K1: grouped 1x1 conv  q = x * q_w   (2,256,32,32) -> (2,512,32,32)
// also emits qT[(bg*1024+p)*64 + d] = q * 0.125 (pre-scaled, d-contiguous)
// grid: 256 blocks = (b*g = 16) x (16 pixel tiles of 64), 256 thr
// ---------------------------------------------------------------------------
__global__ __launch_bounds__(256) void k_qconv(const float* __restrict__ x,
                                               const float* __restrict__ qw,
                                               float* __restrict__ q,
                                               float* __restrict__ qT) {
  const int blk = blockIdx.x;
  const int bg  = blk >> 4;          // 0..15
  const int px0 = (blk & 15) << 6;   // pixel tile base
  const int g   = bg & 7;
  const int b   = bg >> 3;
  const int tid = threadIdx.x;
  __shared__ float xs[32 * 64];      // [c][p]
  __shared__ float wsh[64 * 32];     // [o][c]
  __shared__ float ot[64 * 65];      // transpose staging, padded

  const float* xb = x + ((size_t)(b * 256 + g * 32)) * NPX + px0;
  for (int idx = tid; idx < 32 * 64; idx += 256) {
    int c = idx >> 6, p = idx & 63;
    xs[idx] = xb[(size_t)c * NPX + p];
  }
  const float* wb = qw + g * 64 * 32;
  for (int idx = tid; idx < 64 * 32; idx += 256) wsh[idx] = wb[idx];
  __syncthreads();

  for (int idx = tid; idx < 64 * 64; idx += 256) {
    int o = idx >> 6, p = idx & 63;  // o uniform per wave -> wsh broadcast
    float a0 = 0.f, a1 = 0.f;
#pragma unroll
    for (int c = 0; c < 32; c += 2) {
      a0 = fmaf(wsh[o * 32 + c],     xs[c * 64 + p],       a0);
      a1 = fmaf(wsh[o * 32 + c + 1], xs[(c + 1) * 64 + p], a1);
    }
    float acc = a0 + a1;
    q[((size_t)(bg * 64 + o)) * NPX + px0 + p] = acc;
    ot[o * 65 + p] = acc * 0.125f;   // attention scale DH^-0.5
  }
  __syncthreads();
  float* qTb = qT + ((size_t)bg * NPX + px0) * 64;
  for (int idx = tid; idx < 64 * 64; idx += 256) {
    int p = idx >> 6, o = idx & 63;  // lanes vary o -> coalesced write
    qTb[p * 64 + o] = ot[o * 65 + p];
  }
}

// ---------------------------------------------------------------------------
// K2: offset net: depthwise 6x6 stride4 pad1 conv + bias + exact GELU,
// then 1x1 (64->2), tanh, *4; produce normalized sample grid gkv (16,64,2)
// grid: 16 blocks (one per bg), 256 thr
// ---------------------------------------------------------------------------
__global__ __launch_bounds__(256) void k_offset(const float* __restrict__ q,
                                                const float* __restrict__ w1,
                                                const float* __restrict__ b1,
                                                const float* __restrict__ w2,
                                                float* __restrict__ gkv) {
  const int bg = blockIdx.x;
  const int tid = threadIdx.x;
  __shared__ float ge[64 * 64];   // [c][px] gelu outputs
  __shared__ float w1s[64 * 36];
  __shared__ float b1s[64];
  const float* qb = q + (size_t)bg * 64 * NPX;
  for (int idx = tid; idx < 64 * 36; idx += 256) w1s[idx] = w1[idx];
  if (tid < 64) b1s[tid] = b1[tid];
  __syncthreads();

  for (int idx = tid; idx < 4096; idx += 256) {
    int c = idx >> 6, px = idx & 63;
    int oy = px >> 3, ox = px & 7;
    const float* qc = qb + (size_t)c * NPX;
    float acc = 0.f;
#pragma unroll
    for (int ky = 0; ky < 6; ++ky) {
      int yy = oy * 4 - 1 + ky;
      if (yy < 0 || yy >= 32) continue;
#pragma unroll
      for (int kx = 0; kx < 6; ++kx) {
        int xx = ox * 4 - 1 + kx;
        if (xx < 0 || xx >= 32) continue;
        acc = fmaf(w1s[c * 36 + ky * 6 + kx], qc[yy * 32 + xx], acc);
      }
    }
    acc += b1s[c];
    // exact GELU: x * 0.5 * (1 + erf(x/sqrt(2)))
    ge[c * 64 + px] = 0.5f * acc * (1.f + erff(acc * 0.70710678118654752440f));
  }
  __syncthreads();
  if (tid < 64) {
    int px = tid;
    float s0 = 0.f, s1 = 0.f;
    for (int c = 0; c < 64; ++c) {
      float gv = ge[c * 64 + px];
      s0 = fmaf(w2[c],      gv, s0);   // w2[0][c]
      s1 = fmaf(w2[64 + c], gv, s1);   // w2[1][c]
    }
    float o0 = tanhf(s0) * 4.f;        // offset_scale = downsample = 4
    float o1 = tanhf(s1) * 4.f;
    int oy = px >> 3, ox = px & 7;
    // vgrid = pixel + offset; normalize by (8-1)=7 (faithful to ref)
    gkv[(bg * 64 + px) * 2 + 0] = 2.f * ((float)ox + o0) / 7.f - 1.f;
    gkv[(bg * 64 + px) * 2 + 1] = 2.f * ((float)oy + o1) / 7.f - 1.f;
  }
}

// ---------------------------------------------------------------------------
// K3: bilinear grid_sample (zeros pad, align_corners=False) of x at gkv,
// then grouped 1x1 convs k,v; outputs kh/vh in (bh, j, d) layout (d contig)
// grid: 16 blocks (one per bg), 256 thr
// ---------------------------------------------------------------------------
__global__ __launch_bounds__(256) void k_sample_kv(const float* __restrict__ x,
                                                   const float* __restrict__ kw,
                                                   const float* __restrict__ vw,
                                                   const float* __restrict__ gkv,
                                                   float* __restrict__ kh,
                                                   float* __restrict__ vh) {
  const int bg = blockIdx.x;
  const int g  = bg & 7;
  const int tid = threadIdx.x;
  __shared__ float smp[32 * 64];   // [c][j] sampled kv
  __shared__ float kws[64 * 33];   // padded: read [o][c] with o per-lane
  __shared__ float vws[64 * 33];
  __shared__ float xs_[64], ys_[64];

  for (int idx = tid; idx < 2048; idx += 256) {
    int o = idx >> 5, c = idx & 31;
    kws[o * 33 + c] = kw[(g * 64 + o) * 32 + c];
    vws[o * 33 + c] = vw[(g * 64 + o) * 32 + c];
  }
  if (tid < 64) {
    float g0 = gkv[(bg * 64 + tid) * 2];
    float g1 = gkv[(bg * 64 + tid) * 2 + 1];
    xs_[tid] = (g0 + 1.f) * 16.f - 0.5f;   // (gx+1)*W/2 - 0.5
    ys_[tid] = (g1 + 1.f) * 16.f - 0.5f;
  }
  __syncthreads();

  const float* imgb = x + (size_t)bg * 32 * NPX;  // x viewed (16,32,32,32)
  for (int idx = tid; idx < 2048; idx += 256) {
    int c = idx >> 6, j = idx & 63;
    float xx = xs_[j], yy = ys_[j];
    float x0f = floorf(xx), y0f = floorf(yy);
    int x0 = (int)x0f, y0 = (int)y0f;
    float wx1 = xx - x0f, wy1 = yy - y0f;
    float wx0 = 1.f - wx1, wy0 = 1.f - wy1;
    int x1 = x0 + 1, y1 = y0 + 1;
    bool vx0 = (x0 >= 0) & (x0 < 32), vx1 = (x1 >= 0) & (x1 < 32);
    bool vy0 = (y0 >= 0) & (y0 < 32), vy1 = (y1 >= 0) & (y1 < 32);
    int cx0 = min(max(x0, 0), 31), cx1 = min(max(x1, 0), 31);
    int cy0 = min(max(y0, 0), 31), cy1 = min(max(y1, 0), 31);
    const float* img = imgb + (size_t)c * NPX;
    float v00 = (vy0 && vx0) ? img[cy0 * 32 + cx0] : 0.f;
    float v01 = (vy0 && vx1) ? img[cy0 * 32 + cx1] : 0.f;
    float v10 = (vy1 && vx0) ? img[cy1 * 32 + cx0] : 0.f;
    float v11 = (vy1 && vx1) ? img[cy1 * 32 + cx1] : 0.f;
    smp[c * 64 + j] = v00 * wy0 * wx0 + v01 * wy0 * wx1 +
                      v10 * wy1 * wx0 + v11 * wy1 * wx1;
  }
  __syncthreads();

  for (int idx = tid; idx < 4096; idx += 256) {
    int j = idx >> 6, o = idx & 63;   // j uniform/wave (smp broadcast), o per-lane
    float ak0 = 0.f, ak1 = 0.f, av0 = 0.f, av1 = 0.f;
#pragma unroll
    for (int c = 0; c < 32; c += 2) {
      float s0 = smp[c * 64 + j], s1 = smp[(c + 1) * 64 + j];
      ak0 = fmaf(kws[o * 33 + c],     s0, ak0);
      ak1 = fmaf(kws[o * 33 + c + 1], s1, ak1);
      av0 = fmaf(vws[o * 33 + c],     s0, av0);
      av1 = fmaf(vws[o * 33 + c + 1], s1, av1);
    }
    kh[((size_t)bg * 64 + j) * 64 + o] = ak0 + ak1;   // coalesced (o contig)
    vh[((size_t)bg * 64 + j) * 64 + o] = av0 + av1;
  }
}

// ---------------------------------------------------------------------------
// K4: fused CPB-MLP + sim + softmax + PV per (bh, 16-row i-tile)
// grid: (64 tiles, 16 bh), 256 thr. Dominant kernel (~8.8 GFLOP total).
// ---------------------------------------------------------------------------
__global__ __launch_bounds__(256) void k_attn(
    const float* __restrict__ qT, const float* __restrict__ kh,
    const float* __restrict__ vh, const float* __restrict__ gkv,
    const float* __restrict__ w1, const float* __restrict__ b1,
    const float* __restrict__ w2, const float* __restrict__ b2,
    const float* __restrict__ w3, const float* __restrict__ b3,
    float* __restrict__ ao) {
  const int it  = blockIdx.x;     // 0..63
  const int bh  = blockIdx.y;     // 0..15
  const int i0  = it << 4;
  const int iy  = i0 >> 5;        // constant row-y for the whole tile
  const int ixb = i0 & 31;        // 0 or 16
  const int tid = threadIdx.x;

  __shared__ float ks[64 * 65];    // [j][d], pad 65: dot reads j per-lane
  __shared__ float vs[64 * 65];
  __shared__ float qs[16 * 64];    // [il][d], broadcast reads
  __shared__ float W2s[64 * 64];   // broadcast reads
  __shared__ float utab[16 * 65];  // log-pos x table; ALIASED as ot later
  __shared__ float vtab[64];
  __shared__ float w1xs[64], w1ys[64], b1s[64], b2s[64], w3s[64];
  __shared__ float sim[16 * 65];

  for (int idx = tid; idx < 4096; idx += 256) {
    int j = idx >> 6, d = idx & 63;
    ks[j * 65 + d] = kh[((size_t)bh * 64 + j) * 64 + d];
    vs[j * 65 + d] = vh[((size_t)bh * 64 + j) * 64 + d];
    W2s[idx] = w2[idx];
  }
  for (int idx = tid; idx < 1024; idx += 256)
    qs[idx] = qT[((size_t)bh * NPX + i0) * 64 + idx];
  if (tid < 64) {
    w1xs[tid] = w1[tid * 2];
    w1ys[tid] = w1[tid * 2 + 1];
    b1s[tid]  = b1[tid];
    b2s[tid]  = b2[tid];
    w3s[tid]  = w3[tid];
    float kyv = gkv[(bh * 64 + tid) * 2 + 1];
    float qyn = (2.f / 31.f) * (float)iy - 1.f;
    vtab[tid] = slog1p(qyn - kyv);
  }
  for (int idx = tid; idx < 1024; idx += 256) {
    int il = idx >> 6, j = idx & 63;
    float kxv = gkv[(bh * 64 + j) * 2];
    float qxn = (2.f / 31.f) * (float)(ixb + il) - 1.f;
    utab[il * 65 + j] = slog1p(qxn - kxv);
  }
  __syncthreads();

  const float b3v = b3[0];
#pragma unroll 1
  for (int p = 0; p < 4; ++p) {
    int pair = tid + (p << 8);
    int il = pair >> 6, j = pair & 63;   // il uniform per wave, j = lane
    float u  = utab[il * 65 + j];
    float vv = vtab[j];
    float h1[64];
#pragma unroll
    for (int c = 0; c < 64; ++c)
      h1[c] = fmaxf(fmaf(w1xs[c], u, fmaf(w1ys[c], vv, b1s[c])), 0.f);
    float cb0 = 0.f, cb1 = 0.f;
#pragma unroll 2
    for (int c2 = 0; c2 < 64; ++c2) {
      const float* wr = &W2s[c2 << 6];
      float a0 = 0.f, a1 = 0.f, a2 = 0.f, a3 = 0.f;  // 4-way ILP
#pragma unroll
      for (int c = 0; c < 64; c += 4) {
        a0 = fmaf(wr[c],     h1[c],     a0);
        a1 = fmaf(wr[c + 1], h1[c + 1], a1);
        a2 = fmaf(wr[c + 2], h1[c + 2], a2);
        a3 = fmaf(wr[c + 3], h1[c + 3], a3);
      }
      float av = fmaxf(b2s[c2] + ((a0 + a1) + (a2 + a3)), 0.f);
      if (c2 & 1) cb1 = fmaf(w3s[c2], av, cb1);
      else        cb0 = fmaf(w3s[c2], av, cb0);
    }
    float cb = cb0 + cb1 + b3v;
    float s0 = 0.f, s1 = 0.f, s2 = 0.f, s3 = 0.f;
#pragma unroll
    for (int d = 0; d < 64; d += 4) {
      s0 = fmaf(qs[(il << 6) + d],     ks[j * 65 + d],     s0);
      s1 = fmaf(qs[(il << 6) + d + 1], ks[j * 65 + d + 1], s1);
      s2 = fmaf(qs[(il << 6) + d + 2], ks[j * 65 + d + 2], s2);
      s3 = fmaf(qs[(il << 6) + d + 3], ks[j * 65 + d + 3], s3);
    }
    sim[il * 65 + j] = ((s0 + s1) + (s2 + s3)) + cb;
  }
  __syncthreads();

  {  // softmax: 16 threads per row (rows of 64)
    int r = tid >> 4, sl = tid & 15;
    float sv[4];
    float m = -1e30f;
#pragma unroll
    for (int t = 0; t < 4; ++t) {
      sv[t] = sim[r * 65 + sl + (t << 4)];
      m = fmaxf(m, sv[t]);
    }
#pragma unroll
    for (int off = 8; off > 0; off >>= 1) m = fmaxf(m, __shfl_xor(m, off, 16));
    float ssum = 0.f;
#pragma unroll
    for (int t = 0; t < 4; ++t) { sv[t] = expf(sv[t] - m); ssum += sv[t]; }
#pragma unroll
    for (int off = 8; off > 0; off >>= 1) ssum += __shfl_xor(ssum, off, 16);
    float inv = 1.f / ssum;
#pragma unroll
    for (int t = 0; t < 4; ++t) sim[r * 65 + sl + (t << 4)] = sv[t] * inv;
  }
  __syncthreads();

  float* ot = utab;  // safe alias: utab last read before first sync above
  for (int idx = tid; idx < 1024; idx += 256) {
    int il = idx >> 6, d = idx & 63;   // il uniform/wave, d per-lane
    float a0 = 0.f, a1 = 0.f, a2 = 0.f, a3 = 0.f;
#pragma unroll
    for (int j = 0; j < 64; j += 4) {
      a0 = fmaf(sim[il * 65 + j],     vs[j * 65 + d],       a0);
      a1 = fmaf(sim[il * 65 + j + 1], vs[(j + 1) * 65 + d], a1);
      a2 = fmaf(sim[il * 65 + j + 2], vs[(j + 2) * 65 + d], a2);
      a3 = fmaf(sim[il * 65 + j + 3], vs[(j + 3) * 65 + d], a3);
    }
    ot[il * 65 + d] = (a0 + a1) + (a2 + a3);
  }
  __syncthreads();
  for (int idx = tid; idx < 1024; idx += 256) {
    int d = idx >> 4, il = idx & 15;
    ao[((size_t)bh * 64 + d) * NPX + i0 + il] = ot[il * 65 + d];
  }
}

// ---------------------------------------------------------------------------
// K5: output projection  out[b,o,p] = sum_c out_w[o,c]*ao[b,c,p] + out_b[o]
// grid: 128 blocks = (2 b) x (64 pixel tiles of 16), 256 thr (thread = o)
// ---------------------------------------------------------------------------
__global__ __launch_bounds__(256) void k_proj(const float* __restrict__ ao,
                                              const float* __restrict__ ow,
                                              const float* __restrict__ ob,
                                              float* __restrict__ out) {
  const int blk = blockIdx.x;
  const int b   = blk >> 6;
  const int p0  = (blk & 63) << 4;
  const int tid = threadIdx.x;  // = output channel o
  __shared__ float as_[32 * 16];   // [c][p]
  __shared__ float wls[256 * 33];  // padded: read [o][c] with o per-lane
  float acc[16];
#pragma unroll
  for (int t = 0; t < 16; ++t) acc[t] = 0.f;

  for (int c0 = 0; c0 < 512; c0 += 32) {
    __syncthreads();
    for (int idx = tid; idx < 32 * 16; idx += 256) {
      int c = idx >> 4, p = idx & 15;
      as_[idx] = ao[((size_t)b * 512 + c0 + c) * NPX + p0 + p];
    }
    for (int idx = tid; idx < 256 * 32; idx += 256) {
      int o = idx >> 5, c = idx & 31;
      wls[o * 33 + c] = ow[(size_t)o * 512 + c0 + c];
    }
    __syncthreads();
    for (int c = 0; c < 32; ++c) {
      float w = wls[tid * 33 + c];
#pragma unroll
      for (int t = 0; t < 16; ++t) acc[t] = fmaf(w, as_[c * 16 + t], acc[t]);
    }
  }
  float bias = ob[tid];
  float4* dst = (float4*)(out + ((size_t)b * 256 + tid) * NPX + p0);
#pragma unroll
  for (int t = 0; t < 4; ++t) {
    float4 v;
    v.x = acc[t * 4 + 0] + bias;
    v.y = acc[t * 4 + 1] + bias;
    v.z = acc[t * 4 + 2] + bias;
    v.w = acc[t * 4 + 3] + bias;
    dst[t] = v;
  }
}

// ---------------------------------------------------------------------------
extern "C" void kernel_launch(void* const* d_in, const int* in_sizes, int n_in,
                              void* d_out, int out_size, void* d_ws, size_t ws_size,
                              hipStream_t stream) {
  const float* x      = (const float*)d_in[0];
  const float* q_w    = (const float*)d_in[1];
  const float* k_w    = (const float*)d_in[2];
  const float* v_w    = (const float*)d_in[3];
  const float* out_w  = (const float*)d_in[4];
  const float* out_b  = (const float*)d_in[5];
  const float* off_w1 = (const float*)d_in[6];
  const float* off_b1 = (const float*)d_in[7];
  const float* off_w2 = (const float*)d_in[8];
  const float* cpb_w1 = (const float*)d_in[9];
  const float* cpb_b1 = (const float*)d_in[10];
  const float* cpb_w2 = (const float*)d_in[11];
  const float* cpb_b2 = (const float*)d_in[12];
  const float* cpb_w3 = (const float*)d_in[13];
  const float* cpb_b3 = (const float*)d_in[14];
  float* out = (float*)d_out;

  float* ws  = (float*)d_ws;
  float* q   = ws;             // 2*512*1024       = 1048576
  float* qT  = q  + 1048576;   // 1048576 (pre-scaled, (bh,i,d))
  float* kh  = qT + 1048576;   // 2*8*64*64        = 65536
  float* vh  = kh + 65536;     // 65536
  float* gkv = vh + 65536;     // 16*64*2          = 2048
  float* ao  = gkv + 2048;     // 2*512*1024       = 1048576
  // total ~3.28M floats = 13.1 MB of d_ws

  k_qconv<<<256, 256, 0, stream>>>(x, q_w, q, qT);
  k_offset<<<16, 256, 0, stream>>>(q, off_w1, off_b1, off_w2, gkv);
  k_sample_kv<<<16, 256, 0, stream>>>(x, k_w, v_w, gkv, kh, vh);
  k_attn<<<dim3(64, 16), 256, 0, stream>>>(qT, kh, vh, gkv, cpb_w1, cpb_b1,
                                           cpb_w2, cpb_b2, cpb_w3, cpb_b3, ao);
  k_proj<<<128, 256, 0, stream>>>(ao, out_w, out_b, out);
}

// Round 5
// 170.683 us; speedup vs baseline: 4.6183x; 4.6183x over previous
//
#include <hip/hip_runtime.h>
#include <math.h>

#define NPX 1024  // H*W = 32*32

using bf16x8 = __attribute__((ext_vector_type(8))) short;  // 8 bf16 in 4 VGPRs
using f32x4  = __attribute__((ext_vector_type(4))) float;

__device__ __forceinline__ float slog1p(float p) {
  return copysignf(log1pf(fabsf(p)), p);
}

__device__ __forceinline__ short f2bf(float f) {
  unsigned u = __builtin_bit_cast(unsigned, f);
  unsigned r = (u + 0x7FFFu + ((u >> 16) & 1u)) >> 16;  // RNE
  return (short)r;
}

// ---------------------------------------------------------------------------
// K1: grouped 1x1 conv  q = x * q_w   (2,256,32,32) -> (2,512,32,32)
// also emits qT[(bg*1024+p)*64 + d] = q * 0.125 (pre-scaled, d-contiguous)
// ---------------------------------------------------------------------------
__global__ __launch_bounds__(256) void k_qconv(const float* __restrict__ x,
                                               const float* __restrict__ qw,
                                               float* __restrict__ q,
                                               float* __restrict__ qT) {
  const int blk = blockIdx.x;
  const int bg  = blk >> 4;
  const int px0 = (blk & 15) << 6;
  const int g   = bg & 7;
  const int b   = bg >> 3;
  const int tid = threadIdx.x;
  __shared__ float xs[32 * 64];
  __shared__ float wsh[64 * 32];
  __shared__ float ot[64 * 65];

  const float* xb = x + ((size_t)(b * 256 + g * 32)) * NPX + px0;
  for (int idx = tid; idx < 32 * 64; idx += 256) {
    int c = idx >> 6, p = idx & 63;
    xs[idx] = xb[(size_t)c * NPX + p];
  }
  const float* wb = qw + g * 64 * 32;
  for (int idx = tid; idx < 64 * 32; idx += 256) wsh[idx] = wb[idx];
  __syncthreads();

  for (int idx = tid; idx < 64 * 64; idx += 256) {
    int o = idx >> 6, p = idx & 63;
    float a0 = 0.f, a1 = 0.f;
#pragma unroll
    for (int c = 0; c < 32; c += 2) {
      a0 = fmaf(wsh[o * 32 + c],     xs[c * 64 + p],       a0);
      a1 = fmaf(wsh[o * 32 + c + 1], xs[(c + 1) * 64 + p], a1);
    }
    float acc = a0 + a1;
    q[((size_t)(bg * 64 + o)) * NPX + px0 + p] = acc;
    ot[o * 65 + p] = acc * 0.125f;
  }
  __syncthreads();
  float* qTb = qT + ((size_t)bg * NPX + px0) * 64;
  for (int idx = tid; idx < 64 * 64; idx += 256) {
    int p = idx >> 6, o = idx & 63;
    qTb[p * 64 + o] = ot[o * 65 + p];
  }
}

// ---------------------------------------------------------------------------
// K2: offset net -> normalized sample grid gkv (16,64,2)
// ---------------------------------------------------------------------------
__global__ __launch_bounds__(256) void k_offset(const float* __restrict__ q,
                                                const float* __restrict__ w1,
                                                const float* __restrict__ b1,
                                                const float* __restrict__ w2,
                                                float* __restrict__ gkv) {
  const int bg = blockIdx.x;
  const int tid = threadIdx.x;
  __shared__ float ge[64 * 64];
  __shared__ float w1s[64 * 36];
  __shared__ float b1s[64];
  const float* qb = q + (size_t)bg * 64 * NPX;
  for (int idx = tid; idx < 64 * 36; idx += 256) w1s[idx] = w1[idx];
  if (tid < 64) b1s[tid] = b1[tid];
  __syncthreads();

  for (int idx = tid; idx < 4096; idx += 256) {
    int c = idx >> 6, px = idx & 63;
    int oy = px >> 3, ox = px & 7;
    const float* qc = qb + (size_t)c * NPX;
    float acc = 0.f;
#pragma unroll
    for (int ky = 0; ky < 6; ++ky) {
      int yy = oy * 4 - 1 + ky;
      if (yy < 0 || yy >= 32) continue;
#pragma unroll
      for (int kx = 0; kx < 6; ++kx) {
        int xx = ox * 4 - 1 + kx;
        if (xx < 0 || xx >= 32) continue;
        acc = fmaf(w1s[c * 36 + ky * 6 + kx], qc[yy * 32 + xx], acc);
      }
    }
    acc += b1s[c];
    ge[c * 64 + px] = 0.5f * acc * (1.f + erff(acc * 0.70710678118654752440f));
  }
  __syncthreads();
  if (tid < 64) {
    int px = tid;
    float s0 = 0.f, s1 = 0.f;
    for (int c = 0; c < 64; ++c) {
      float gv = ge[c * 64 + px];
      s0 = fmaf(w2[c],      gv, s0);
      s1 = fmaf(w2[64 + c], gv, s1);
    }
    float o0 = tanhf(s0) * 4.f;
    float o1 = tanhf(s1) * 4.f;
    int oy = px >> 3, ox = px & 7;
    gkv[(bg * 64 + px) * 2 + 0] = 2.f * ((float)ox + o0) / 7.f - 1.f;
    gkv[(bg * 64 + px) * 2 + 1] = 2.f * ((float)oy + o1) / 7.f - 1.f;
  }
}

// ---------------------------------------------------------------------------
// K3: bilinear grid_sample + grouped 1x1 convs k,v -> kh/vh (bh, j, d)
// ---------------------------------------------------------------------------
__global__ __launch_bounds__(256) void k_sample_kv(const float* __restrict__ x,
                                                   const float* __restrict__ kw,
                                                   const float* __restrict__ vw,
                                                   const float* __restrict__ gkv,
                                                   float* __restrict__ kh,
                                                   float* __restrict__ vh) {
  const int bg = blockIdx.x;
  const int g  = bg & 7;
  const int tid = threadIdx.x;
  __shared__ float smp[32 * 64];
  __shared__ float kws[64 * 33];
  __shared__ float vws[64 * 33];
  __shared__ float xs_[64], ys_[64];

  for (int idx = tid; idx < 2048; idx += 256) {
    int o = idx >> 5, c = idx & 31;
    kws[o * 33 + c] = kw[(g * 64 + o) * 32 + c];
    vws[o * 33 + c] = vw[(g * 64 + o) * 32 + c];
  }
  if (tid < 64) {
    float g0 = gkv[(bg * 64 + tid) * 2];
    float g1 = gkv[(bg * 64 + tid) * 2 + 1];
    xs_[tid] = (g0 + 1.f) * 16.f - 0.5f;
    ys_[tid] = (g1 + 1.f) * 16.f - 0.5f;
  }
  __syncthreads();

  const float* imgb = x + (size_t)bg * 32 * NPX;
  for (int idx = tid; idx < 2048; idx += 256) {
    int c = idx >> 6, j = idx & 63;
    float xx = xs_[j], yy = ys_[j];
    float x0f = floorf(xx), y0f = floorf(yy);
    int x0 = (int)x0f, y0 = (int)y0f;
    float wx1 = xx - x0f, wy1 = yy - y0f;
    float wx0 = 1.f - wx1, wy0 = 1.f - wy1;
    int x1 = x0 + 1, y1 = y0 + 1;
    bool vx0 = (x0 >= 0) & (x0 < 32), vx1 = (x1 >= 0) & (x1 < 32);
    bool vy0 = (y0 >= 0) & (y0 < 32), vy1 = (y1 >= 0) & (y1 < 32);
    int cx0 = min(max(x0, 0), 31), cx1 = min(max(x1, 0), 31);
    int cy0 = min(max(y0, 0), 31), cy1 = min(max(y1, 0), 31);
    const float* img = imgb + (size_t)c * NPX;
    float v00 = (vy0 && vx0) ? img[cy0 * 32 + cx0] : 0.f;
    float v01 = (vy0 && vx1) ? img[cy0 * 32 + cx1] : 0.f;
    float v10 = (vy1 && vx0) ? img[cy1 * 32 + cx0] : 0.f;
    float v11 = (vy1 && vx1) ? img[cy1 * 32 + cx1] : 0.f;
    smp[c * 64 + j] = v00 * wy0 * wx0 + v01 * wy0 * wx1 +
                      v10 * wy1 * wx0 + v11 * wy1 * wx1;
  }
  __syncthreads();

  for (int idx = tid; idx < 4096; idx += 256) {
    int j = idx >> 6, o = idx & 63;
    float ak0 = 0.f, ak1 = 0.f, av0 = 0.f, av1 = 0.f;
#pragma unroll
    for (int c = 0; c < 32; c += 2) {
      float s0 = smp[c * 64 + j], s1 = smp[(c + 1) * 64 + j];
      ak0 = fmaf(kws[o * 33 + c],     s0, ak0);
      ak1 = fmaf(kws[o * 33 + c + 1], s1, ak1);
      av0 = fmaf(vws[o * 33 + c],     s0, av0);
      av1 = fmaf(vws[o * 33 + c + 1], s1, av1);
    }
    kh[((size_t)bg * 64 + j) * 64 + o] = ak0 + ak1;
    vh[((size_t)bg * 64 + j) * 64 + o] = av0 + av1;
  }
}

// ---------------------------------------------------------------------------
// K4: fused CPB-MLP (MFMA) + QK^T (MFMA) + softmax + PV per (bh, 16-row tile)
// grid: (64 tiles, 16 bh), 256 thr = 4 waves; wave w owns j-cols [16w,16w+16)
// ---------------------------------------------------------------------------
__global__ __launch_bounds__(256) void k_attn(
    const float* __restrict__ qT, const float* __restrict__ kh,
    const float* __restrict__ vh, const float* __restrict__ gkv,
    const float* __restrict__ w1, const float* __restrict__ b1,
    const float* __restrict__ w2, const float* __restrict__ b2,
    const float* __restrict__ w3, const float* __restrict__ b3,
    float* __restrict__ ao) {
  const int it  = blockIdx.x;     // 0..63
  const int bh  = blockIdx.y;     // 0..15
  const int i0  = it << 4;
  const int iy  = i0 >> 5;        // row-y constant over tile
  const int ixb = i0 & 31;
  const int tid = threadIdx.x;

  __shared__ float ks[64 * 65];    // [j][d]
  __shared__ float vs[64 * 65];
  __shared__ float qs[16 * 64];    // [il][d] (pre-scaled)
  __shared__ float W2s[64 * 64];   // [c2][c]
  __shared__ float utab[16 * 65];  // u(il,j); ALIASED as ot after softmax
  __shared__ float vtab[64];
  __shared__ float w1xs[64], w1ys[64], b1s[64], b2s[64], w3s[64];
  __shared__ float sim[16 * 65];

  for (int idx = tid; idx < 4096; idx += 256) {
    int j = idx >> 6, d = idx & 63;
    ks[j * 65 + d] = kh[((size_t)bh * 64 + j) * 64 + d];
    vs[j * 65 + d] = vh[((size_t)bh * 64 + j) * 64 + d];
    W2s[idx] = w2[idx];
  }
  for (int idx = tid; idx < 1024; idx += 256)
    qs[idx] = qT[((size_t)bh * NPX + i0) * 64 + idx];
  if (tid < 64) {
    w1xs[tid] = w1[tid * 2];
    w1ys[tid] = w1[tid * 2 + 1];
    b1s[tid]  = b1[tid];
    b2s[tid]  = b2[tid];
    w3s[tid]  = w3[tid];
    float kyv = gkv[(bh * 64 + tid) * 2 + 1];
    float qyn = (2.f / 31.f) * (float)iy - 1.f;
    vtab[tid] = slog1p(qyn - kyv);
  }
  for (int idx = tid; idx < 1024; idx += 256) {
    int il = idx >> 6, j = idx & 63;
    float kxv = gkv[(bh * 64 + j) * 2];
    float qxn = (2.f / 31.f) * (float)(ixb + il) - 1.f;
    utab[il * 65 + j] = slog1p(qxn - kxv);
  }
  __syncthreads();

  const float b3v = b3[0];
  const int w  = tid >> 6;   // wave 0..3 -> j-block
  const int l  = tid & 63;
  const int lm = l & 15;     // MFMA n-index / m-index
  const int lg = l >> 4;     // MFMA k-block / row-group

  // per-lane layer-3 constants: c2 = c2t*16 + lm
  float b2v[4], w3v[4];
#pragma unroll
  for (int c2t = 0; c2t < 4; ++c2t) {
    b2v[c2t] = b2s[c2t * 16 + lm];
    w3v[c2t] = w3s[c2t * 16 + lm];
  }
  // W2 B-fragments: B[k=c][n=c2] = W2[c2][c]; frag elem r -> c = s*32+lg*8+r
  bf16x8 bw2[4][2];
#pragma unroll
  for (int c2t = 0; c2t < 4; ++c2t)
#pragma unroll
    for (int s = 0; s < 2; ++s)
#pragma unroll
      for (int r = 0; r < 8; ++r)
        bw2[c2t][s][r] = f2bf(W2s[(c2t * 16 + lm) * 64 + s * 32 + lg * 8 + r]);

  // ---- CPB pass: per il, wave w computes cb for j in [16w, 16w+16) ----
  const int jb = w * 16;
#pragma unroll 1
  for (int il = 0; il < 16; ++il) {
    float u  = utab[il * 65 + jb + lm];
    float vv = vtab[jb + lm];
    bf16x8 af[2];  // A[m=point(lm)][k=c]: elem r -> c = s*32+lg*8+r
#pragma unroll
    for (int s = 0; s < 2; ++s)
#pragma unroll
      for (int r = 0; r < 8; ++r) {
        int c = s * 32 + lg * 8 + r;
        float h = fmaf(w1xs[c], u, fmaf(w1ys[c], vv, b1s[c]));
        af[s][r] = f2bf(fmaxf(h, 0.f));
      }
    f32x4 acc[4];
#pragma unroll
    for (int c2t = 0; c2t < 4; ++c2t) {
      acc[c2t] = (f32x4){0.f, 0.f, 0.f, 0.f};
      acc[c2t] = __builtin_amdgcn_mfma_f32_16x16x32_bf16(af[0], bw2[c2t][0], acc[c2t], 0, 0, 0);
      acc[c2t] = __builtin_amdgcn_mfma_f32_16x16x32_bf16(af[1], bw2[c2t][1], acc[c2t], 0, 0, 0);
    }
    // layer 3: relu(+b2) dot w3, then reduce over lm (16 c2 per tile)
    float sres[4];
#pragma unroll
    for (int r = 0; r < 4; ++r) {
      float t0 = fmaxf(acc[0][r] + b2v[0], 0.f) * w3v[0];
      t0 = fmaf(fmaxf(acc[1][r] + b2v[1], 0.f), w3v[1], t0);
      t0 = fmaf(fmaxf(acc[2][r] + b2v[2], 0.f), w3v[2], t0);
      t0 = fmaf(fmaxf(acc[3][r] + b2v[3], 0.f), w3v[3], t0);
      sres[r] = t0;
    }
#pragma unroll
    for (int r = 0; r < 4; ++r) {
      sres[r] += __shfl_xor(sres[r], 1);
      sres[r] += __shfl_xor(sres[r], 2);
      sres[r] += __shfl_xor(sres[r], 4);
      sres[r] += __shfl_xor(sres[r], 8);
    }
    // D row (= point-in-tile) = lg*4 + r -> j = jb + lg*4 + r
    if (lm == 0) {
#pragma unroll
      for (int r = 0; r < 4; ++r)
        sim[il * 65 + jb + lg * 4 + r] = sres[r] + b3v;
    }
  }

  // ---- QK pass: wave w adds Q.K^T into sim[:, jb..jb+15] ----
  {
    bf16x8 aq[2], bk[2];
#pragma unroll
    for (int s = 0; s < 2; ++s)
#pragma unroll
      for (int r = 0; r < 8; ++r) {
        aq[s][r] = f2bf(qs[lm * 64 + s * 32 + lg * 8 + r]);           // A[il=lm][d]
        bk[s][r] = f2bf(ks[(jb + lm) * 65 + s * 32 + lg * 8 + r]);    // B[d][j=lm]
      }
    f32x4 qacc = (f32x4){0.f, 0.f, 0.f, 0.f};
    qacc = __builtin_amdgcn_mfma_f32_16x16x32_bf16(aq[0], bk[0], qacc, 0, 0, 0);
    qacc = __builtin_amdgcn_mfma_f32_16x16x32_bf16(aq[1], bk[1], qacc, 0, 0, 0);
    // D: row = il = lg*4+r, col = j = jb+lm  (same wave owns this region)
#pragma unroll
    for (int r = 0; r < 4; ++r)
      sim[(lg * 4 + r) * 65 + jb + lm] += qacc[r];
  }
  __syncthreads();

  {  // softmax: 16 threads per row of 64
    int r = tid >> 4, sl = tid & 15;
    float sv[4];
    float m = -1e30f;
#pragma unroll
    for (int t = 0; t < 4; ++t) {
      sv[t] = sim[r * 65 + sl + (t << 4)];
      m = fmaxf(m, sv[t]);
    }
#pragma unroll
    for (int off = 8; off > 0; off >>= 1) m = fmaxf(m, __shfl_xor(m, off, 16));
    float ssum = 0.f;
#pragma unroll
    for (int t = 0; t < 4; ++t) { sv[t] = expf(sv[t] - m); ssum += sv[t]; }
#pragma unroll
    for (int off = 8; off > 0; off >>= 1) ssum += __shfl_xor(ssum, off, 16);
    float inv = 1.f / ssum;
#pragma unroll
    for (int t = 0; t < 4; ++t) sim[r * 65 + sl + (t << 4)] = sv[t] * inv;
  }
  __syncthreads();

  float* ot = utab;  // alias: utab dead after CPB pass
  for (int idx = tid; idx < 1024; idx += 256) {
    int il = idx >> 6, d = idx & 63;
    float a0 = 0.f, a1 = 0.f, a2 = 0.f, a3 = 0.f;
#pragma unroll
    for (int j = 0; j < 64; j += 4) {
      a0 = fmaf(sim[il * 65 + j],     vs[j * 65 + d],       a0);
      a1 = fmaf(sim[il * 65 + j + 1], vs[(j + 1) * 65 + d], a1);
      a2 = fmaf(sim[il * 65 + j + 2], vs[(j + 2) * 65 + d], a2);
      a3 = fmaf(sim[il * 65 + j + 3], vs[(j + 3) * 65 + d], a3);
    }
    ot[il * 65 + d] = (a0 + a1) + (a2 + a3);
  }
  __syncthreads();
  for (int idx = tid; idx < 1024; idx += 256) {
    int d = idx >> 4, il = idx & 15;
    ao[((size_t)bh * 64 + d) * NPX + i0 + il] = ot[il * 65 + d];
  }
}

// ---------------------------------------------------------------------------
// K5: output projection
// ---------------------------------------------------------------------------
__global__ __launch_bounds__(256) void k_proj(const float* __restrict__ ao,
                                              const float* __restrict__ ow,
                                              const float* __restrict__ ob,
                                              float* __restrict__ out) {
  const int blk = blockIdx.x;
  const int b   = blk >> 6;
  const int p0  = (blk & 63) << 4;
  const int tid = threadIdx.x;
  __shared__ float as_[32 * 16];
  __shared__ float wls[256 * 33];
  float acc[16];
#pragma unroll
  for (int t = 0; t < 16; ++t) acc[t] = 0.f;

  for (int c0 = 0; c0 < 512; c0 += 32) {
    __syncthreads();
    for (int idx = tid; idx < 32 * 16; idx += 256) {
      int c = idx >> 4, p = idx & 15;
      as_[idx] = ao[((size_t)b * 512 + c0 + c) * NPX + p0 + p];
    }
    for (int idx = tid; idx < 256 * 32; idx += 256) {
      int o = idx >> 5, c = idx & 31;
      wls[o * 33 + c] = ow[(size_t)o * 512 + c0 + c];
    }
    __syncthreads();
    for (int c = 0; c < 32; ++c) {
      float wv = wls[tid * 33 + c];
#pragma unroll
      for (int t = 0; t < 16; ++t) acc[t] = fmaf(wv, as_[c * 16 + t], acc[t]);
    }
  }
  float bias = ob[tid];
  float4* dst = (float4*)(out + ((size_t)b * 256 + tid) * NPX + p0);
#pragma unroll
  for (int t = 0; t < 4; ++t) {
    float4 v;
    v.x = acc[t * 4 + 0] + bias;
    v.y = acc[t * 4 + 1] + bias;
    v.z = acc[t * 4 + 2] + bias;
    v.w = acc[t * 4 + 3] + bias;
    dst[t] = v;
  }
}

// ---------------------------------------------------------------------------
extern "C" void kernel_launch(void* const* d_in, const int* in_sizes, int n_in,
                              void* d_out, int out_size, void* d_ws, size_t ws_size,
                              hipStream_t stream) {
  const float* x      = (const float*)d_in[0];
  const float* q_w    = (const float*)d_in[1];
  const float* k_w    = (const float*)d_in[2];
  const float* v_w    = (const float*)d_in[3];
  const float* out_w  = (const float*)d_in[4];
  const float* out_b  = (const float*)d_in[5];
  const float* off_w1 = (const float*)d_in[6];
  const float* off_b1 = (const float*)d_in[7];
  const float* off_w2 = (const float*)d_in[8];
  const float* cpb_w1 = (const float*)d_in[9];
  const float* cpb_b1 = (const float*)d_in[10];
  const float* cpb_w2 = (const float*)d_in[11];
  const float* cpb_b2 = (const float*)d_in[12];
  const float* cpb_w3 = (const float*)d_in[13];
  const float* cpb_b3 = (const float*)d_in[14];
  float* out = (float*)d_out;

  float* ws  = (float*)d_ws;
  float* q   = ws;             // 2*512*1024
  float* qT  = q  + 1048576;   // (bh,i,d) pre-scaled
  float* kh  = qT + 1048576;
  float* vh  = kh + 65536;
  float* gkv = vh + 65536;
  float* ao  = gkv + 2048;

  k_qconv<<<256, 256, 0, stream>>>(x, q_w, q, qT);
  k_offset<<<16, 256, 0, stream>>>(q, off_w1, off_b1, off_w2, gkv);
  k_sample_kv<<<16, 256, 0, stream>>>(x, k_w, v_w, gkv, kh, vh);
  k_attn<<<dim3(64, 16), 256, 0, stream>>>(qT, kh, vh, gkv, cpb_w1, cpb_b1,
                                           cpb_w2, cpb_b2, cpb_w3, cpb_b3, ao);
  k_proj<<<128, 256, 0, stream>>>(ao, out_w, out_b, out);
}

// Round 6
// 136.734 us; speedup vs baseline: 5.7650x; 1.2483x over previous
//
#include <hip/hip_runtime.h>
#include <math.h>

#define NPX 1024  // H*W = 32*32

using bf16x8 = __attribute__((ext_vector_type(8))) short;  // 8 bf16 in 4 VGPRs
using f32x4  = __attribute__((ext_vector_type(4))) float;

__device__ __forceinline__ float slog1p(float p) {
  return copysignf(log1pf(fabsf(p)), p);
}

__device__ __forceinline__ unsigned short f2bf(float f) {
  unsigned u = __builtin_bit_cast(unsigned, f);
  unsigned r = (u + 0x7FFFu + ((u >> 16) & 1u)) >> 16;  // RNE
  return (unsigned short)r;
}
__device__ __forceinline__ float bf2f(unsigned short h) {
  return __builtin_bit_cast(float, (unsigned)h << 16);
}

// ---------------------------------------------------------------------------
// K0: pack out_w into MFMA-fragment-major bf16 hi/lo:
// whP[((kt*4+lg)*256 + o)*8 + r] = hi(ow[o][kt*32+lg*8+r]); wlP likewise.
// grid: 512 blocks x 256 thr (one elem each)
// ---------------------------------------------------------------------------
__global__ __launch_bounds__(256) void k_prep_w(const float* __restrict__ ow,
                                                unsigned short* __restrict__ whP,
                                                unsigned short* __restrict__ wlP) {
  int idx = blockIdx.x * 256 + threadIdx.x;  // 0..131071
  int o = idx >> 9, c = idx & 511;
  float v = ow[(size_t)o * 512 + c];
  unsigned short hi = f2bf(v);
  unsigned short lo = f2bf(v - bf2f(hi));
  int kt = c >> 5, lg = (c >> 3) & 3, r = c & 7;
  size_t dst = ((size_t)(kt * 4 + lg) * 256 + o) * 8 + r;
  whP[dst] = hi;
  wlP[dst] = lo;
}

// ---------------------------------------------------------------------------
// K1: grouped 1x1 conv  q = x * q_w ; also qT = q*0.125 in (bh,i,d) layout
// ---------------------------------------------------------------------------
__global__ __launch_bounds__(256) void k_qconv(const float* __restrict__ x,
                                               const float* __restrict__ qw,
                                               float* __restrict__ q,
                                               float* __restrict__ qT) {
  const int blk = blockIdx.x;
  const int bg  = blk >> 4;
  const int px0 = (blk & 15) << 6;
  const int g   = bg & 7;
  const int b   = bg >> 3;
  const int tid = threadIdx.x;
  __shared__ float xs[32 * 64];
  __shared__ float wsh[64 * 32];
  __shared__ float ot[64 * 65];

  const float* xb = x + ((size_t)(b * 256 + g * 32)) * NPX + px0;
  for (int idx = tid; idx < 32 * 64; idx += 256) {
    int c = idx >> 6, p = idx & 63;
    xs[idx] = xb[(size_t)c * NPX + p];
  }
  const float* wb = qw + g * 64 * 32;
  for (int idx = tid; idx < 64 * 32; idx += 256) wsh[idx] = wb[idx];
  __syncthreads();

  for (int idx = tid; idx < 64 * 64; idx += 256) {
    int o = idx >> 6, p = idx & 63;
    float a0 = 0.f, a1 = 0.f;
#pragma unroll
    for (int c = 0; c < 32; c += 2) {
      a0 = fmaf(wsh[o * 32 + c],     xs[c * 64 + p],       a0);
      a1 = fmaf(wsh[o * 32 + c + 1], xs[(c + 1) * 64 + p], a1);
    }
    float acc = a0 + a1;
    q[((size_t)(bg * 64 + o)) * NPX + px0 + p] = acc;
    ot[o * 65 + p] = acc * 0.125f;
  }
  __syncthreads();
  float* qTb = qT + ((size_t)bg * NPX + px0) * 64;
  for (int idx = tid; idx < 64 * 64; idx += 256) {
    int p = idx >> 6, o = idx & 63;
    qTb[p * 64 + o] = ot[o * 65 + p];
  }
}

// ---------------------------------------------------------------------------
// K2: offset net -> normalized sample grid gkv (16,64,2)
// ---------------------------------------------------------------------------
__global__ __launch_bounds__(256) void k_offset(const float* __restrict__ q,
                                                const float* __restrict__ w1,
                                                const float* __restrict__ b1,
                                                const float* __restrict__ w2,
                                                float* __restrict__ gkv) {
  const int bg = blockIdx.x;
  const int tid = threadIdx.x;
  __shared__ float ge[64 * 64];
  __shared__ float w1s[64 * 36];
  __shared__ float b1s[64];
  const float* qb = q + (size_t)bg * 64 * NPX;
  for (int idx = tid; idx < 64 * 36; idx += 256) w1s[idx] = w1[idx];
  if (tid < 64) b1s[tid] = b1[tid];
  __syncthreads();

  for (int idx = tid; idx < 4096; idx += 256) {
    int c = idx >> 6, px = idx & 63;
    int oy = px >> 3, ox = px & 7;
    const float* qc = qb + (size_t)c * NPX;
    float acc = 0.f;
#pragma unroll
    for (int ky = 0; ky < 6; ++ky) {
      int yy = oy * 4 - 1 + ky;
      if (yy < 0 || yy >= 32) continue;
#pragma unroll
      for (int kx = 0; kx < 6; ++kx) {
        int xx = ox * 4 - 1 + kx;
        if (xx < 0 || xx >= 32) continue;
        acc = fmaf(w1s[c * 36 + ky * 6 + kx], qc[yy * 32 + xx], acc);
      }
    }
    acc += b1s[c];
    ge[c * 64 + px] = 0.5f * acc * (1.f + erff(acc * 0.70710678118654752440f));
  }
  __syncthreads();
  if (tid < 64) {
    int px = tid;
    float s0 = 0.f, s1 = 0.f;
    for (int c = 0; c < 64; ++c) {
      float gv = ge[c * 64 + px];
      s0 = fmaf(w2[c],      gv, s0);
      s1 = fmaf(w2[64 + c], gv, s1);
    }
    float o0 = tanhf(s0) * 4.f;
    float o1 = tanhf(s1) * 4.f;
    int oy = px >> 3, ox = px & 7;
    gkv[(bg * 64 + px) * 2 + 0] = 2.f * ((float)ox + o0) / 7.f - 1.f;
    gkv[(bg * 64 + px) * 2 + 1] = 2.f * ((float)oy + o1) / 7.f - 1.f;
  }
}

// ---------------------------------------------------------------------------
// K3: bilinear grid_sample + grouped 1x1 convs k,v -> kh/vh (bh, j, d)
// ---------------------------------------------------------------------------
__global__ __launch_bounds__(256) void k_sample_kv(const float* __restrict__ x,
                                                   const float* __restrict__ kw,
                                                   const float* __restrict__ vw,
                                                   const float* __restrict__ gkv,
                                                   float* __restrict__ kh,
                                                   float* __restrict__ vh) {
  const int bg = blockIdx.x;
  const int g  = bg & 7;
  const int tid = threadIdx.x;
  __shared__ float smp[32 * 64];
  __shared__ float kws[64 * 33];
  __shared__ float vws[64 * 33];
  __shared__ float xs_[64], ys_[64];

  for (int idx = tid; idx < 2048; idx += 256) {
    int o = idx >> 5, c = idx & 31;
    kws[o * 33 + c] = kw[(g * 64 + o) * 32 + c];
    vws[o * 33 + c] = vw[(g * 64 + o) * 32 + c];
  }
  if (tid < 64) {
    float g0 = gkv[(bg * 64 + tid) * 2];
    float g1 = gkv[(bg * 64 + tid) * 2 + 1];
    xs_[tid] = (g0 + 1.f) * 16.f - 0.5f;
    ys_[tid] = (g1 + 1.f) * 16.f - 0.5f;
  }
  __syncthreads();

  const float* imgb = x + (size_t)bg * 32 * NPX;
  for (int idx = tid; idx < 2048; idx += 256) {
    int c = idx >> 6, j = idx & 63;
    float xx = xs_[j], yy = ys_[j];
    float x0f = floorf(xx), y0f = floorf(yy);
    int x0 = (int)x0f, y0 = (int)y0f;
    float wx1 = xx - x0f, wy1 = yy - y0f;
    float wx0 = 1.f - wx1, wy0 = 1.f - wy1;
    int x1 = x0 + 1, y1 = y0 + 1;
    bool vx0 = (x0 >= 0) & (x0 < 32), vx1 = (x1 >= 0) & (x1 < 32);
    bool vy0 = (y0 >= 0) & (y0 < 32), vy1 = (y1 >= 0) & (y1 < 32);
    int cx0 = min(max(x0, 0), 31), cx1 = min(max(x1, 0), 31);
    int cy0 = min(max(y0, 0), 31), cy1 = min(max(y1, 0), 31);
    const float* img = imgb + (size_t)c * NPX;
    float v00 = (vy0 && vx0) ? img[cy0 * 32 + cx0] : 0.f;
    float v01 = (vy0 && vx1) ? img[cy0 * 32 + cx1] : 0.f;
    float v10 = (vy1 && vx0) ? img[cy1 * 32 + cx0] : 0.f;
    float v11 = (vy1 && vx1) ? img[cy1 * 32 + cx1] : 0.f;
    smp[c * 64 + j] = v00 * wy0 * wx0 + v01 * wy0 * wx1 +
                      v10 * wy1 * wx0 + v11 * wy1 * wx1;
  }
  __syncthreads();

  for (int idx = tid; idx < 4096; idx += 256) {
    int j = idx >> 6, o = idx & 63;
    float ak0 = 0.f, ak1 = 0.f, av0 = 0.f, av1 = 0.f;
#pragma unroll
    for (int c = 0; c < 32; c += 2) {
      float s0 = smp[c * 64 + j], s1 = smp[(c + 1) * 64 + j];
      ak0 = fmaf(kws[o * 33 + c],     s0, ak0);
      ak1 = fmaf(kws[o * 33 + c + 1], s1, ak1);
      av0 = fmaf(vws[o * 33 + c],     s0, av0);
      av1 = fmaf(vws[o * 33 + c + 1], s1, av1);
    }
    kh[((size_t)bg * 64 + j) * 64 + o] = ak0 + ak1;
    vh[((size_t)bg * 64 + j) * 64 + o] = av0 + av1;
  }
}

// ---------------------------------------------------------------------------
// K4: fused CPB-MLP (MFMA) + QK^T (MFMA) + softmax + PV per (bh, 16-row tile)
// epilogue writes attention output as bf16 hi/lo in [px][c] row-major
// ---------------------------------------------------------------------------
__global__ __launch_bounds__(256) void k_attn(
    const float* __restrict__ qT, const float* __restrict__ kh,
    const float* __restrict__ vh, const float* __restrict__ gkv,
    const float* __restrict__ w1, const float* __restrict__ b1,
    const float* __restrict__ w2, const float* __restrict__ b2,
    const float* __restrict__ w3, const float* __restrict__ b3,
    unsigned short* __restrict__ aoh, unsigned short* __restrict__ aol) {
  const int it  = blockIdx.x;     // 0..63
  const int bh  = blockIdx.y;     // 0..15
  const int i0  = it << 4;
  const int iy  = i0 >> 5;
  const int ixb = i0 & 31;
  const int tid = threadIdx.x;

  __shared__ float ks[64 * 65];
  __shared__ float vs[64 * 65];
  __shared__ float qs[16 * 64];
  __shared__ float W2s[64 * 64];
  __shared__ float utab[16 * 65];  // ALIASED as ot after softmax
  __shared__ float vtab[64];
  __shared__ float w1xs[64], w1ys[64], b1s[64], b2s[64], w3s[64];
  __shared__ float sim[16 * 65];

  for (int idx = tid; idx < 4096; idx += 256) {
    int j = idx >> 6, d = idx & 63;
    ks[j * 65 + d] = kh[((size_t)bh * 64 + j) * 64 + d];
    vs[j * 65 + d] = vh[((size_t)bh * 64 + j) * 64 + d];
    W2s[idx] = w2[idx];
  }
  for (int idx = tid; idx < 1024; idx += 256)
    qs[idx] = qT[((size_t)bh * NPX + i0) * 64 + idx];
  if (tid < 64) {
    w1xs[tid] = w1[tid * 2];
    w1ys[tid] = w1[tid * 2 + 1];
    b1s[tid]  = b1[tid];
    b2s[tid]  = b2[tid];
    w3s[tid]  = w3[tid];
    float kyv = gkv[(bh * 64 + tid) * 2 + 1];
    float qyn = (2.f / 31.f) * (float)iy - 1.f;
    vtab[tid] = slog1p(qyn - kyv);
  }
  for (int idx = tid; idx < 1024; idx += 256) {
    int il = idx >> 6, j = idx & 63;
    float kxv = gkv[(bh * 64 + j) * 2];
    float qxn = (2.f / 31.f) * (float)(ixb + il) - 1.f;
    utab[il * 65 + j] = slog1p(qxn - kxv);
  }
  __syncthreads();

  const float b3v = b3[0];
  const int w  = tid >> 6;   // wave 0..3 -> j-block
  const int l  = tid & 63;
  const int lm = l & 15;
  const int lg = l >> 4;

  float b2v[4], w3v[4];
#pragma unroll
  for (int c2t = 0; c2t < 4; ++c2t) {
    b2v[c2t] = b2s[c2t * 16 + lm];
    w3v[c2t] = w3s[c2t * 16 + lm];
  }
  bf16x8 bw2[4][2];
#pragma unroll
  for (int c2t = 0; c2t < 4; ++c2t)
#pragma unroll
    for (int s = 0; s < 2; ++s)
#pragma unroll
      for (int r = 0; r < 8; ++r)
        bw2[c2t][s][r] = (short)f2bf(W2s[(c2t * 16 + lm) * 64 + s * 32 + lg * 8 + r]);

  const int jb = w * 16;
#pragma unroll 1
  for (int il = 0; il < 16; ++il) {
    float u  = utab[il * 65 + jb + lm];
    float vv = vtab[jb + lm];
    bf16x8 af[2];
#pragma unroll
    for (int s = 0; s < 2; ++s)
#pragma unroll
      for (int r = 0; r < 8; ++r) {
        int c = s * 32 + lg * 8 + r;
        float h = fmaf(w1xs[c], u, fmaf(w1ys[c], vv, b1s[c]));
        af[s][r] = (short)f2bf(fmaxf(h, 0.f));
      }
    f32x4 acc[4];
#pragma unroll
    for (int c2t = 0; c2t < 4; ++c2t) {
      acc[c2t] = (f32x4){0.f, 0.f, 0.f, 0.f};
      acc[c2t] = __builtin_amdgcn_mfma_f32_16x16x32_bf16(af[0], bw2[c2t][0], acc[c2t], 0, 0, 0);
      acc[c2t] = __builtin_amdgcn_mfma_f32_16x16x32_bf16(af[1], bw2[c2t][1], acc[c2t], 0, 0, 0);
    }
    float sres[4];
#pragma unroll
    for (int r = 0; r < 4; ++r) {
      float t0 = fmaxf(acc[0][r] + b2v[0], 0.f) * w3v[0];
      t0 = fmaf(fmaxf(acc[1][r] + b2v[1], 0.f), w3v[1], t0);
      t0 = fmaf(fmaxf(acc[2][r] + b2v[2], 0.f), w3v[2], t0);
      t0 = fmaf(fmaxf(acc[3][r] + b2v[3], 0.f), w3v[3], t0);
      sres[r] = t0;
    }
#pragma unroll
    for (int r = 0; r < 4; ++r) {
      sres[r] += __shfl_xor(sres[r], 1);
      sres[r] += __shfl_xor(sres[r], 2);
      sres[r] += __shfl_xor(sres[r], 4);
      sres[r] += __shfl_xor(sres[r], 8);
    }
    if (lm == 0) {
#pragma unroll
      for (int r = 0; r < 4; ++r)
        sim[il * 65 + jb + lg * 4 + r] = sres[r] + b3v;
    }
  }

  {  // QK pass
    bf16x8 aq[2], bk[2];
#pragma unroll
    for (int s = 0; s < 2; ++s)
#pragma unroll
      for (int r = 0; r < 8; ++r) {
        aq[s][r] = (short)f2bf(qs[lm * 64 + s * 32 + lg * 8 + r]);
        bk[s][r] = (short)f2bf(ks[(jb + lm) * 65 + s * 32 + lg * 8 + r]);
      }
    f32x4 qacc = (f32x4){0.f, 0.f, 0.f, 0.f};
    qacc = __builtin_amdgcn_mfma_f32_16x16x32_bf16(aq[0], bk[0], qacc, 0, 0, 0);
    qacc = __builtin_amdgcn_mfma_f32_16x16x32_bf16(aq[1], bk[1], qacc, 0, 0, 0);
#pragma unroll
    for (int r = 0; r < 4; ++r)
      sim[(lg * 4 + r) * 65 + jb + lm] += qacc[r];
  }
  __syncthreads();

  {  // softmax: 16 threads per row of 64
    int r = tid >> 4, sl = tid & 15;
    float sv[4];
    float m = -1e30f;
#pragma unroll
    for (int t = 0; t < 4; ++t) {
      sv[t] = sim[r * 65 + sl + (t << 4)];
      m = fmaxf(m, sv[t]);
    }
#pragma unroll
    for (int off = 8; off > 0; off >>= 1) m = fmaxf(m, __shfl_xor(m, off, 16));
    float ssum = 0.f;
#pragma unroll
    for (int t = 0; t < 4; ++t) { sv[t] = expf(sv[t] - m); ssum += sv[t]; }
#pragma unroll
    for (int off = 8; off > 0; off >>= 1) ssum += __shfl_xor(ssum, off, 16);
    float inv = 1.f / ssum;
#pragma unroll
    for (int t = 0; t < 4; ++t) sim[r * 65 + sl + (t << 4)] = sv[t] * inv;
  }
  __syncthreads();

  float* ot = utab;  // alias: utab dead after CPB pass
  for (int idx = tid; idx < 1024; idx += 256) {
    int il = idx >> 6, d = idx & 63;
    float a0 = 0.f, a1 = 0.f, a2 = 0.f, a3 = 0.f;
#pragma unroll
    for (int j = 0; j < 64; j += 4) {
      a0 = fmaf(sim[il * 65 + j],     vs[j * 65 + d],       a0);
      a1 = fmaf(sim[il * 65 + j + 1], vs[(j + 1) * 65 + d], a1);
      a2 = fmaf(sim[il * 65 + j + 2], vs[(j + 2) * 65 + d], a2);
      a3 = fmaf(sim[il * 65 + j + 3], vs[(j + 3) * 65 + d], a3);
    }
    ot[il * 65 + d] = (a0 + a1) + (a2 + a3);
  }
  __syncthreads();
  // epilogue: split fp32 -> bf16 hi/lo, write [px][c] row-major (c = h*64+d)
  {
    const int b = bh >> 3, h = bh & 7;
    unsigned short* dh = aoh + ((size_t)(b * 1024 + i0)) * 512 + h * 64;
    unsigned short* dl = aol + ((size_t)(b * 1024 + i0)) * 512 + h * 64;
    for (int idx = tid; idx < 1024; idx += 256) {
      int il = idx >> 6, d = idx & 63;
      float v = ot[il * 65 + d];
      unsigned short hi = f2bf(v);
      unsigned short lo = f2bf(v - bf2f(hi));
      dh[(size_t)il * 512 + d] = hi;
      dl[(size_t)il * 512 + d] = lo;
    }
  }
}

// ---------------------------------------------------------------------------
// K5: projection as split-bf16 MFMA GEMM: out[p][o] = sum_c A[p][c] W[o][c]
// grid: 128 blocks (16-px tiles), 256 thr = 4 waves; wave w owns o in [64w,64w+64)
// No LDS, no barriers: A rows and packed W frags are single 16B L2 loads.
// ---------------------------------------------------------------------------
__global__ __launch_bounds__(256) void k_proj_mfma(
    const unsigned short* __restrict__ aoh, const unsigned short* __restrict__ aol,
    const unsigned short* __restrict__ whP, const unsigned short* __restrict__ wlP,
    const float* __restrict__ ob, float* __restrict__ out) {
  const int p0 = blockIdx.x << 4;       // global px 0..2047
  const int b  = p0 >> 10;
  const int pb = p0 & 1023;             // px within batch
  const int w  = threadIdx.x >> 6;
  const int l  = threadIdx.x & 63;
  const int lm = l & 15, lg = l >> 4;

  f32x4 acc[4];
#pragma unroll
  for (int nt = 0; nt < 4; ++nt) acc[nt] = (f32x4){0.f, 0.f, 0.f, 0.f};

  const unsigned short* arh = aoh + ((size_t)(p0 + lm)) * 512 + lg * 8;
  const unsigned short* arl = aol + ((size_t)(p0 + lm)) * 512 + lg * 8;
  const int ob0 = w * 64;

#pragma unroll 4
  for (int kt = 0; kt < 16; ++kt) {
    bf16x8 ah = *(const bf16x8*)(arh + kt * 32);
    bf16x8 al = *(const bf16x8*)(arl + kt * 32);
    const size_t wb = ((size_t)(kt * 4 + lg) * 256 + ob0 + lm) * 8;
#pragma unroll
    for (int nt = 0; nt < 4; ++nt) {
      bf16x8 bhf = *(const bf16x8*)(whP + wb + nt * 128);  // (+nt*16 o)*8
      bf16x8 blf = *(const bf16x8*)(wlP + wb + nt * 128);
      acc[nt] = __builtin_amdgcn_mfma_f32_16x16x32_bf16(ah, bhf, acc[nt], 0, 0, 0);
      acc[nt] = __builtin_amdgcn_mfma_f32_16x16x32_bf16(ah, blf, acc[nt], 0, 0, 0);
      acc[nt] = __builtin_amdgcn_mfma_f32_16x16x32_bf16(al, bhf, acc[nt], 0, 0, 0);
    }
  }
#pragma unroll
  for (int nt = 0; nt < 4; ++nt) {
    int o = ob0 + nt * 16 + lm;
    float bias = ob[o];
    float4 v;
    v.x = acc[nt][0] + bias;
    v.y = acc[nt][1] + bias;
    v.z = acc[nt][2] + bias;
    v.w = acc[nt][3] + bias;
    *(float4*)(out + ((size_t)(b * 256 + o)) * NPX + pb + lg * 4) = v;
  }
}

// ---------------------------------------------------------------------------
extern "C" void kernel_launch(void* const* d_in, const int* in_sizes, int n_in,
                              void* d_out, int out_size, void* d_ws, size_t ws_size,
                              hipStream_t stream) {
  const float* x      = (const float*)d_in[0];
  const float* q_w    = (const float*)d_in[1];
  const float* k_w    = (const float*)d_in[2];
  const float* v_w    = (const float*)d_in[3];
  const float* out_w  = (const float*)d_in[4];
  const float* out_b  = (const float*)d_in[5];
  const float* off_w1 = (const float*)d_in[6];
  const float* off_b1 = (const float*)d_in[7];
  const float* off_w2 = (const float*)d_in[8];
  const float* cpb_w1 = (const float*)d_in[9];
  const float* cpb_b1 = (const float*)d_in[10];
  const float* cpb_w2 = (const float*)d_in[11];
  const float* cpb_b2 = (const float*)d_in[12];
  const float* cpb_w3 = (const float*)d_in[13];
  const float* cpb_b3 = (const float*)d_in[14];
  float* out = (float*)d_out;

  float* ws  = (float*)d_ws;
  float* q   = ws;                         // 1048576 f; REUSED as aoh/aol by k_attn
  unsigned short* aoh = (unsigned short*)q;        // 2048*512 shorts (2 MB)
  unsigned short* aol = aoh + 2048 * 512;          // 2048*512 shorts (2 MB) — fits q exactly
  float* qT  = ws + 1048576;               // 1048576 f
  float* kh  = qT + 1048576;               // 65536 f
  float* vh  = kh + 65536;                 // 65536 f
  float* gkv = vh + 65536;                 // 2048 f
  unsigned short* whP = (unsigned short*)(gkv + 2048);  // 131072 shorts
  unsigned short* wlP = whP + 131072;                   // 131072 shorts
  // total ~2.36M float-slots = 9.5 MB (< previous 13.1 MB footprint)

  k_prep_w<<<512, 256, 0, stream>>>(out_w, whP, wlP);
  k_qconv<<<256, 256, 0, stream>>>(x, q_w, q, qT);
  k_offset<<<16, 256, 0, stream>>>(q, off_w1, off_b1, off_w2, gkv);
  k_sample_kv<<<16, 256, 0, stream>>>(x, k_w, v_w, gkv, kh, vh);
  k_attn<<<dim3(64, 16), 256, 0, stream>>>(qT, kh, vh, gkv, cpb_w1, cpb_b1,
                                           cpb_w2, cpb_b2, cpb_w3, cpb_b3,
                                           aoh, aol);
  k_proj_mfma<<<128, 256, 0, stream>>>(aoh, aol, whP, wlP, out_b, out);
}

// Round 8
// 122.092 us; speedup vs baseline: 6.4563x; 1.1199x over previous
//
#include <hip/hip_runtime.h>
#include <math.h>

#define NPX 1024  // H*W = 32*32

using bf16x8 = __attribute__((ext_vector_type(8))) short;  // 8 bf16 in 4 VGPRs
using f32x4  = __attribute__((ext_vector_type(4))) float;

__device__ __forceinline__ float slog1p(float p) {
  return copysignf(log1pf(fabsf(p)), p);
}

__device__ __forceinline__ unsigned short f2bf(float f) {
  unsigned u = __builtin_bit_cast(unsigned, f);
  unsigned r = (u + 0x7FFFu + ((u >> 16) & 1u)) >> 16;  // RNE
  return (unsigned short)r;
}
__device__ __forceinline__ float bf2f(unsigned short h) {
  return __builtin_bit_cast(float, (unsigned)h << 16);
}

// ---------------------------------------------------------------------------
// K0: pack out_w into MFMA-fragment-major bf16 hi/lo (blocks 0..511) and
// cpb_w2 into fragment-major bf16 (block 512).
// w2P[((lg*16+lm)*8 + c2t*2+s)*8 + r] = bf16(w2[(c2t*16+lm)*64 + s*32+lg*8+r])
// ---------------------------------------------------------------------------
__global__ __launch_bounds__(256) void k_prep_w(const float* __restrict__ ow,
                                                const float* __restrict__ w2g,
                                                unsigned short* __restrict__ whP,
                                                unsigned short* __restrict__ wlP,
                                                unsigned short* __restrict__ w2P) {
  if (blockIdx.x < 512) {
    int idx = blockIdx.x * 256 + threadIdx.x;  // 0..131071
    int o = idx >> 9, c = idx & 511;
    float v = ow[(size_t)o * 512 + c];
    unsigned short hi = f2bf(v);
    unsigned short lo = f2bf(v - bf2f(hi));
    int kt = c >> 5, lg = (c >> 3) & 3, r = c & 7;
    size_t dst = ((size_t)(kt * 4 + lg) * 256 + o) * 8 + r;
    whP[dst] = hi;
    wlP[dst] = lo;
  } else {
    for (int e = threadIdx.x; e < 4096; e += 256) {
      int r = e & 7;
      int f = (e >> 3) & 7;        // c2t*2+s
      int c2t = f >> 1, s = f & 1;
      int lane = e >> 6;           // lg*16+lm
      int lm = lane & 15, lg = lane >> 4;
      int c2 = c2t * 16 + lm, c = s * 32 + lg * 8 + r;
      w2P[e] = f2bf(w2g[c2 * 64 + c]);
    }
  }
}

// ---------------------------------------------------------------------------
// K1: grouped 1x1 conv  q = x * q_w ; also qT = q*0.125 in (bh,i,d) layout
// ---------------------------------------------------------------------------
__global__ __launch_bounds__(256) void k_qconv(const float* __restrict__ x,
                                               const float* __restrict__ qw,
                                               float* __restrict__ q,
                                               float* __restrict__ qT) {
  const int blk = blockIdx.x;
  const int bg  = blk >> 4;
  const int px0 = (blk & 15) << 6;
  const int g   = bg & 7;
  const int b   = bg >> 3;
  const int tid = threadIdx.x;
  __shared__ float xs[32 * 64];
  __shared__ float wsh[64 * 32];
  __shared__ float ot[64 * 65];

  const float* xb = x + ((size_t)(b * 256 + g * 32)) * NPX + px0;
  for (int idx = tid; idx < 32 * 64; idx += 256) {
    int c = idx >> 6, p = idx & 63;
    xs[idx] = xb[(size_t)c * NPX + p];
  }
  const float* wb = qw + g * 64 * 32;
  for (int idx = tid; idx < 64 * 32; idx += 256) wsh[idx] = wb[idx];
  __syncthreads();

  for (int idx = tid; idx < 64 * 64; idx += 256) {
    int o = idx >> 6, p = idx & 63;
    float a0 = 0.f, a1 = 0.f;
#pragma unroll
    for (int c = 0; c < 32; c += 2) {
      a0 = fmaf(wsh[o * 32 + c],     xs[c * 64 + p],       a0);
      a1 = fmaf(wsh[o * 32 + c + 1], xs[(c + 1) * 64 + p], a1);
    }
    float acc = a0 + a1;
    q[((size_t)(bg * 64 + o)) * NPX + px0 + p] = acc;
    ot[o * 65 + p] = acc * 0.125f;
  }
  __syncthreads();
  float* qTb = qT + ((size_t)bg * NPX + px0) * 64;
  for (int idx = tid; idx < 64 * 64; idx += 256) {
    int p = idx >> 6, o = idx & 63;
    qTb[p * 64 + o] = ot[o * 65 + p];
  }
}

// ---------------------------------------------------------------------------
// K2+K3 merged: offset net -> gkv, then bilinear grid_sample + k/v convs.
// grid: 16 blocks (one per bg), 256 thr
// ---------------------------------------------------------------------------
__global__ __launch_bounds__(256) void k_offset_sample(
    const float* __restrict__ q, const float* __restrict__ w1,
    const float* __restrict__ b1, const float* __restrict__ w2,
    const float* __restrict__ x, const float* __restrict__ kw,
    const float* __restrict__ vw, float* __restrict__ gkv,
    float* __restrict__ kh, float* __restrict__ vh) {
  const int bg = blockIdx.x;
  const int g  = bg & 7;
  const int tid = threadIdx.x;
  __shared__ float ge[64 * 64];
  __shared__ float w1s[64 * 36];
  __shared__ float b1s[64];
  __shared__ float kws[64 * 33];
  __shared__ float vws[64 * 33];
  __shared__ float xs_[64], ys_[64];

  for (int idx = tid; idx < 64 * 36; idx += 256) w1s[idx] = w1[idx];
  if (tid < 64) b1s[tid] = b1[tid];
  for (int idx = tid; idx < 2048; idx += 256) {
    int o = idx >> 5, c = idx & 31;
    kws[o * 33 + c] = kw[(g * 64 + o) * 32 + c];
    vws[o * 33 + c] = vw[(g * 64 + o) * 32 + c];
  }
  __syncthreads();

  const float* qb = q + (size_t)bg * 64 * NPX;
  for (int idx = tid; idx < 4096; idx += 256) {
    int c = idx >> 6, px = idx & 63;
    int oy = px >> 3, ox = px & 7;
    const float* qc = qb + (size_t)c * NPX;
    float acc = 0.f;
#pragma unroll
    for (int ky = 0; ky < 6; ++ky) {
      int yy = oy * 4 - 1 + ky;
      if (yy < 0 || yy >= 32) continue;
#pragma unroll
      for (int kx = 0; kx < 6; ++kx) {
        int xx = ox * 4 - 1 + kx;
        if (xx < 0 || xx >= 32) continue;
        acc = fmaf(w1s[c * 36 + ky * 6 + kx], qc[yy * 32 + xx], acc);
      }
    }
    acc += b1s[c];
    ge[c * 64 + px] = 0.5f * acc * (1.f + erff(acc * 0.70710678118654752440f));
  }
  __syncthreads();

  if (tid < 64) {
    int px = tid;
    float s0 = 0.f, s1 = 0.f;
    for (int c = 0; c < 64; ++c) {
      float gv = ge[c * 64 + px];
      s0 = fmaf(w2[c],      gv, s0);
      s1 = fmaf(w2[64 + c], gv, s1);
    }
    float o0 = tanhf(s0) * 4.f;
    float o1 = tanhf(s1) * 4.f;
    int oy = px >> 3, ox = px & 7;
    float g0 = 2.f * ((float)ox + o0) / 7.f - 1.f;
    float g1 = 2.f * ((float)oy + o1) / 7.f - 1.f;
    gkv[(bg * 64 + px) * 2 + 0] = g0;
    gkv[(bg * 64 + px) * 2 + 1] = g1;
    xs_[px] = (g0 + 1.f) * 16.f - 0.5f;
    ys_[px] = (g1 + 1.f) * 16.f - 0.5f;
  }
  __syncthreads();

  float* smp = ge;  // ge dead now
  const float* imgb = x + (size_t)bg * 32 * NPX;
  for (int idx = tid; idx < 2048; idx += 256) {
    int c = idx >> 6, j = idx & 63;
    float xx = xs_[j], yy = ys_[j];
    float x0f = floorf(xx), y0f = floorf(yy);
    int x0 = (int)x0f, y0 = (int)y0f;
    float wx1 = xx - x0f, wy1 = yy - y0f;
    float wx0 = 1.f - wx1, wy0 = 1.f - wy1;
    int x1 = x0 + 1, y1 = y0 + 1;
    bool vx0 = (x0 >= 0) & (x0 < 32), vx1 = (x1 >= 0) & (x1 < 32);
    bool vy0 = (y0 >= 0) & (y0 < 32), vy1 = (y1 >= 0) & (y1 < 32);
    int cx0 = min(max(x0, 0), 31), cx1 = min(max(x1, 0), 31);
    int cy0 = min(max(y0, 0), 31), cy1 = min(max(y1, 0), 31);
    const float* img = imgb + (size_t)c * NPX;
    float v00 = (vy0 && vx0) ? img[cy0 * 32 + cx0] : 0.f;
    float v01 = (vy0 && vx1) ? img[cy0 * 32 + cx1] : 0.f;
    float v10 = (vy1 && vx0) ? img[cy1 * 32 + cx0] : 0.f;
    float v11 = (vy1 && vx1) ? img[cy1 * 32 + cx1] : 0.f;
    smp[c * 64 + j] = v00 * wy0 * wx0 + v01 * wy0 * wx1 +
                      v10 * wy1 * wx0 + v11 * wy1 * wx1;
  }
  __syncthreads();

  for (int idx = tid; idx < 4096; idx += 256) {
    int j = idx >> 6, o = idx & 63;
    float ak0 = 0.f, ak1 = 0.f, av0 = 0.f, av1 = 0.f;
#pragma unroll
    for (int c = 0; c < 32; c += 2) {
      float s0 = smp[c * 64 + j], s1 = smp[(c + 1) * 64 + j];
      ak0 = fmaf(kws[o * 33 + c],     s0, ak0);
      ak1 = fmaf(kws[o * 33 + c + 1], s1, ak1);
      av0 = fmaf(vws[o * 33 + c],     s0, av0);
      av1 = fmaf(vws[o * 33 + c + 1], s1, av1);
    }
    kh[((size_t)bg * 64 + j) * 64 + o] = ak0 + ak1;
    vh[((size_t)bg * 64 + j) * 64 + o] = av0 + av1;
  }
}

// ---------------------------------------------------------------------------
// K4: fused CPB-MLP + QK^T + softmax + PV, all MFMA; minimal LDS (~10 KB).
// grid: (64 tiles, 16 bh), 256 thr = 4 waves; wave w owns j-cols [16w,16w+16)
// for CPB/QK and d-cols [16w,16w+16) for PV.
// ---------------------------------------------------------------------------
__global__ __launch_bounds__(256) void k_attn(
    const float* __restrict__ qT, const float* __restrict__ kh,
    const float* __restrict__ vh, const float* __restrict__ gkv,
    const float* __restrict__ w1, const float* __restrict__ b1,
    const unsigned short* __restrict__ w2P, const float* __restrict__ b2,
    const float* __restrict__ w3, const float* __restrict__ b3,
    unsigned short* __restrict__ aoh, unsigned short* __restrict__ aol) {
  const int it  = blockIdx.x;     // 0..63
  const int bh  = blockIdx.y;     // 0..15
  const int i0  = it << 4;
  const int iy  = i0 >> 5;
  const int ixb = i0 & 31;
  const int tid = threadIdx.x;

  __shared__ float utab[16 * 65];
  __shared__ float vtab[64];
  __shared__ float w1xs[64], w1ys[64], b1s[64], b2s[64], w3s[64];
  __shared__ float sim[16 * 65];

  const int w  = tid >> 6;   // wave 0..3
  const int l  = tid & 63;
  const int lm = l & 15;
  const int lg = l >> 4;
  const int jb = w * 16;

  // --- W2 fragments: 8x coalesced 16B loads from packed global ---
  bf16x8 bw2[4][2];
  {
    const unsigned short* wp = w2P + (lg * 16 + lm) * 64;
#pragma unroll
    for (int c2t = 0; c2t < 4; ++c2t)
#pragma unroll
      for (int s = 0; s < 2; ++s)
        bw2[c2t][s] = *(const bf16x8*)(wp + (c2t * 2 + s) * 8);
  }
  // --- V B-fragments (hi/lo split), built once from global (L2-resident) ---
  bf16x8 bvh[2], bvl[2];
  {
    const float* vb = vh + (size_t)bh * 64 * 64 + jb + lm;
#pragma unroll
    for (int s = 0; s < 2; ++s)
#pragma unroll
      for (int r = 0; r < 8; ++r) {
        float v = vb[(size_t)(s * 32 + lg * 8 + r) * 64];
        unsigned short hi = f2bf(v);
        bvh[s][r] = (short)hi;
        bvl[s][r] = (short)f2bf(v - bf2f(hi));
      }
  }

  // --- stage utab/vtab/params (only cross-thread data in LDS) ---
  for (int idx = tid; idx < 1024; idx += 256) {
    int il = idx >> 6, j = idx & 63;
    float kxv = gkv[(bh * 64 + j) * 2];
    float qxn = (2.f / 31.f) * (float)(ixb + il) - 1.f;
    utab[il * 65 + j] = slog1p(qxn - kxv);
  }
  if (tid < 64) {
    w1xs[tid] = w1[tid * 2];
    w1ys[tid] = w1[tid * 2 + 1];
    b1s[tid]  = b1[tid];
    b2s[tid]  = b2[tid];
    w3s[tid]  = w3[tid];
    float kyv = gkv[(bh * 64 + tid) * 2 + 1];
    float qyn = (2.f / 31.f) * (float)iy - 1.f;
    vtab[tid] = slog1p(qyn - kyv);
  }
  __syncthreads();

  // --- hoisted il-invariant layer-1 terms ---
  float w1v[16], tc[16];
  {
    float vvj = vtab[jb + lm];
#pragma unroll
    for (int s = 0; s < 2; ++s)
#pragma unroll
      for (int r = 0; r < 8; ++r) {
        int c = s * 32 + lg * 8 + r;
        w1v[s * 8 + r] = w1xs[c];
        tc[s * 8 + r]  = fmaf(w1ys[c], vvj, b1s[c]);
      }
  }
  float b2v[4], w3v[4];
#pragma unroll
  for (int c2t = 0; c2t < 4; ++c2t) {
    b2v[c2t] = b2s[c2t * 16 + lm];
    w3v[c2t] = w3s[c2t * 16 + lm];
  }
  const float b3v = b3[0];

  // --- CPB pass: per il, wave computes cb for its 16 j ---
#pragma unroll 1
  for (int il = 0; il < 16; ++il) {
    float u = utab[il * 65 + jb + lm];
    bf16x8 af[2];
#pragma unroll
    for (int s = 0; s < 2; ++s)
#pragma unroll
      for (int r = 0; r < 8; ++r)
        af[s][r] = (short)f2bf(fmaxf(fmaf(w1v[s * 8 + r], u, tc[s * 8 + r]), 0.f));
    f32x4 acc[4];
#pragma unroll
    for (int c2t = 0; c2t < 4; ++c2t) {
      acc[c2t] = (f32x4){0.f, 0.f, 0.f, 0.f};
      acc[c2t] = __builtin_amdgcn_mfma_f32_16x16x32_bf16(af[0], bw2[c2t][0], acc[c2t], 0, 0, 0);
      acc[c2t] = __builtin_amdgcn_mfma_f32_16x16x32_bf16(af[1], bw2[c2t][1], acc[c2t], 0, 0, 0);
    }
    float sres[4];
#pragma unroll
    for (int r = 0; r < 4; ++r) {
      float t0 = fmaxf(acc[0][r] + b2v[0], 0.f) * w3v[0];
      t0 = fmaf(fmaxf(acc[1][r] + b2v[1], 0.f), w3v[1], t0);
      t0 = fmaf(fmaxf(acc[2][r] + b2v[2], 0.f), w3v[2], t0);
      t0 = fmaf(fmaxf(acc[3][r] + b2v[3], 0.f), w3v[3], t0);
      sres[r] = t0;
    }
#pragma unroll
    for (int r = 0; r < 4; ++r) {
      sres[r] += __shfl_xor(sres[r], 1);
      sres[r] += __shfl_xor(sres[r], 2);
      sres[r] += __shfl_xor(sres[r], 4);
      sres[r] += __shfl_xor(sres[r], 8);
    }
    if (lm == 0) {
#pragma unroll
      for (int r = 0; r < 4; ++r)
        sim[il * 65 + jb + lg * 4 + r] = sres[r] + b3v;
    }
  }

  // --- QK pass: fragments straight from global (L2), add into sim ---
  {
    bf16x8 aq[2], bk[2];
    const float* qb = qT + ((size_t)bh * NPX + i0 + lm) * 64;
    const float* kb = kh + ((size_t)(bh * 64 + jb + lm)) * 64;
#pragma unroll
    for (int s = 0; s < 2; ++s) {
      float4 q0 = *(const float4*)(qb + s * 32 + lg * 8);
      float4 q1 = *(const float4*)(qb + s * 32 + lg * 8 + 4);
      float4 k0 = *(const float4*)(kb + s * 32 + lg * 8);
      float4 k1 = *(const float4*)(kb + s * 32 + lg * 8 + 4);
      aq[s][0] = (short)f2bf(q0.x); aq[s][1] = (short)f2bf(q0.y);
      aq[s][2] = (short)f2bf(q0.z); aq[s][3] = (short)f2bf(q0.w);
      aq[s][4] = (short)f2bf(q1.x); aq[s][5] = (short)f2bf(q1.y);
      aq[s][6] = (short)f2bf(q1.z); aq[s][7] = (short)f2bf(q1.w);
      bk[s][0] = (short)f2bf(k0.x); bk[s][1] = (short)f2bf(k0.y);
      bk[s][2] = (short)f2bf(k0.z); bk[s][3] = (short)f2bf(k0.w);
      bk[s][4] = (short)f2bf(k1.x); bk[s][5] = (short)f2bf(k1.y);
      bk[s][6] = (short)f2bf(k1.z); bk[s][7] = (short)f2bf(k1.w);
    }
    f32x4 qacc = (f32x4){0.f, 0.f, 0.f, 0.f};
    qacc = __builtin_amdgcn_mfma_f32_16x16x32_bf16(aq[0], bk[0], qacc, 0, 0, 0);
    qacc = __builtin_amdgcn_mfma_f32_16x16x32_bf16(aq[1], bk[1], qacc, 0, 0, 0);
#pragma unroll
    for (int r = 0; r < 4; ++r)
      sim[(lg * 4 + r) * 65 + jb + lm] += qacc[r];
  }
  __syncthreads();

  // --- softmax: 16 threads per row of 64 ---
  {
    int r = tid >> 4, sl = tid & 15;
    float sv[4];
    float m = -1e30f;
#pragma unroll
    for (int t = 0; t < 4; ++t) {
      sv[t] = sim[r * 65 + sl + (t << 4)];
      m = fmaxf(m, sv[t]);
    }
#pragma unroll
    for (int off = 8; off > 0; off >>= 1) m = fmaxf(m, __shfl_xor(m, off, 16));
    float ssum = 0.f;
#pragma unroll
    for (int t = 0; t < 4; ++t) { sv[t] = expf(sv[t] - m); ssum += sv[t]; }
#pragma unroll
    for (int off = 8; off > 0; off >>= 1) ssum += __shfl_xor(ssum, off, 16);
    float inv = 1.f / ssum;
#pragma unroll
    for (int t = 0; t < 4; ++t) sim[r * 65 + sl + (t << 4)] = sv[t] * inv;
  }
  __syncthreads();

  // --- PV via MFMA (P bf16 x V hi/lo), direct hi/lo epilogue ---
  {
    bf16x8 ap[2];
#pragma unroll
    for (int s = 0; s < 2; ++s)
#pragma unroll
      for (int r = 0; r < 8; ++r)
        ap[s][r] = (short)f2bf(sim[lm * 65 + s * 32 + lg * 8 + r]);
    f32x4 po = (f32x4){0.f, 0.f, 0.f, 0.f};
    po = __builtin_amdgcn_mfma_f32_16x16x32_bf16(ap[0], bvh[0], po, 0, 0, 0);
    po = __builtin_amdgcn_mfma_f32_16x16x32_bf16(ap[1], bvh[1], po, 0, 0, 0);
    po = __builtin_amdgcn_mfma_f32_16x16x32_bf16(ap[0], bvl[0], po, 0, 0, 0);
    po = __builtin_amdgcn_mfma_f32_16x16x32_bf16(ap[1], bvl[1], po, 0, 0, 0);
    const int b = bh >> 3, h = bh & 7;
    size_t base = ((size_t)(b * 1024 + i0 + lg * 4)) * 512 + h * 64 + jb + lm;
#pragma unroll
    for (int r = 0; r < 4; ++r) {
      float v = po[r];
      unsigned short hi = f2bf(v);
      aoh[base + (size_t)r * 512] = hi;
      aol[base + (size_t)r * 512] = f2bf(v - bf2f(hi));
    }
  }
}

// ---------------------------------------------------------------------------
// K5: projection as split-bf16 MFMA GEMM (unchanged)
// ---------------------------------------------------------------------------
__global__ __launch_bounds__(256) void k_proj_mfma(
    const unsigned short* __restrict__ aoh, const unsigned short* __restrict__ aol,
    const unsigned short* __restrict__ whP, const unsigned short* __restrict__ wlP,
    const float* __restrict__ ob, float* __restrict__ out) {
  const int p0 = blockIdx.x << 4;
  const int b  = p0 >> 10;
  const int pb = p0 & 1023;
  const int w  = threadIdx.x >> 6;
  const int l  = threadIdx.x & 63;
  const int lm = l & 15, lg = l >> 4;

  f32x4 acc[4];
#pragma unroll
  for (int nt = 0; nt < 4; ++nt) acc[nt] = (f32x4){0.f, 0.f, 0.f, 0.f};

  const unsigned short* arh = aoh + ((size_t)(p0 + lm)) * 512 + lg * 8;
  const unsigned short* arl = aol + ((size_t)(p0 + lm)) * 512 + lg * 8;
  const int ob0 = w * 64;

#pragma unroll 4
  for (int kt = 0; kt < 16; ++kt) {
    bf16x8 ah = *(const bf16x8*)(arh + kt * 32);
    bf16x8 al = *(const bf16x8*)(arl + kt * 32);
    const size_t wb = ((size_t)(kt * 4 + lg) * 256 + ob0 + lm) * 8;
#pragma unroll
    for (int nt = 0; nt < 4; ++nt) {
      bf16x8 bhf = *(const bf16x8*)(whP + wb + nt * 128);
      bf16x8 blf = *(const bf16x8*)(wlP + wb + nt * 128);
      acc[nt] = __builtin_amdgcn_mfma_f32_16x16x32_bf16(ah, bhf, acc[nt], 0, 0, 0);
      acc[nt] = __builtin_amdgcn_mfma_f32_16x16x32_bf16(ah, blf, acc[nt], 0, 0, 0);
      acc[nt] = __builtin_amdgcn_mfma_f32_16x16x32_bf16(al, bhf, acc[nt], 0, 0, 0);
    }
  }
#pragma unroll
  for (int nt = 0; nt < 4; ++nt) {
    int o = ob0 + nt * 16 + lm;
    float bias = ob[o];
    float4 v;
    v.x = acc[nt][0] + bias;
    v.y = acc[nt][1] + bias;
    v.z = acc[nt][2] + bias;
    v.w = acc[nt][3] + bias;
    *(float4*)(out + ((size_t)(b * 256 + o)) * NPX + pb + lg * 4) = v;
  }
}

// ---------------------------------------------------------------------------
extern "C" void kernel_launch(void* const* d_in, const int* in_sizes, int n_in,
                              void* d_out, int out_size, void* d_ws, size_t ws_size,
                              hipStream_t stream) {
  const float* x      = (const float*)d_in[0];
  const float* q_w    = (const float*)d_in[1];
  const float* k_w    = (const float*)d_in[2];
  const float* v_w    = (const float*)d_in[3];
  const float* out_w  = (const float*)d_in[4];
  const float* out_b  = (const float*)d_in[5];
  const float* off_w1 = (const float*)d_in[6];
  const float* off_b1 = (const float*)d_in[7];
  const float* off_w2 = (const float*)d_in[8];
  const float* cpb_w1 = (const float*)d_in[9];
  const float* cpb_b1 = (const float*)d_in[10];
  const float* cpb_w2 = (const float*)d_in[11];
  const float* cpb_b2 = (const float*)d_in[12];
  const float* cpb_w3 = (const float*)d_in[13];
  const float* cpb_b3 = (const float*)d_in[14];
  float* out = (float*)d_out;

  float* ws  = (float*)d_ws;
  float* q   = ws;                          // 1048576 f; reused as aoh/aol
  unsigned short* aoh = (unsigned short*)q; // 2048*512 shorts
  unsigned short* aol = aoh + 2048 * 512;   // 2048*512 shorts
  float* qT  = ws + 1048576;                // 1048576 f
  float* kh  = qT + 1048576;                // 65536 f
  float* vh  = kh + 65536;                  // 65536 f
  float* gkv = vh + 65536;                  // 2048 f
  unsigned short* whP = (unsigned short*)(gkv + 2048);  // 131072 shorts
  unsigned short* wlP = whP + 131072;                   // 131072 shorts
  unsigned short* w2P = wlP + 131072;                   // 4096 shorts

  k_prep_w<<<513, 256, 0, stream>>>(out_w, cpb_w2, whP, wlP, w2P);
  k_qconv<<<256, 256, 0, stream>>>(x, q_w, q, qT);
  k_offset_sample<<<16, 256, 0, stream>>>(q, off_w1, off_b1, off_w2,
                                          x, k_w, v_w, gkv, kh, vh);
  k_attn<<<dim3(64, 16), 256, 0, stream>>>(qT, kh, vh, gkv, cpb_w1, cpb_b1,
                                           w2P, cpb_b2, cpb_w3, cpb_b3,
                                           aoh, aol);
  k_proj_mfma<<<128, 256, 0, stream>>>(aoh, aol, whP, wlP, out_b, out);
}

// Round 9
// 88.733 us; speedup vs baseline: 8.8836x; 1.3760x over previous
//
#include <hip/hip_runtime.h>
#include <math.h>

#define NPX 1024  // H*W = 32*32

using bf16x8 = __attribute__((ext_vector_type(8))) short;  // 8 bf16 in 4 VGPRs
using f32x4  = __attribute__((ext_vector_type(4))) float;

__device__ __forceinline__ float slog1p(float p) {
  return copysignf(log1pf(fabsf(p)), p);
}

__device__ __forceinline__ unsigned short f2bf(float f) {
  unsigned u = __builtin_bit_cast(unsigned, f);
  unsigned r = (u + 0x7FFFu + ((u >> 16) & 1u)) >> 16;  // RNE
  return (unsigned short)r;
}
__device__ __forceinline__ float bf2f(unsigned short h) {
  return __builtin_bit_cast(float, (unsigned)h << 16);
}

// ---------------------------------------------------------------------------
// K0: pack out_w into MFMA-fragment-major bf16 hi/lo (blocks 0..511) and
// cpb_w2 into fragment-major bf16 (block 512).
// ---------------------------------------------------------------------------
__global__ __launch_bounds__(256) void k_prep_w(const float* __restrict__ ow,
                                                const float* __restrict__ w2g,
                                                unsigned short* __restrict__ whP,
                                                unsigned short* __restrict__ wlP,
                                                unsigned short* __restrict__ w2P) {
  if (blockIdx.x < 512) {
    int idx = blockIdx.x * 256 + threadIdx.x;  // 0..131071
    int o = idx >> 9, c = idx & 511;
    float v = ow[(size_t)o * 512 + c];
    unsigned short hi = f2bf(v);
    unsigned short lo = f2bf(v - bf2f(hi));
    int kt = c >> 5, lg = (c >> 3) & 3, r = c & 7;
    size_t dst = ((size_t)(kt * 4 + lg) * 256 + o) * 8 + r;
    whP[dst] = hi;
    wlP[dst] = lo;
  } else {
    for (int e = threadIdx.x; e < 4096; e += 256) {
      int r = e & 7;
      int f = (e >> 3) & 7;        // c2t*2+s
      int c2t = f >> 1, s = f & 1;
      int lane = e >> 6;           // lg*16+lm
      int lm = lane & 15, lg = lane >> 4;
      int c2 = c2t * 16 + lm, c = s * 32 + lg * 8 + r;
      w2P[e] = f2bf(w2g[c2 * 64 + c]);
    }
  }
}

// ---------------------------------------------------------------------------
// K1: grouped 1x1 conv  q = x * q_w ; also qT = q*0.125 in (bh,i,d) layout
// ---------------------------------------------------------------------------
__global__ __launch_bounds__(256) void k_qconv(const float* __restrict__ x,
                                               const float* __restrict__ qw,
                                               float* __restrict__ q,
                                               float* __restrict__ qT) {
  const int blk = blockIdx.x;
  const int bg  = blk >> 4;
  const int px0 = (blk & 15) << 6;
  const int g   = bg & 7;
  const int b   = bg >> 3;
  const int tid = threadIdx.x;
  __shared__ float xs[32 * 64];
  __shared__ float wsh[64 * 32];
  __shared__ float ot[64 * 65];

  const float* xb = x + ((size_t)(b * 256 + g * 32)) * NPX + px0;
  for (int idx = tid; idx < 32 * 64; idx += 256) {
    int c = idx >> 6, p = idx & 63;
    xs[idx] = xb[(size_t)c * NPX + p];
  }
  const float* wb = qw + g * 64 * 32;
  for (int idx = tid; idx < 64 * 32; idx += 256) wsh[idx] = wb[idx];
  __syncthreads();

  for (int idx = tid; idx < 64 * 64; idx += 256) {
    int o = idx >> 6, p = idx & 63;
    float a0 = 0.f, a1 = 0.f;
#pragma unroll
    for (int c = 0; c < 32; c += 2) {
      a0 = fmaf(wsh[o * 32 + c],     xs[c * 64 + p],       a0);
      a1 = fmaf(wsh[o * 32 + c + 1], xs[(c + 1) * 64 + p], a1);
    }
    float acc = a0 + a1;
    q[((size_t)(bg * 64 + o)) * NPX + px0 + p] = acc;
    ot[o * 65 + p] = acc * 0.125f;
  }
  __syncthreads();
  float* qTb = qT + ((size_t)bg * NPX + px0) * 64;
  for (int idx = tid; idx < 64 * 64; idx += 256) {
    int p = idx >> 6, o = idx & 63;
    qTb[p * 64 + o] = ot[o * 65 + p];
  }
}

// ---------------------------------------------------------------------------
// K2+K3: offset net + grid_sample + k/v convs, partitioned over px.
// Everything is per-px independent except the c-reduction in the 1x1 (block
// local, 16-lane shfl). grid: (4 px-chunks of 16, 16 bg), 256 thr.
// ---------------------------------------------------------------------------
__global__ __launch_bounds__(256) void k_offset_sample(
    const float* __restrict__ q, const float* __restrict__ w1,
    const float* __restrict__ b1, const float* __restrict__ w2,
    const float* __restrict__ x, const float* __restrict__ kw,
    const float* __restrict__ vw, float* __restrict__ gkv,
    float* __restrict__ kh, float* __restrict__ vh) {
  const int px0 = blockIdx.x << 4;   // 0,16,32,48
  const int bg  = blockIdx.y;
  const int g   = bg & 7;
  const int tid = threadIdx.x;
  __shared__ float ge[64 * 17];      // [c][lp] gelu outs, padded
  __shared__ float w1s[64 * 36];
  __shared__ float b1s[64];
  __shared__ float kws[64 * 33];
  __shared__ float vws[64 * 33];
  __shared__ float smp[32 * 17];     // [c][lj] sampled, padded
  __shared__ float xs_[16], ys_[16];

  for (int idx = tid; idx < 64 * 36; idx += 256) w1s[idx] = w1[idx];
  if (tid < 64) b1s[tid] = b1[tid];
  for (int idx = tid; idx < 2048; idx += 256) {
    int o = idx >> 5, c = idx & 31;
    kws[o * 33 + c] = kw[(g * 64 + o) * 32 + c];
    vws[o * 33 + c] = vw[(g * 64 + o) * 32 + c];
  }
  __syncthreads();

  // depthwise 6x6 s4 + bias + exact GELU: 64 c x 16 px, 4 per thread
  const float* qb = q + (size_t)bg * 64 * NPX;
  for (int idx = tid; idx < 1024; idx += 256) {
    int c = idx >> 4, lp = idx & 15;
    int px = px0 + lp;
    int oy = px >> 3, ox = px & 7;
    const float* qc = qb + (size_t)c * NPX;
    float acc = 0.f;
#pragma unroll
    for (int ky = 0; ky < 6; ++ky) {
      int yy = oy * 4 - 1 + ky;
      if (yy < 0 || yy >= 32) continue;
#pragma unroll
      for (int kx = 0; kx < 6; ++kx) {
        int xx = ox * 4 - 1 + kx;
        if (xx < 0 || xx >= 32) continue;
        acc = fmaf(w1s[c * 36 + ky * 6 + kx], qc[yy * 32 + xx], acc);
      }
    }
    acc += b1s[c];
    ge[c * 17 + lp] = 0.5f * acc * (1.f + erff(acc * 0.70710678118654752440f));
  }
  __syncthreads();

  // 1x1 (64->2): 16 lanes per px, 4 channels each, shfl-reduce width 16
  {
    int lp = tid >> 4, sl = tid & 15;
    float s0 = 0.f, s1 = 0.f;
#pragma unroll
    for (int k = 0; k < 4; ++k) {
      int c = sl + k * 16;
      float gv = ge[c * 17 + lp];
      s0 = fmaf(w2[c],      gv, s0);
      s1 = fmaf(w2[64 + c], gv, s1);
    }
#pragma unroll
    for (int off = 8; off > 0; off >>= 1) {
      s0 += __shfl_xor(s0, off, 16);
      s1 += __shfl_xor(s1, off, 16);
    }
    if (sl == 0) {
      float o0 = tanhf(s0) * 4.f;
      float o1 = tanhf(s1) * 4.f;
      int px = px0 + lp;
      int oy = px >> 3, ox = px & 7;
      float g0 = 2.f * ((float)ox + o0) / 7.f - 1.f;
      float g1 = 2.f * ((float)oy + o1) / 7.f - 1.f;
      gkv[(bg * 64 + px) * 2 + 0] = g0;
      gkv[(bg * 64 + px) * 2 + 1] = g1;
      xs_[lp] = (g0 + 1.f) * 16.f - 0.5f;
      ys_[lp] = (g1 + 1.f) * 16.f - 0.5f;
    }
  }
  __syncthreads();

  // bilinear sample: 32 c x 16 j
  const float* imgb = x + (size_t)bg * 32 * NPX;
  for (int idx = tid; idx < 512; idx += 256) {
    int c = idx >> 4, lj = idx & 15;
    float xx = xs_[lj], yy = ys_[lj];
    float x0f = floorf(xx), y0f = floorf(yy);
    int x0 = (int)x0f, y0 = (int)y0f;
    float wx1 = xx - x0f, wy1 = yy - y0f;
    float wx0 = 1.f - wx1, wy0 = 1.f - wy1;
    int x1 = x0 + 1, y1 = y0 + 1;
    bool vx0 = (x0 >= 0) & (x0 < 32), vx1 = (x1 >= 0) & (x1 < 32);
    bool vy0 = (y0 >= 0) & (y0 < 32), vy1 = (y1 >= 0) & (y1 < 32);
    int cx0 = min(max(x0, 0), 31), cx1 = min(max(x1, 0), 31);
    int cy0 = min(max(y0, 0), 31), cy1 = min(max(y1, 0), 31);
    const float* img = imgb + (size_t)c * NPX;
    float v00 = (vy0 && vx0) ? img[cy0 * 32 + cx0] : 0.f;
    float v01 = (vy0 && vx1) ? img[cy0 * 32 + cx1] : 0.f;
    float v10 = (vy1 && vx0) ? img[cy1 * 32 + cx0] : 0.f;
    float v11 = (vy1 && vx1) ? img[cy1 * 32 + cx1] : 0.f;
    smp[c * 17 + lj] = v00 * wy0 * wx0 + v01 * wy0 * wx1 +
                       v10 * wy1 * wx0 + v11 * wy1 * wx1;
  }
  __syncthreads();

  // k/v 1x1 convs: 16 j x 64 o (j uniform per wave -> smp broadcast)
  for (int idx = tid; idx < 1024; idx += 256) {
    int lj = idx >> 6, o = idx & 63;
    int j = px0 + lj;
    float ak0 = 0.f, ak1 = 0.f, av0 = 0.f, av1 = 0.f;
#pragma unroll
    for (int c = 0; c < 32; c += 2) {
      float s0 = smp[c * 17 + lj], s1 = smp[(c + 1) * 17 + lj];
      ak0 = fmaf(kws[o * 33 + c],     s0, ak0);
      ak1 = fmaf(kws[o * 33 + c + 1], s1, ak1);
      av0 = fmaf(vws[o * 33 + c],     s0, av0);
      av1 = fmaf(vws[o * 33 + c + 1], s1, av1);
    }
    kh[((size_t)bg * 64 + j) * 64 + o] = ak0 + ak1;
    vh[((size_t)bg * 64 + j) * 64 + o] = av0 + av1;
  }
}

// ---------------------------------------------------------------------------
// K4: fused CPB-MLP + QK^T + softmax + PV, all MFMA; minimal LDS (~10 KB).
// grid: (64 tiles, 16 bh), 256 thr = 4 waves; wave w owns j-cols [16w,16w+16)
// ---------------------------------------------------------------------------
__global__ __launch_bounds__(256) void k_attn(
    const float* __restrict__ qT, const float* __restrict__ kh,
    const float* __restrict__ vh, const float* __restrict__ gkv,
    const float* __restrict__ w1, const float* __restrict__ b1,
    const unsigned short* __restrict__ w2P, const float* __restrict__ b2,
    const float* __restrict__ w3, const float* __restrict__ b3,
    unsigned short* __restrict__ aoh, unsigned short* __restrict__ aol) {
  const int it  = blockIdx.x;     // 0..63
  const int bh  = blockIdx.y;     // 0..15
  const int i0  = it << 4;
  const int iy  = i0 >> 5;
  const int ixb = i0 & 31;
  const int tid = threadIdx.x;

  __shared__ float utab[16 * 65];
  __shared__ float vtab[64];
  __shared__ float w1xs[64], w1ys[64], b1s[64], b2s[64], w3s[64];
  __shared__ float sim[16 * 65];

  const int w  = tid >> 6;   // wave 0..3
  const int l  = tid & 63;
  const int lm = l & 15;
  const int lg = l >> 4;
  const int jb = w * 16;

  // --- W2 fragments: 8x coalesced 16B loads from packed global ---
  bf16x8 bw2[4][2];
  {
    const unsigned short* wp = w2P + (lg * 16 + lm) * 64;
#pragma unroll
    for (int c2t = 0; c2t < 4; ++c2t)
#pragma unroll
      for (int s = 0; s < 2; ++s)
        bw2[c2t][s] = *(const bf16x8*)(wp + (c2t * 2 + s) * 8);
  }
  // --- V B-fragments (hi/lo split), built once from global (L2-resident) ---
  bf16x8 bvh[2], bvl[2];
  {
    const float* vb = vh + (size_t)bh * 64 * 64 + jb + lm;
#pragma unroll
    for (int s = 0; s < 2; ++s)
#pragma unroll
      for (int r = 0; r < 8; ++r) {
        float v = vb[(size_t)(s * 32 + lg * 8 + r) * 64];
        unsigned short hi = f2bf(v);
        bvh[s][r] = (short)hi;
        bvl[s][r] = (short)f2bf(v - bf2f(hi));
      }
  }

  // --- stage utab/vtab/params ---
  for (int idx = tid; idx < 1024; idx += 256) {
    int il = idx >> 6, j = idx & 63;
    float kxv = gkv[(bh * 64 + j) * 2];
    float qxn = (2.f / 31.f) * (float)(ixb + il) - 1.f;
    utab[il * 65 + j] = slog1p(qxn - kxv);
  }
  if (tid < 64) {
    w1xs[tid] = w1[tid * 2];
    w1ys[tid] = w1[tid * 2 + 1];
    b1s[tid]  = b1[tid];
    b2s[tid]  = b2[tid];
    w3s[tid]  = w3[tid];
    float kyv = gkv[(bh * 64 + tid) * 2 + 1];
    float qyn = (2.f / 31.f) * (float)iy - 1.f;
    vtab[tid] = slog1p(qyn - kyv);
  }
  __syncthreads();

  // --- hoisted il-invariant layer-1 terms ---
  float w1v[16], tc[16];
  {
    float vvj = vtab[jb + lm];
#pragma unroll
    for (int s = 0; s < 2; ++s)
#pragma unroll
      for (int r = 0; r < 8; ++r) {
        int c = s * 32 + lg * 8 + r;
        w1v[s * 8 + r] = w1xs[c];
        tc[s * 8 + r]  = fmaf(w1ys[c], vvj, b1s[c]);
      }
  }
  float b2v[4], w3v[4];
#pragma unroll
  for (int c2t = 0; c2t < 4; ++c2t) {
    b2v[c2t] = b2s[c2t * 16 + lm];
    w3v[c2t] = w3s[c2t * 16 + lm];
  }
  const float b3v = b3[0];

  // --- CPB pass ---
#pragma unroll 1
  for (int il = 0; il < 16; ++il) {
    float u = utab[il * 65 + jb + lm];
    bf16x8 af[2];
#pragma unroll
    for (int s = 0; s < 2; ++s)
#pragma unroll
      for (int r = 0; r < 8; ++r)
        af[s][r] = (short)f2bf(fmaxf(fmaf(w1v[s * 8 + r], u, tc[s * 8 + r]), 0.f));
    f32x4 acc[4];
#pragma unroll
    for (int c2t = 0; c2t < 4; ++c2t) {
      acc[c2t] = (f32x4){0.f, 0.f, 0.f, 0.f};
      acc[c2t] = __builtin_amdgcn_mfma_f32_16x16x32_bf16(af[0], bw2[c2t][0], acc[c2t], 0, 0, 0);
      acc[c2t] = __builtin_amdgcn_mfma_f32_16x16x32_bf16(af[1], bw2[c2t][1], acc[c2t], 0, 0, 0);
    }
    float sres[4];
#pragma unroll
    for (int r = 0; r < 4; ++r) {
      float t0 = fmaxf(acc[0][r] + b2v[0], 0.f) * w3v[0];
      t0 = fmaf(fmaxf(acc[1][r] + b2v[1], 0.f), w3v[1], t0);
      t0 = fmaf(fmaxf(acc[2][r] + b2v[2], 0.f), w3v[2], t0);
      t0 = fmaf(fmaxf(acc[3][r] + b2v[3], 0.f), w3v[3], t0);
      sres[r] = t0;
    }
#pragma unroll
    for (int r = 0; r < 4; ++r) {
      sres[r] += __shfl_xor(sres[r], 1);
      sres[r] += __shfl_xor(sres[r], 2);
      sres[r] += __shfl_xor(sres[r], 4);
      sres[r] += __shfl_xor(sres[r], 8);
    }
    if (lm == 0) {
#pragma unroll
      for (int r = 0; r < 4; ++r)
        sim[il * 65 + jb + lg * 4 + r] = sres[r] + b3v;
    }
  }

  // --- QK pass ---
  {
    bf16x8 aq[2], bk[2];
    const float* qb = qT + ((size_t)bh * NPX + i0 + lm) * 64;
    const float* kb = kh + ((size_t)(bh * 64 + jb + lm)) * 64;
#pragma unroll
    for (int s = 0; s < 2; ++s) {
      float4 q0 = *(const float4*)(qb + s * 32 + lg * 8);
      float4 q1 = *(const float4*)(qb + s * 32 + lg * 8 + 4);
      float4 k0 = *(const float4*)(kb + s * 32 + lg * 8);
      float4 k1 = *(const float4*)(kb + s * 32 + lg * 8 + 4);
      aq[s][0] = (short)f2bf(q0.x); aq[s][1] = (short)f2bf(q0.y);
      aq[s][2] = (short)f2bf(q0.z); aq[s][3] = (short)f2bf(q0.w);
      aq[s][4] = (short)f2bf(q1.x); aq[s][5] = (short)f2bf(q1.y);
      aq[s][6] = (short)f2bf(q1.z); aq[s][7] = (short)f2bf(q1.w);
      bk[s][0] = (short)f2bf(k0.x); bk[s][1] = (short)f2bf(k0.y);
      bk[s][2] = (short)f2bf(k0.z); bk[s][3] = (short)f2bf(k0.w);
      bk[s][4] = (short)f2bf(k1.x); bk[s][5] = (short)f2bf(k1.y);
      bk[s][6] = (short)f2bf(k1.z); bk[s][7] = (short)f2bf(k1.w);
    }
    f32x4 qacc = (f32x4){0.f, 0.f, 0.f, 0.f};
    qacc = __builtin_amdgcn_mfma_f32_16x16x32_bf16(aq[0], bk[0], qacc, 0, 0, 0);
    qacc = __builtin_amdgcn_mfma_f32_16x16x32_bf16(aq[1], bk[1], qacc, 0, 0, 0);
#pragma unroll
    for (int r = 0; r < 4; ++r)
      sim[(lg * 4 + r) * 65 + jb + lm] += qacc[r];
  }
  __syncthreads();

  // --- softmax: 16 threads per row of 64 ---
  {
    int r = tid >> 4, sl = tid & 15;
    float sv[4];
    float m = -1e30f;
#pragma unroll
    for (int t = 0; t < 4; ++t) {
      sv[t] = sim[r * 65 + sl + (t << 4)];
      m = fmaxf(m, sv[t]);
    }
#pragma unroll
    for (int off = 8; off > 0; off >>= 1) m = fmaxf(m, __shfl_xor(m, off, 16));
    float ssum = 0.f;
#pragma unroll
    for (int t = 0; t < 4; ++t) { sv[t] = expf(sv[t] - m); ssum += sv[t]; }
#pragma unroll
    for (int off = 8; off > 0; off >>= 1) ssum += __shfl_xor(ssum, off, 16);
    float inv = 1.f / ssum;
#pragma unroll
    for (int t = 0; t < 4; ++t) sim[r * 65 + sl + (t << 4)] = sv[t] * inv;
  }
  __syncthreads();

  // --- PV via MFMA (P bf16 x V hi/lo), direct hi/lo epilogue ---
  {
    bf16x8 ap[2];
#pragma unroll
    for (int s = 0; s < 2; ++s)
#pragma unroll
      for (int r = 0; r < 8; ++r)
        ap[s][r] = (short)f2bf(sim[lm * 65 + s * 32 + lg * 8 + r]);
    f32x4 po = (f32x4){0.f, 0.f, 0.f, 0.f};
    po = __builtin_amdgcn_mfma_f32_16x16x32_bf16(ap[0], bvh[0], po, 0, 0, 0);
    po = __builtin_amdgcn_mfma_f32_16x16x32_bf16(ap[1], bvh[1], po, 0, 0, 0);
    po = __builtin_amdgcn_mfma_f32_16x16x32_bf16(ap[0], bvl[0], po, 0, 0, 0);
    po = __builtin_amdgcn_mfma_f32_16x16x32_bf16(ap[1], bvl[1], po, 0, 0, 0);
    const int b = bh >> 3, h = bh & 7;
    size_t base = ((size_t)(b * 1024 + i0 + lg * 4)) * 512 + h * 64 + jb + lm;
#pragma unroll
    for (int r = 0; r < 4; ++r) {
      float v = po[r];
      unsigned short hi = f2bf(v);
      aoh[base + (size_t)r * 512] = hi;
      aol[base + (size_t)r * 512] = f2bf(v - bf2f(hi));
    }
  }
}

// ---------------------------------------------------------------------------
// K5: projection as split-bf16 MFMA GEMM (unchanged)
// ---------------------------------------------------------------------------
__global__ __launch_bounds__(256) void k_proj_mfma(
    const unsigned short* __restrict__ aoh, const unsigned short* __restrict__ aol,
    const unsigned short* __restrict__ whP, const unsigned short* __restrict__ wlP,
    const float* __restrict__ ob, float* __restrict__ out) {
  const int p0 = blockIdx.x << 4;
  const int b  = p0 >> 10;
  const int pb = p0 & 1023;
  const int w  = threadIdx.x >> 6;
  const int l  = threadIdx.x & 63;
  const int lm = l & 15, lg = l >> 4;

  f32x4 acc[4];
#pragma unroll
  for (int nt = 0; nt < 4; ++nt) acc[nt] = (f32x4){0.f, 0.f, 0.f, 0.f};

  const unsigned short* arh = aoh + ((size_t)(p0 + lm)) * 512 + lg * 8;
  const unsigned short* arl = aol + ((size_t)(p0 + lm)) * 512 + lg * 8;
  const int ob0 = w * 64;

#pragma unroll 4
  for (int kt = 0; kt < 16; ++kt) {
    bf16x8 ah = *(const bf16x8*)(arh + kt * 32);
    bf16x8 al = *(const bf16x8*)(arl + kt * 32);
    const size_t wb = ((size_t)(kt * 4 + lg) * 256 + ob0 + lm) * 8;
#pragma unroll
    for (int nt = 0; nt < 4; ++nt) {
      bf16x8 bhf = *(const bf16x8*)(whP + wb + nt * 128);
      bf16x8 blf = *(const bf16x8*)(wlP + wb + nt * 128);
      acc[nt] = __builtin_amdgcn_mfma_f32_16x16x32_bf16(ah, bhf, acc[nt], 0, 0, 0);
      acc[nt] = __builtin_amdgcn_mfma_f32_16x16x32_bf16(ah, blf, acc[nt], 0, 0, 0);
      acc[nt] = __builtin_amdgcn_mfma_f32_16x16x32_bf16(al, bhf, acc[nt], 0, 0, 0);
    }
  }
#pragma unroll
  for (int nt = 0; nt < 4; ++nt) {
    int o = ob0 + nt * 16 + lm;
    float bias = ob[o];
    float4 v;
    v.x = acc[nt][0] + bias;
    v.y = acc[nt][1] + bias;
    v.z = acc[nt][2] + bias;
    v.w = acc[nt][3] + bias;
    *(float4*)(out + ((size_t)(b * 256 + o)) * NPX + pb + lg * 4) = v;
  }
}

// ---------------------------------------------------------------------------
extern "C" void kernel_launch(void* const* d_in, const int* in_sizes, int n_in,
                              void* d_out, int out_size, void* d_ws, size_t ws_size,
                              hipStream_t stream) {
  const float* x      = (const float*)d_in[0];
  const float* q_w    = (const float*)d_in[1];
  const float* k_w    = (const float*)d_in[2];
  const float* v_w    = (const float*)d_in[3];
  const float* out_w  = (const float*)d_in[4];
  const float* out_b  = (const float*)d_in[5];
  const float* off_w1 = (const float*)d_in[6];
  const float* off_b1 = (const float*)d_in[7];
  const float* off_w2 = (const float*)d_in[8];
  const float* cpb_w1 = (const float*)d_in[9];
  const float* cpb_b1 = (const float*)d_in[10];
  const float* cpb_w2 = (const float*)d_in[11];
  const float* cpb_b2 = (const float*)d_in[12];
  const float* cpb_w3 = (const float*)d_in[13];
  const float* cpb_b3 = (const float*)d_in[14];
  float* out = (float*)d_out;

  float* ws  = (float*)d_ws;
  float* q   = ws;                          // 1048576 f; reused as aoh/aol
  unsigned short* aoh = (unsigned short*)q; // 2048*512 shorts
  unsigned short* aol = aoh + 2048 * 512;   // 2048*512 shorts
  float* qT  = ws + 1048576;                // 1048576 f
  float* kh  = qT + 1048576;                // 65536 f
  float* vh  = kh + 65536;                  // 65536 f
  float* gkv = vh + 65536;                  // 2048 f
  unsigned short* whP = (unsigned short*)(gkv + 2048);  // 131072 shorts
  unsigned short* wlP = whP + 131072;                   // 131072 shorts
  unsigned short* w2P = wlP + 131072;                   // 4096 shorts

  k_prep_w<<<513, 256, 0, stream>>>(out_w, cpb_w2, whP, wlP, w2P);
  k_qconv<<<256, 256, 0, stream>>>(x, q_w, q, qT);
  k_offset_sample<<<dim3(4, 16), 256, 0, stream>>>(q, off_w1, off_b1, off_w2,
                                                   x, k_w, v_w, gkv, kh, vh);
  k_attn<<<dim3(64, 16), 256, 0, stream>>>(qT, kh, vh, gkv, cpb_w1, cpb_b1,
                                           w2P, cpb_b2, cpb_w3, cpb_b3,
                                           aoh, aol);
  k_proj_mfma<<<128, 256, 0, stream>>>(aoh, aol, whP, wlP, out_b, out);
}

// Round 10
// 83.792 us; speedup vs baseline: 9.4074x; 1.0590x over previous
//
#include <hip/hip_runtime.h>
#include <math.h>

#define NPX 1024  // H*W = 32*32

using bf16x8 = __attribute__((ext_vector_type(8))) short;  // 8 bf16 in 4 VGPRs
using f32x4  = __attribute__((ext_vector_type(4))) float;
using u32x4  = __attribute__((ext_vector_type(4))) unsigned;

__device__ __forceinline__ float slog1p(float p) {
  return copysignf(log1pf(fabsf(p)), p);   // exact version (cold paths)
}
__device__ __forceinline__ float fast_slog1p(float p) {
  // ln(1+|p|) via v_log_f32; 1+|p| in [1,~3] so no catastrophic cancellation
  return copysignf(__logf(1.f + fabsf(p)), p);
}

__device__ __forceinline__ unsigned short f2bf(float f) {
  unsigned u = __builtin_bit_cast(unsigned, f);
  unsigned r = (u + 0x7FFFu + ((u >> 16) & 1u)) >> 16;  // RNE
  return (unsigned short)r;
}
__device__ __forceinline__ float bf2f(unsigned short h) {
  return __builtin_bit_cast(float, (unsigned)h << 16);
}
// HW packed conversion: low16 = bf16(lo), high16 = bf16(hi)
__device__ __forceinline__ unsigned cvt_pk(float lo, float hi) {
  unsigned r;
  asm("v_cvt_pk_bf16_f32 %0, %1, %2" : "=v"(r) : "v"(lo), "v"(hi));
  return r;
}

// ---------------------------------------------------------------------------
// K0: pack out_w into MFMA-fragment-major bf16 hi/lo (blocks 0..511) and
// cpb_w2 into fragment-major bf16 (block 512).
// ---------------------------------------------------------------------------
__global__ __launch_bounds__(256) void k_prep_w(const float* __restrict__ ow,
                                                const float* __restrict__ w2g,
                                                unsigned short* __restrict__ whP,
                                                unsigned short* __restrict__ wlP,
                                                unsigned short* __restrict__ w2P) {
  if (blockIdx.x < 512) {
    int idx = blockIdx.x * 256 + threadIdx.x;  // 0..131071
    int o = idx >> 9, c = idx & 511;
    float v = ow[(size_t)o * 512 + c];
    unsigned short hi = f2bf(v);
    unsigned short lo = f2bf(v - bf2f(hi));
    int kt = c >> 5, lg = (c >> 3) & 3, r = c & 7;
    size_t dst = ((size_t)(kt * 4 + lg) * 256 + o) * 8 + r;
    whP[dst] = hi;
    wlP[dst] = lo;
  } else {
    for (int e = threadIdx.x; e < 4096; e += 256) {
      int r = e & 7;
      int f = (e >> 3) & 7;        // c2t*2+s
      int c2t = f >> 1, s = f & 1;
      int lane = e >> 6;           // lg*16+lm
      int lm = lane & 15, lg = lane >> 4;
      int c2 = c2t * 16 + lm, c = s * 32 + lg * 8 + r;
      w2P[e] = f2bf(w2g[c2 * 64 + c]);
    }
  }
}

// ---------------------------------------------------------------------------
// K1: grouped 1x1 conv  q = x * q_w ; also qT = q*0.125 in (bh,i,d) layout
// ---------------------------------------------------------------------------
__global__ __launch_bounds__(256) void k_qconv(const float* __restrict__ x,
                                               const float* __restrict__ qw,
                                               float* __restrict__ q,
                                               float* __restrict__ qT) {
  const int blk = blockIdx.x;
  const int bg  = blk >> 4;
  const int px0 = (blk & 15) << 6;
  const int g   = bg & 7;
  const int b   = bg >> 3;
  const int tid = threadIdx.x;
  __shared__ float xs[32 * 64];
  __shared__ float wsh[64 * 32];
  __shared__ float ot[64 * 65];

  const float* xb = x + ((size_t)(b * 256 + g * 32)) * NPX + px0;
  for (int idx = tid; idx < 32 * 64; idx += 256) {
    int c = idx >> 6, p = idx & 63;
    xs[idx] = xb[(size_t)c * NPX + p];
  }
  const float* wb = qw + g * 64 * 32;
  for (int idx = tid; idx < 64 * 32; idx += 256) wsh[idx] = wb[idx];
  __syncthreads();

  for (int idx = tid; idx < 64 * 64; idx += 256) {
    int o = idx >> 6, p = idx & 63;
    float a0 = 0.f, a1 = 0.f;
#pragma unroll
    for (int c = 0; c < 32; c += 2) {
      a0 = fmaf(wsh[o * 32 + c],     xs[c * 64 + p],       a0);
      a1 = fmaf(wsh[o * 32 + c + 1], xs[(c + 1) * 64 + p], a1);
    }
    float acc = a0 + a1;
    q[((size_t)(bg * 64 + o)) * NPX + px0 + p] = acc;
    ot[o * 65 + p] = acc * 0.125f;
  }
  __syncthreads();
  float* qTb = qT + ((size_t)bg * NPX + px0) * 64;
  for (int idx = tid; idx < 64 * 64; idx += 256) {
    int p = idx >> 6, o = idx & 63;
    qTb[p * 64 + o] = ot[o * 65 + p];
  }
}

// ---------------------------------------------------------------------------
// K2+K3: offset net + grid_sample + k/v convs, partitioned over px.
// grid: (4 px-chunks of 16, 16 bg), 256 thr.
// ---------------------------------------------------------------------------
__global__ __launch_bounds__(256) void k_offset_sample(
    const float* __restrict__ q, const float* __restrict__ w1,
    const float* __restrict__ b1, const float* __restrict__ w2,
    const float* __restrict__ x, const float* __restrict__ kw,
    const float* __restrict__ vw, float* __restrict__ gkv,
    float* __restrict__ kh, float* __restrict__ vh) {
  const int px0 = blockIdx.x << 4;   // 0,16,32,48
  const int bg  = blockIdx.y;
  const int g   = bg & 7;
  const int tid = threadIdx.x;
  __shared__ float ge[64 * 17];      // [c][lp] gelu outs, padded
  __shared__ float w1s[64 * 36];
  __shared__ float b1s[64];
  __shared__ float kws[64 * 33];
  __shared__ float vws[64 * 33];
  __shared__ float smp[32 * 17];     // [c][lj] sampled, padded
  __shared__ float xs_[16], ys_[16];

  for (int idx = tid; idx < 64 * 36; idx += 256) w1s[idx] = w1[idx];
  if (tid < 64) b1s[tid] = b1[tid];
  for (int idx = tid; idx < 2048; idx += 256) {
    int o = idx >> 5, c = idx & 31;
    kws[o * 33 + c] = kw[(g * 64 + o) * 32 + c];
    vws[o * 33 + c] = vw[(g * 64 + o) * 32 + c];
  }
  __syncthreads();

  const float* qb = q + (size_t)bg * 64 * NPX;
  for (int idx = tid; idx < 1024; idx += 256) {
    int c = idx >> 4, lp = idx & 15;
    int px = px0 + lp;
    int oy = px >> 3, ox = px & 7;
    const float* qc = qb + (size_t)c * NPX;
    float acc = 0.f;
#pragma unroll
    for (int ky = 0; ky < 6; ++ky) {
      int yy = oy * 4 - 1 + ky;
      if (yy < 0 || yy >= 32) continue;
#pragma unroll
      for (int kx = 0; kx < 6; ++kx) {
        int xx = ox * 4 - 1 + kx;
        if (xx < 0 || xx >= 32) continue;
        acc = fmaf(w1s[c * 36 + ky * 6 + kx], qc[yy * 32 + xx], acc);
      }
    }
    acc += b1s[c];
    ge[c * 17 + lp] = 0.5f * acc * (1.f + erff(acc * 0.70710678118654752440f));
  }
  __syncthreads();

  {
    int lp = tid >> 4, sl = tid & 15;
    float s0 = 0.f, s1 = 0.f;
#pragma unroll
    for (int k = 0; k < 4; ++k) {
      int c = sl + k * 16;
      float gv = ge[c * 17 + lp];
      s0 = fmaf(w2[c],      gv, s0);
      s1 = fmaf(w2[64 + c], gv, s1);
    }
#pragma unroll
    for (int off = 8; off > 0; off >>= 1) {
      s0 += __shfl_xor(s0, off, 16);
      s1 += __shfl_xor(s1, off, 16);
    }
    if (sl == 0) {
      float o0 = tanhf(s0) * 4.f;
      float o1 = tanhf(s1) * 4.f;
      int px = px0 + lp;
      int oy = px >> 3, ox = px & 7;
      float g0 = 2.f * ((float)ox + o0) / 7.f - 1.f;
      float g1 = 2.f * ((float)oy + o1) / 7.f - 1.f;
      gkv[(bg * 64 + px) * 2 + 0] = g0;
      gkv[(bg * 64 + px) * 2 + 1] = g1;
      xs_[lp] = (g0 + 1.f) * 16.f - 0.5f;
      ys_[lp] = (g1 + 1.f) * 16.f - 0.5f;
    }
  }
  __syncthreads();

  const float* imgb = x + (size_t)bg * 32 * NPX;
  for (int idx = tid; idx < 512; idx += 256) {
    int c = idx >> 4, lj = idx & 15;
    float xx = xs_[lj], yy = ys_[lj];
    float x0f = floorf(xx), y0f = floorf(yy);
    int x0 = (int)x0f, y0 = (int)y0f;
    float wx1 = xx - x0f, wy1 = yy - y0f;
    float wx0 = 1.f - wx1, wy0 = 1.f - wy1;
    int x1 = x0 + 1, y1 = y0 + 1;
    bool vx0 = (x0 >= 0) & (x0 < 32), vx1 = (x1 >= 0) & (x1 < 32);
    bool vy0 = (y0 >= 0) & (y0 < 32), vy1 = (y1 >= 0) & (y1 < 32);
    int cx0 = min(max(x0, 0), 31), cx1 = min(max(x1, 0), 31);
    int cy0 = min(max(y0, 0), 31), cy1 = min(max(y1, 0), 31);
    const float* img = imgb + (size_t)c * NPX;
    float v00 = (vy0 && vx0) ? img[cy0 * 32 + cx0] : 0.f;
    float v01 = (vy0 && vx1) ? img[cy0 * 32 + cx1] : 0.f;
    float v10 = (vy1 && vx0) ? img[cy1 * 32 + cx0] : 0.f;
    float v11 = (vy1 && vx1) ? img[cy1 * 32 + cx1] : 0.f;
    smp[c * 17 + lj] = v00 * wy0 * wx0 + v01 * wy0 * wx1 +
                       v10 * wy1 * wx0 + v11 * wy1 * wx1;
  }
  __syncthreads();

  for (int idx = tid; idx < 1024; idx += 256) {
    int lj = idx >> 6, o = idx & 63;
    int j = px0 + lj;
    float ak0 = 0.f, ak1 = 0.f, av0 = 0.f, av1 = 0.f;
#pragma unroll
    for (int c = 0; c < 32; c += 2) {
      float s0 = smp[c * 17 + lj], s1 = smp[(c + 1) * 17 + lj];
      ak0 = fmaf(kws[o * 33 + c],     s0, ak0);
      ak1 = fmaf(kws[o * 33 + c + 1], s1, ak1);
      av0 = fmaf(vws[o * 33 + c],     s0, av0);
      av1 = fmaf(vws[o * 33 + c + 1], s1, av1);
    }
    kh[((size_t)bg * 64 + j) * 64 + o] = ak0 + ak1;
    vh[((size_t)bg * 64 + j) * 64 + o] = av0 + av1;
  }
}

// ---------------------------------------------------------------------------
// K4: fused CPB-MLP + QK^T + softmax + PV, all MFMA; hot-path conversions via
// v_cvt_pk_bf16_f32; b2 folded into MFMA C-operand; fast slog1p staging.
// grid: (64 tiles, 16 bh), 256 thr = 4 waves; wave w owns j-cols [16w,16w+16)
// ---------------------------------------------------------------------------
__global__ __launch_bounds__(256) void k_attn(
    const float* __restrict__ qT, const float* __restrict__ kh,
    const float* __restrict__ vh, const float* __restrict__ gkv,
    const float* __restrict__ w1, const float* __restrict__ b1,
    const unsigned short* __restrict__ w2P, const float* __restrict__ b2,
    const float* __restrict__ w3, const float* __restrict__ b3,
    unsigned short* __restrict__ aoh, unsigned short* __restrict__ aol) {
  const int it  = blockIdx.x;     // 0..63
  const int bh  = blockIdx.y;     // 0..15
  const int i0  = it << 4;
  const int iy  = i0 >> 5;
  const int ixb = i0 & 31;
  const int tid = threadIdx.x;

  __shared__ float utab[16 * 65];
  __shared__ float vtab[64];
  __shared__ float w1xs[64], w1ys[64], b1s[64], b2s[64], w3s[64];
  __shared__ float sim[16 * 65];

  const int w  = tid >> 6;   // wave 0..3
  const int l  = tid & 63;
  const int lm = l & 15;
  const int lg = l >> 4;
  const int jb = w * 16;

  // --- W2 fragments: 8x coalesced 16B loads from packed global ---
  bf16x8 bw2[4][2];
  {
    const unsigned short* wp = w2P + (lg * 16 + lm) * 64;
#pragma unroll
    for (int c2t = 0; c2t < 4; ++c2t)
#pragma unroll
      for (int s = 0; s < 2; ++s)
        bw2[c2t][s] = *(const bf16x8*)(wp + (c2t * 2 + s) * 8);
  }
  // --- V B-fragments (hi/lo split), built once from global (L2-resident) ---
  bf16x8 bvh[2], bvl[2];
  {
    const float* vb = vh + (size_t)bh * 64 * 64 + jb + lm;
#pragma unroll
    for (int s = 0; s < 2; ++s)
#pragma unroll
      for (int r = 0; r < 8; ++r) {
        float v = vb[(size_t)(s * 32 + lg * 8 + r) * 64];
        unsigned short hi = f2bf(v);
        bvh[s][r] = (short)hi;
        bvl[s][r] = (short)f2bf(v - bf2f(hi));
      }
  }

  // --- stage utab/vtab/params (fast log) ---
  for (int idx = tid; idx < 1024; idx += 256) {
    int il = idx >> 6, j = idx & 63;
    float kxv = gkv[(bh * 64 + j) * 2];
    float qxn = (2.f / 31.f) * (float)(ixb + il) - 1.f;
    utab[il * 65 + j] = fast_slog1p(qxn - kxv);
  }
  if (tid < 64) {
    w1xs[tid] = w1[tid * 2];
    w1ys[tid] = w1[tid * 2 + 1];
    b1s[tid]  = b1[tid];
    b2s[tid]  = b2[tid];
    w3s[tid]  = w3[tid];
    float kyv = gkv[(bh * 64 + tid) * 2 + 1];
    float qyn = (2.f / 31.f) * (float)iy - 1.f;
    vtab[tid] = fast_slog1p(qyn - kyv);
  }
  __syncthreads();

  // --- hoisted il-invariant layer-1 terms ---
  float w1v[16], tc[16];
  {
    float vvj = vtab[jb + lm];
#pragma unroll
    for (int s = 0; s < 2; ++s)
#pragma unroll
      for (int r = 0; r < 8; ++r) {
        int c = s * 32 + lg * 8 + r;
        w1v[s * 8 + r] = w1xs[c];
        tc[s * 8 + r]  = fmaf(w1ys[c], vvj, b1s[c]);
      }
  }
  float b2v[4], w3v[4];
#pragma unroll
  for (int c2t = 0; c2t < 4; ++c2t) {
    b2v[c2t] = b2s[c2t * 16 + lm];
    w3v[c2t] = w3s[c2t * 16 + lm];
  }
  const float b3v = b3[0];

  // --- CPB pass ---
#pragma unroll 1
  for (int il = 0; il < 16; ++il) {
    float u = utab[il * 65 + jb + lm];
    float h[16];
#pragma unroll
    for (int e = 0; e < 16; ++e)
      h[e] = fmaxf(fmaf(w1v[e], u, tc[e]), 0.f);
    bf16x8 af[2];
#pragma unroll
    for (int s = 0; s < 2; ++s) {
      u32x4 wds;
#pragma unroll
      for (int p = 0; p < 4; ++p)
        wds[p] = cvt_pk(h[s * 8 + p * 2], h[s * 8 + p * 2 + 1]);
      af[s] = __builtin_bit_cast(bf16x8, wds);
    }
    f32x4 acc[4];
#pragma unroll
    for (int c2t = 0; c2t < 4; ++c2t) {
      acc[c2t] = (f32x4){b2v[c2t], b2v[c2t], b2v[c2t], b2v[c2t]};  // b2 via C
      acc[c2t] = __builtin_amdgcn_mfma_f32_16x16x32_bf16(af[0], bw2[c2t][0], acc[c2t], 0, 0, 0);
      acc[c2t] = __builtin_amdgcn_mfma_f32_16x16x32_bf16(af[1], bw2[c2t][1], acc[c2t], 0, 0, 0);
    }
    float sres[4];
#pragma unroll
    for (int r = 0; r < 4; ++r) {
      float t0 = fmaxf(acc[0][r], 0.f) * w3v[0];
      t0 = fmaf(fmaxf(acc[1][r], 0.f), w3v[1], t0);
      t0 = fmaf(fmaxf(acc[2][r], 0.f), w3v[2], t0);
      t0 = fmaf(fmaxf(acc[3][r], 0.f), w3v[3], t0);
      sres[r] = t0;
    }
#pragma unroll
    for (int r = 0; r < 4; ++r) {
      sres[r] += __shfl_xor(sres[r], 1);
      sres[r] += __shfl_xor(sres[r], 2);
      sres[r] += __shfl_xor(sres[r], 4);
      sres[r] += __shfl_xor(sres[r], 8);
    }
    if (lm == 0) {
#pragma unroll
      for (int r = 0; r < 4; ++r)
        sim[il * 65 + jb + lg * 4 + r] = sres[r] + b3v;
    }
  }

  // --- QK pass: fragments straight from global (L2), packed conversion ---
  {
    bf16x8 aq[2], bk[2];
    const float* qb = qT + ((size_t)bh * NPX + i0 + lm) * 64;
    const float* kb = kh + ((size_t)(bh * 64 + jb + lm)) * 64;
#pragma unroll
    for (int s = 0; s < 2; ++s) {
      float4 q0 = *(const float4*)(qb + s * 32 + lg * 8);
      float4 q1 = *(const float4*)(qb + s * 32 + lg * 8 + 4);
      float4 k0 = *(const float4*)(kb + s * 32 + lg * 8);
      float4 k1 = *(const float4*)(kb + s * 32 + lg * 8 + 4);
      u32x4 wq, wk;
      wq[0] = cvt_pk(q0.x, q0.y); wq[1] = cvt_pk(q0.z, q0.w);
      wq[2] = cvt_pk(q1.x, q1.y); wq[3] = cvt_pk(q1.z, q1.w);
      wk[0] = cvt_pk(k0.x, k0.y); wk[1] = cvt_pk(k0.z, k0.w);
      wk[2] = cvt_pk(k1.x, k1.y); wk[3] = cvt_pk(k1.z, k1.w);
      aq[s] = __builtin_bit_cast(bf16x8, wq);
      bk[s] = __builtin_bit_cast(bf16x8, wk);
    }
    f32x4 qacc = (f32x4){0.f, 0.f, 0.f, 0.f};
    qacc = __builtin_amdgcn_mfma_f32_16x16x32_bf16(aq[0], bk[0], qacc, 0, 0, 0);
    qacc = __builtin_amdgcn_mfma_f32_16x16x32_bf16(aq[1], bk[1], qacc, 0, 0, 0);
#pragma unroll
    for (int r = 0; r < 4; ++r)
      sim[(lg * 4 + r) * 65 + jb + lm] += qacc[r];
  }
  __syncthreads();

  // --- softmax: 16 threads per row of 64 ---
  {
    int r = tid >> 4, sl = tid & 15;
    float sv[4];
    float m = -1e30f;
#pragma unroll
    for (int t = 0; t < 4; ++t) {
      sv[t] = sim[r * 65 + sl + (t << 4)];
      m = fmaxf(m, sv[t]);
    }
#pragma unroll
    for (int off = 8; off > 0; off >>= 1) m = fmaxf(m, __shfl_xor(m, off, 16));
    float ssum = 0.f;
#pragma unroll
    for (int t = 0; t < 4; ++t) { sv[t] = expf(sv[t] - m); ssum += sv[t]; }
#pragma unroll
    for (int off = 8; off > 0; off >>= 1) ssum += __shfl_xor(ssum, off, 16);
    float inv = 1.f / ssum;
#pragma unroll
    for (int t = 0; t < 4; ++t) sim[r * 65 + sl + (t << 4)] = sv[t] * inv;
  }
  __syncthreads();

  // --- PV via MFMA (P bf16 x V hi/lo), direct hi/lo epilogue ---
  {
    bf16x8 ap[2];
#pragma unroll
    for (int s = 0; s < 2; ++s) {
      u32x4 wp;
#pragma unroll
      for (int p = 0; p < 4; ++p)
        wp[p] = cvt_pk(sim[lm * 65 + s * 32 + lg * 8 + p * 2],
                       sim[lm * 65 + s * 32 + lg * 8 + p * 2 + 1]);
      ap[s] = __builtin_bit_cast(bf16x8, wp);
    }
    f32x4 po = (f32x4){0.f, 0.f, 0.f, 0.f};
    po = __builtin_amdgcn_mfma_f32_16x16x32_bf16(ap[0], bvh[0], po, 0, 0, 0);
    po = __builtin_amdgcn_mfma_f32_16x16x32_bf16(ap[1], bvh[1], po, 0, 0, 0);
    po = __builtin_amdgcn_mfma_f32_16x16x32_bf16(ap[0], bvl[0], po, 0, 0, 0);
    po = __builtin_amdgcn_mfma_f32_16x16x32_bf16(ap[1], bvl[1], po, 0, 0, 0);
    const int b = bh >> 3, h = bh & 7;
    size_t base = ((size_t)(b * 1024 + i0 + lg * 4)) * 512 + h * 64 + jb + lm;
#pragma unroll
    for (int r = 0; r < 4; ++r) {
      float v = po[r];
      unsigned short hi = f2bf(v);
      aoh[base + (size_t)r * 512] = hi;
      aol[base + (size_t)r * 512] = f2bf(v - bf2f(hi));
    }
  }
}

// ---------------------------------------------------------------------------
// K5: projection as split-bf16 MFMA GEMM (unchanged)
// ---------------------------------------------------------------------------
__global__ __launch_bounds__(256) void k_proj_mfma(
    const unsigned short* __restrict__ aoh, const unsigned short* __restrict__ aol,
    const unsigned short* __restrict__ whP, const unsigned short* __restrict__ wlP,
    const float* __restrict__ ob, float* __restrict__ out) {
  const int p0 = blockIdx.x << 4;
  const int b  = p0 >> 10;
  const int pb = p0 & 1023;
  const int w  = threadIdx.x >> 6;
  const int l  = threadIdx.x & 63;
  const int lm = l & 15, lg = l >> 4;

  f32x4 acc[4];
#pragma unroll
  for (int nt = 0; nt < 4; ++nt) acc[nt] = (f32x4){0.f, 0.f, 0.f, 0.f};

  const unsigned short* arh = aoh + ((size_t)(p0 + lm)) * 512 + lg * 8;
  const unsigned short* arl = aol + ((size_t)(p0 + lm)) * 512 + lg * 8;
  const int ob0 = w * 64;

#pragma unroll 4
  for (int kt = 0; kt < 16; ++kt) {
    bf16x8 ah = *(const bf16x8*)(arh + kt * 32);
    bf16x8 al = *(const bf16x8*)(arl + kt * 32);
    const size_t wb = ((size_t)(kt * 4 + lg) * 256 + ob0 + lm) * 8;
#pragma unroll
    for (int nt = 0; nt < 4; ++nt) {
      bf16x8 bhf = *(const bf16x8*)(whP + wb + nt * 128);
      bf16x8 blf = *(const bf16x8*)(wlP + wb + nt * 128);
      acc[nt] = __builtin_amdgcn_mfma_f32_16x16x32_bf16(ah, bhf, acc[nt], 0, 0, 0);
      acc[nt] = __builtin_amdgcn_mfma_f32_16x16x32_bf16(ah, blf, acc[nt], 0, 0, 0);
      acc[nt] = __builtin_amdgcn_mfma_f32_16x16x32_bf16(al, bhf, acc[nt], 0, 0, 0);
    }
  }
#pragma unroll
  for (int nt = 0; nt < 4; ++nt) {
    int o = ob0 + nt * 16 + lm;
    float bias = ob[o];
    float4 v;
    v.x = acc[nt][0] + bias;
    v.y = acc[nt][1] + bias;
    v.z = acc[nt][2] + bias;
    v.w = acc[nt][3] + bias;
    *(float4*)(out + ((size_t)(b * 256 + o)) * NPX + pb + lg * 4) = v;
  }
}

// ---------------------------------------------------------------------------
extern "C" void kernel_launch(void* const* d_in, const int* in_sizes, int n_in,
                              void* d_out, int out_size, void* d_ws, size_t ws_size,
                              hipStream_t stream) {
  const float* x      = (const float*)d_in[0];
  const float* q_w    = (const float*)d_in[1];
  const float* k_w    = (const float*)d_in[2];
  const float* v_w    = (const float*)d_in[3];
  const float* out_w  = (const float*)d_in[4];
  const float* out_b  = (const float*)d_in[5];
  const float* off_w1 = (const float*)d_in[6];
  const float* off_b1 = (const float*)d_in[7];
  const float* off_w2 = (const float*)d_in[8];
  const float* cpb_w1 = (const float*)d_in[9];
  const float* cpb_b1 = (const float*)d_in[10];
  const float* cpb_w2 = (const float*)d_in[11];
  const float* cpb_b2 = (const float*)d_in[12];
  const float* cpb_w3 = (const float*)d_in[13];
  const float* cpb_b3 = (const float*)d_in[14];
  float* out = (float*)d_out;

  float* ws  = (float*)d_ws;
  float* q   = ws;                          // 1048576 f; reused as aoh/aol
  unsigned short* aoh = (unsigned short*)q; // 2048*512 shorts
  unsigned short* aol = aoh + 2048 * 512;   // 2048*512 shorts
  float* qT  = ws + 1048576;                // 1048576 f
  float* kh  = qT + 1048576;                // 65536 f
  float* vh  = kh + 65536;                  // 65536 f
  float* gkv = vh + 65536;                  // 2048 f
  unsigned short* whP = (unsigned short*)(gkv + 2048);  // 131072 shorts
  unsigned short* wlP = whP + 131072;                   // 131072 shorts
  unsigned short* w2P = wlP + 131072;                   // 4096 shorts

  k_prep_w<<<513, 256, 0, stream>>>(out_w, cpb_w2, whP, wlP, w2P);
  k_qconv<<<256, 256, 0, stream>>>(x, q_w, q, qT);
  k_offset_sample<<<dim3(4, 16), 256, 0, stream>>>(q, off_w1, off_b1, off_w2,
                                                   x, k_w, v_w, gkv, kh, vh);
  k_attn<<<dim3(64, 16), 256, 0, stream>>>(qT, kh, vh, gkv, cpb_w1, cpb_b1,
                                           w2P, cpb_b2, cpb_w3, cpb_b3,
                                           aoh, aol);
  k_proj_mfma<<<128, 256, 0, stream>>>(aoh, aol, whP, wlP, out_b, out);
}

// Round 11
// 80.087 us; speedup vs baseline: 9.8427x; 1.0463x over previous
//
#include <hip/hip_runtime.h>
#include <math.h>

#define NPX 1024  // H*W = 32*32

using bf16x8 = __attribute__((ext_vector_type(8))) short;  // 8 bf16 in 4 VGPRs
using f32x4  = __attribute__((ext_vector_type(4))) float;
using u32x4  = __attribute__((ext_vector_type(4))) unsigned;

__device__ __forceinline__ float fast_slog1p(float p) {
  // ln(1+|p|) via v_log_f32; 1+|p| in [1,~3] so no catastrophic cancellation
  return copysignf(__logf(1.f + fabsf(p)), p);
}

__device__ __forceinline__ unsigned short f2bf(float f) {
  unsigned u = __builtin_bit_cast(unsigned, f);
  unsigned r = (u + 0x7FFFu + ((u >> 16) & 1u)) >> 16;  // RNE
  return (unsigned short)r;
}
__device__ __forceinline__ float bf2f(unsigned short h) {
  return __builtin_bit_cast(float, (unsigned)h << 16);
}
// HW packed conversion: low16 = bf16(lo), high16 = bf16(hi)
__device__ __forceinline__ unsigned cvt_pk(float lo, float hi) {
  unsigned r;
  asm("v_cvt_pk_bf16_f32 %0, %1, %2" : "=v"(r) : "v"(lo), "v"(hi));
  return r;
}

// ---------------------------------------------------------------------------
// K0: pack out_w into MFMA-fragment-major bf16 hi/lo (blocks 0..511) and
// cpb_w2 into fragment-major bf16 (block 512).
// ---------------------------------------------------------------------------
__global__ __launch_bounds__(256) void k_prep_w(const float* __restrict__ ow,
                                                const float* __restrict__ w2g,
                                                unsigned short* __restrict__ whP,
                                                unsigned short* __restrict__ wlP,
                                                unsigned short* __restrict__ w2P) {
  if (blockIdx.x < 512) {
    int idx = blockIdx.x * 256 + threadIdx.x;  // 0..131071
    int o = idx >> 9, c = idx & 511;
    float v = ow[(size_t)o * 512 + c];
    unsigned short hi = f2bf(v);
    unsigned short lo = f2bf(v - bf2f(hi));
    int kt = c >> 5, lg = (c >> 3) & 3, r = c & 7;
    size_t dst = ((size_t)(kt * 4 + lg) * 256 + o) * 8 + r;
    whP[dst] = hi;
    wlP[dst] = lo;
  } else {
    for (int e = threadIdx.x; e < 4096; e += 256) {
      int r = e & 7;
      int f = (e >> 3) & 7;        // c2t*2+s
      int c2t = f >> 1, s = f & 1;
      int lane = e >> 6;           // lg*16+lm
      int lm = lane & 15, lg = lane >> 4;
      int c2 = c2t * 16 + lm, c = s * 32 + lg * 8 + r;
      w2P[e] = f2bf(w2g[c2 * 64 + c]);
    }
  }
}

// ---------------------------------------------------------------------------
// K1: grouped 1x1 conv  q = x * q_w ; also qT = q*0.125 in (bh,i,d) layout
// ---------------------------------------------------------------------------
__global__ __launch_bounds__(256) void k_qconv(const float* __restrict__ x,
                                               const float* __restrict__ qw,
                                               float* __restrict__ q,
                                               float* __restrict__ qT) {
  const int blk = blockIdx.x;
  const int bg  = blk >> 4;
  const int px0 = (blk & 15) << 6;
  const int g   = bg & 7;
  const int b   = bg >> 3;
  const int tid = threadIdx.x;
  __shared__ float xs[32 * 64];
  __shared__ float wsh[64 * 32];
  __shared__ float ot[64 * 65];

  const float* xb = x + ((size_t)(b * 256 + g * 32)) * NPX + px0;
  for (int idx = tid; idx < 32 * 64; idx += 256) {
    int c = idx >> 6, p = idx & 63;
    xs[idx] = xb[(size_t)c * NPX + p];
  }
  const float* wb = qw + g * 64 * 32;
  for (int idx = tid; idx < 64 * 32; idx += 256) wsh[idx] = wb[idx];
  __syncthreads();

  for (int idx = tid; idx < 64 * 64; idx += 256) {
    int o = idx >> 6, p = idx & 63;
    float a0 = 0.f, a1 = 0.f;
#pragma unroll
    for (int c = 0; c < 32; c += 2) {
      a0 = fmaf(wsh[o * 32 + c],     xs[c * 64 + p],       a0);
      a1 = fmaf(wsh[o * 32 + c + 1], xs[(c + 1) * 64 + p], a1);
    }
    float acc = a0 + a1;
    q[((size_t)(bg * 64 + o)) * NPX + px0 + p] = acc;
    ot[o * 65 + p] = acc * 0.125f;
  }
  __syncthreads();
  float* qTb = qT + ((size_t)bg * NPX + px0) * 64;
  for (int idx = tid; idx < 64 * 64; idx += 256) {
    int p = idx >> 6, o = idx & 63;
    qTb[p * 64 + o] = ot[o * 65 + p];
  }
}

// ---------------------------------------------------------------------------
// K2+K3: offset net + grid_sample + k/v convs, partitioned over px.
// Emits V directly as bf16 hi/lo in MFMA B-fragment layout (vPh/vPl).
// grid: (4 px-chunks of 16, 16 bg), 256 thr.
// ---------------------------------------------------------------------------
__global__ __launch_bounds__(256) void k_offset_sample(
    const float* __restrict__ q, const float* __restrict__ w1,
    const float* __restrict__ b1, const float* __restrict__ w2,
    const float* __restrict__ x, const float* __restrict__ kw,
    const float* __restrict__ vw, float* __restrict__ gkv,
    float* __restrict__ kh,
    unsigned short* __restrict__ vPh, unsigned short* __restrict__ vPl) {
  const int px0 = blockIdx.x << 4;   // 0,16,32,48
  const int bg  = blockIdx.y;
  const int g   = bg & 7;
  const int tid = threadIdx.x;
  __shared__ float ge[64 * 17];      // [c][lp] gelu outs, padded
  __shared__ float w1s[64 * 36];
  __shared__ float b1s[64];
  __shared__ float kws[64 * 33];
  __shared__ float vws[64 * 33];
  __shared__ float smp[32 * 17];     // [c][lj] sampled, padded
  __shared__ float xs_[16], ys_[16];

  for (int idx = tid; idx < 64 * 36; idx += 256) w1s[idx] = w1[idx];
  if (tid < 64) b1s[tid] = b1[tid];
  for (int idx = tid; idx < 2048; idx += 256) {
    int o = idx >> 5, c = idx & 31;
    kws[o * 33 + c] = kw[(g * 64 + o) * 32 + c];
    vws[o * 33 + c] = vw[(g * 64 + o) * 32 + c];
  }
  __syncthreads();

  const float* qb = q + (size_t)bg * 64 * NPX;
  for (int idx = tid; idx < 1024; idx += 256) {
    int c = idx >> 4, lp = idx & 15;
    int px = px0 + lp;
    int oy = px >> 3, ox = px & 7;
    const float* qc = qb + (size_t)c * NPX;
    float acc = 0.f;
#pragma unroll
    for (int ky = 0; ky < 6; ++ky) {
      int yy = oy * 4 - 1 + ky;
      if (yy < 0 || yy >= 32) continue;
#pragma unroll
      for (int kx = 0; kx < 6; ++kx) {
        int xx = ox * 4 - 1 + kx;
        if (xx < 0 || xx >= 32) continue;
        acc = fmaf(w1s[c * 36 + ky * 6 + kx], qc[yy * 32 + xx], acc);
      }
    }
    acc += b1s[c];
    ge[c * 17 + lp] = 0.5f * acc * (1.f + erff(acc * 0.70710678118654752440f));
  }
  __syncthreads();

  {
    int lp = tid >> 4, sl = tid & 15;
    float s0 = 0.f, s1 = 0.f;
#pragma unroll
    for (int k = 0; k < 4; ++k) {
      int c = sl + k * 16;
      float gv = ge[c * 17 + lp];
      s0 = fmaf(w2[c],      gv, s0);
      s1 = fmaf(w2[64 + c], gv, s1);
    }
#pragma unroll
    for (int off = 8; off > 0; off >>= 1) {
      s0 += __shfl_xor(s0, off, 16);
      s1 += __shfl_xor(s1, off, 16);
    }
    if (sl == 0) {
      float o0 = tanhf(s0) * 4.f;
      float o1 = tanhf(s1) * 4.f;
      int px = px0 + lp;
      int oy = px >> 3, ox = px & 7;
      float g0 = 2.f * ((float)ox + o0) / 7.f - 1.f;
      float g1 = 2.f * ((float)oy + o1) / 7.f - 1.f;
      gkv[(bg * 64 + px) * 2 + 0] = g0;
      gkv[(bg * 64 + px) * 2 + 1] = g1;
      xs_[lp] = (g0 + 1.f) * 16.f - 0.5f;
      ys_[lp] = (g1 + 1.f) * 16.f - 0.5f;
    }
  }
  __syncthreads();

  const float* imgb = x + (size_t)bg * 32 * NPX;
  for (int idx = tid; idx < 512; idx += 256) {
    int c = idx >> 4, lj = idx & 15;
    float xx = xs_[lj], yy = ys_[lj];
    float x0f = floorf(xx), y0f = floorf(yy);
    int x0 = (int)x0f, y0 = (int)y0f;
    float wx1 = xx - x0f, wy1 = yy - y0f;
    float wx0 = 1.f - wx1, wy0 = 1.f - wy1;
    int x1 = x0 + 1, y1 = y0 + 1;
    bool vx0 = (x0 >= 0) & (x0 < 32), vx1 = (x1 >= 0) & (x1 < 32);
    bool vy0 = (y0 >= 0) & (y0 < 32), vy1 = (y1 >= 0) & (y1 < 32);
    int cx0 = min(max(x0, 0), 31), cx1 = min(max(x1, 0), 31);
    int cy0 = min(max(y0, 0), 31), cy1 = min(max(y1, 0), 31);
    const float* img = imgb + (size_t)c * NPX;
    float v00 = (vy0 && vx0) ? img[cy0 * 32 + cx0] : 0.f;
    float v01 = (vy0 && vx1) ? img[cy0 * 32 + cx1] : 0.f;
    float v10 = (vy1 && vx0) ? img[cy1 * 32 + cx0] : 0.f;
    float v11 = (vy1 && vx1) ? img[cy1 * 32 + cx1] : 0.f;
    smp[c * 17 + lj] = v00 * wy0 * wx0 + v01 * wy0 * wx1 +
                       v10 * wy1 * wx0 + v11 * wy1 * wx1;
  }
  __syncthreads();

  for (int idx = tid; idx < 1024; idx += 256) {
    int lj = idx >> 6, o = idx & 63;
    int j = px0 + lj;
    float ak0 = 0.f, ak1 = 0.f, av0 = 0.f, av1 = 0.f;
#pragma unroll
    for (int c = 0; c < 32; c += 2) {
      float s0 = smp[c * 17 + lj], s1 = smp[(c + 1) * 17 + lj];
      ak0 = fmaf(kws[o * 33 + c],     s0, ak0);
      ak1 = fmaf(kws[o * 33 + c + 1], s1, ak1);
      av0 = fmaf(vws[o * 33 + c],     s0, av0);
      av1 = fmaf(vws[o * 33 + c + 1], s1, av1);
    }
    kh[((size_t)bg * 64 + j) * 64 + o] = ak0 + ak1;
    // V -> bf16 hi/lo in MFMA B-fragment layout:
    // frag(k=j, n=d=o): s=(j>>5)&1, lg=(j>>3)&3, r=j&7; nb=o>>4, lm=o&15
    float av = av0 + av1;
    unsigned short hi = f2bf(av);
    unsigned short lo = f2bf(av - bf2f(hi));
    int s  = (j >> 5) & 1, lgj = (j >> 3) & 3, r = j & 7;
    int nb = o >> 4, lmo = o & 15;
    size_t dst = (((size_t)(bg * 4 + nb) * 64) + lgj * 16 + lmo) * 16 + s * 8 + r;
    vPh[dst] = hi;
    vPl[dst] = lo;
  }
}

// ---------------------------------------------------------------------------
// K4: fused CPB-MLP + QK^T + softmax + PV, all MFMA.
// CPB uses swapped operands (W2 as A, h1 as B) so layer-3 is in-register +
// 2 shfl (vs 16). V fragments pre-packed (vPh/vPl).
// grid: (64 tiles, 16 bh), 256 thr = 4 waves; wave w owns j-cols [16w,16w+16)
// ---------------------------------------------------------------------------
__global__ __launch_bounds__(256) void k_attn(
    const float* __restrict__ qT, const float* __restrict__ kh,
    const unsigned short* __restrict__ vPh, const unsigned short* __restrict__ vPl,
    const float* __restrict__ gkv,
    const float* __restrict__ w1, const float* __restrict__ b1,
    const unsigned short* __restrict__ w2P, const float* __restrict__ b2,
    const float* __restrict__ w3, const float* __restrict__ b3,
    unsigned short* __restrict__ aoh, unsigned short* __restrict__ aol) {
  const int it  = blockIdx.x;     // 0..63
  const int bh  = blockIdx.y;     // 0..15
  const int i0  = it << 4;
  const int iy  = i0 >> 5;
  const int ixb = i0 & 31;
  const int tid = threadIdx.x;

  __shared__ float utab[16 * 65];
  __shared__ float vtab[64];
  __shared__ float w1xs[64], w1ys[64], b1s[64], b2s[64], w3s[64];
  __shared__ float sim[16 * 65];

  const int w  = tid >> 6;   // wave 0..3
  const int l  = tid & 63;
  const int lm = l & 15;
  const int lg = l >> 4;
  const int jb = w * 16;

  // --- W2 fragments (dual-use A-layout: lane holds W2[c2t*16+lm][s*32+lg*8+r])
  bf16x8 bw2[4][2];
  {
    const unsigned short* wp = w2P + (lg * 16 + lm) * 64;
#pragma unroll
    for (int c2t = 0; c2t < 4; ++c2t)
#pragma unroll
      for (int s = 0; s < 2; ++s)
        bw2[c2t][s] = *(const bf16x8*)(wp + (c2t * 2 + s) * 8);
  }
  // --- V B-fragments: 4 coalesced 16B loads from packed global ---
  bf16x8 bvh[2], bvl[2];
  {
    const size_t vbase = (((size_t)(bh * 4 + w) * 64) + l) * 16;
#pragma unroll
    for (int s = 0; s < 2; ++s) {
      bvh[s] = *(const bf16x8*)(vPh + vbase + s * 8);
      bvl[s] = *(const bf16x8*)(vPl + vbase + s * 8);
    }
  }

  // --- stage utab/vtab/params (fast log) ---
  for (int idx = tid; idx < 1024; idx += 256) {
    int il = idx >> 6, j = idx & 63;
    float kxv = gkv[(bh * 64 + j) * 2];
    float qxn = (2.f / 31.f) * (float)(ixb + il) - 1.f;
    utab[il * 65 + j] = fast_slog1p(qxn - kxv);
  }
  if (tid < 64) {
    w1xs[tid] = w1[tid * 2];
    w1ys[tid] = w1[tid * 2 + 1];
    b1s[tid]  = b1[tid];
    b2s[tid]  = b2[tid];
    w3s[tid]  = w3[tid];
    float kyv = gkv[(bh * 64 + tid) * 2 + 1];
    float qyn = (2.f / 31.f) * (float)iy - 1.f;
    vtab[tid] = fast_slog1p(qyn - kyv);
  }
  __syncthreads();

  // --- hoisted il-invariant layer-1 terms ---
  float w1v[16], tc[16];
  {
    float vvj = vtab[jb + lm];
#pragma unroll
    for (int s = 0; s < 2; ++s)
#pragma unroll
      for (int r = 0; r < 8; ++r) {
        int c = s * 32 + lg * 8 + r;
        w1v[s * 8 + r] = w1xs[c];
        tc[s * 8 + r]  = fmaf(w1ys[c], vvj, b1s[c]);
      }
  }
  // per-lane layer-3 constants for swapped layout: c2 = c2t*16 + lg*4 + r
  float b2r[4][4], w3r[4][4];
#pragma unroll
  for (int c2t = 0; c2t < 4; ++c2t)
#pragma unroll
    for (int r = 0; r < 4; ++r) {
      int c2 = c2t * 16 + lg * 4 + r;
      b2r[c2t][r] = b2s[c2];
      w3r[c2t][r] = w3s[c2];
    }
  const float b3v = b3[0];

  // --- CPB pass: swapped operands; lane lm = point j-within-16 ---
#pragma unroll 1
  for (int il = 0; il < 16; ++il) {
    float u = utab[il * 65 + jb + lm];
    float h[16];
#pragma unroll
    for (int e = 0; e < 16; ++e)
      h[e] = fmaxf(fmaf(w1v[e], u, tc[e]), 0.f);
    bf16x8 hf[2];   // B-fragment: col=point=lm, k=c
#pragma unroll
    for (int s = 0; s < 2; ++s) {
      u32x4 wds;
#pragma unroll
      for (int p = 0; p < 4; ++p)
        wds[p] = cvt_pk(h[s * 8 + p * 2], h[s * 8 + p * 2 + 1]);
      hf[s] = __builtin_bit_cast(bf16x8, wds);
    }
    // D[m=c2][n=point]: lane holds point=lm, c2 = c2t*16 + lg*4 + r
    float tot = 0.f;
#pragma unroll
    for (int c2t = 0; c2t < 4; ++c2t) {
      f32x4 acc = (f32x4){b2r[c2t][0], b2r[c2t][1], b2r[c2t][2], b2r[c2t][3]};
      acc = __builtin_amdgcn_mfma_f32_16x16x32_bf16(bw2[c2t][0], hf[0], acc, 0, 0, 0);
      acc = __builtin_amdgcn_mfma_f32_16x16x32_bf16(bw2[c2t][1], hf[1], acc, 0, 0, 0);
#pragma unroll
      for (int r = 0; r < 4; ++r)
        tot = fmaf(fmaxf(acc[r], 0.f), w3r[c2t][r], tot);
    }
    tot += __shfl_xor(tot, 16);
    tot += __shfl_xor(tot, 32);
    if (lg == 0)
      sim[il * 65 + jb + lm] = tot + b3v;
  }

  // --- QK pass: fragments straight from global (L2), packed conversion ---
  {
    bf16x8 aq[2], bk[2];
    const float* qb = qT + ((size_t)bh * NPX + i0 + lm) * 64;
    const float* kb = kh + ((size_t)(bh * 64 + jb + lm)) * 64;
#pragma unroll
    for (int s = 0; s < 2; ++s) {
      float4 q0 = *(const float4*)(qb + s * 32 + lg * 8);
      float4 q1 = *(const float4*)(qb + s * 32 + lg * 8 + 4);
      float4 k0 = *(const float4*)(kb + s * 32 + lg * 8);
      float4 k1 = *(const float4*)(kb + s * 32 + lg * 8 + 4);
      u32x4 wq, wk;
      wq[0] = cvt_pk(q0.x, q0.y); wq[1] = cvt_pk(q0.z, q0.w);
      wq[2] = cvt_pk(q1.x, q1.y); wq[3] = cvt_pk(q1.z, q1.w);
      wk[0] = cvt_pk(k0.x, k0.y); wk[1] = cvt_pk(k0.z, k0.w);
      wk[2] = cvt_pk(k1.x, k1.y); wk[3] = cvt_pk(k1.z, k1.w);
      aq[s] = __builtin_bit_cast(bf16x8, wq);
      bk[s] = __builtin_bit_cast(bf16x8, wk);
    }
    f32x4 qacc = (f32x4){0.f, 0.f, 0.f, 0.f};
    qacc = __builtin_amdgcn_mfma_f32_16x16x32_bf16(aq[0], bk[0], qacc, 0, 0, 0);
    qacc = __builtin_amdgcn_mfma_f32_16x16x32_bf16(aq[1], bk[1], qacc, 0, 0, 0);
#pragma unroll
    for (int r = 0; r < 4; ++r)
      sim[(lg * 4 + r) * 65 + jb + lm] += qacc[r];
  }
  __syncthreads();

  // --- softmax: 16 threads per row of 64 ---
  {
    int r = tid >> 4, sl = tid & 15;
    float sv[4];
    float m = -1e30f;
#pragma unroll
    for (int t = 0; t < 4; ++t) {
      sv[t] = sim[r * 65 + sl + (t << 4)];
      m = fmaxf(m, sv[t]);
    }
#pragma unroll
    for (int off = 8; off > 0; off >>= 1) m = fmaxf(m, __shfl_xor(m, off, 16));
    float ssum = 0.f;
#pragma unroll
    for (int t = 0; t < 4; ++t) { sv[t] = expf(sv[t] - m); ssum += sv[t]; }
#pragma unroll
    for (int off = 8; off > 0; off >>= 1) ssum += __shfl_xor(ssum, off, 16);
    float inv = 1.f / ssum;
#pragma unroll
    for (int t = 0; t < 4; ++t) sim[r * 65 + sl + (t << 4)] = sv[t] * inv;
  }
  __syncthreads();

  // --- PV via MFMA (P bf16 x V hi/lo), direct hi/lo epilogue ---
  {
    bf16x8 ap[2];
#pragma unroll
    for (int s = 0; s < 2; ++s) {
      u32x4 wp;
#pragma unroll
      for (int p = 0; p < 4; ++p)
        wp[p] = cvt_pk(sim[lm * 65 + s * 32 + lg * 8 + p * 2],
                       sim[lm * 65 + s * 32 + lg * 8 + p * 2 + 1]);
      ap[s] = __builtin_bit_cast(bf16x8, wp);
    }
    f32x4 po = (f32x4){0.f, 0.f, 0.f, 0.f};
    po = __builtin_amdgcn_mfma_f32_16x16x32_bf16(ap[0], bvh[0], po, 0, 0, 0);
    po = __builtin_amdgcn_mfma_f32_16x16x32_bf16(ap[1], bvh[1], po, 0, 0, 0);
    po = __builtin_amdgcn_mfma_f32_16x16x32_bf16(ap[0], bvl[0], po, 0, 0, 0);
    po = __builtin_amdgcn_mfma_f32_16x16x32_bf16(ap[1], bvl[1], po, 0, 0, 0);
    const int b = bh >> 3, h = bh & 7;
    size_t base = ((size_t)(b * 1024 + i0 + lg * 4)) * 512 + h * 64 + jb + lm;
#pragma unroll
    for (int r = 0; r < 4; ++r) {
      float v = po[r];
      unsigned short hi = f2bf(v);
      aoh[base + (size_t)r * 512] = hi;
      aol[base + (size_t)r * 512] = f2bf(v - bf2f(hi));
    }
  }
}

// ---------------------------------------------------------------------------
// K5: projection as split-bf16 MFMA GEMM (unchanged)
// ---------------------------------------------------------------------------
__global__ __launch_bounds__(256) void k_proj_mfma(
    const unsigned short* __restrict__ aoh, const unsigned short* __restrict__ aol,
    const unsigned short* __restrict__ whP, const unsigned short* __restrict__ wlP,
    const float* __restrict__ ob, float* __restrict__ out) {
  const int p0 = blockIdx.x << 4;
  const int b  = p0 >> 10;
  const int pb = p0 & 1023;
  const int w  = threadIdx.x >> 6;
  const int l  = threadIdx.x & 63;
  const int lm = l & 15, lg = l >> 4;

  f32x4 acc[4];
#pragma unroll
  for (int nt = 0; nt < 4; ++nt) acc[nt] = (f32x4){0.f, 0.f, 0.f, 0.f};

  const unsigned short* arh = aoh + ((size_t)(p0 + lm)) * 512 + lg * 8;
  const unsigned short* arl = aol + ((size_t)(p0 + lm)) * 512 + lg * 8;
  const int ob0 = w * 64;

#pragma unroll 4
  for (int kt = 0; kt < 16; ++kt) {
    bf16x8 ah = *(const bf16x8*)(arh + kt * 32);
    bf16x8 al = *(const bf16x8*)(arl + kt * 32);
    const size_t wb = ((size_t)(kt * 4 + lg) * 256 + ob0 + lm) * 8;
#pragma unroll
    for (int nt = 0; nt < 4; ++nt) {
      bf16x8 bhf = *(const bf16x8*)(whP + wb + nt * 128);
      bf16x8 blf = *(const bf16x8*)(wlP + wb + nt * 128);
      acc[nt] = __builtin_amdgcn_mfma_f32_16x16x32_bf16(ah, bhf, acc[nt], 0, 0, 0);
      acc[nt] = __builtin_amdgcn_mfma_f32_16x16x32_bf16(ah, blf, acc[nt], 0, 0, 0);
      acc[nt] = __builtin_amdgcn_mfma_f32_16x16x32_bf16(al, bhf, acc[nt], 0, 0, 0);
    }
  }
#pragma unroll
  for (int nt = 0; nt < 4; ++nt) {
    int o = ob0 + nt * 16 + lm;
    float bias = ob[o];
    float4 v;
    v.x = acc[nt][0] + bias;
    v.y = acc[nt][1] + bias;
    v.z = acc[nt][2] + bias;
    v.w = acc[nt][3] + bias;
    *(float4*)(out + ((size_t)(b * 256 + o)) * NPX + pb + lg * 4) = v;
  }
}

// ---------------------------------------------------------------------------
extern "C" void kernel_launch(void* const* d_in, const int* in_sizes, int n_in,
                              void* d_out, int out_size, void* d_ws, size_t ws_size,
                              hipStream_t stream) {
  const float* x      = (const float*)d_in[0];
  const float* q_w    = (const float*)d_in[1];
  const float* k_w    = (const float*)d_in[2];
  const float* v_w    = (const float*)d_in[3];
  const float* out_w  = (const float*)d_in[4];
  const float* out_b  = (const float*)d_in[5];
  const float* off_w1 = (const float*)d_in[6];
  const float* off_b1 = (const float*)d_in[7];
  const float* off_w2 = (const float*)d_in[8];
  const float* cpb_w1 = (const float*)d_in[9];
  const float* cpb_b1 = (const float*)d_in[10];
  const float* cpb_w2 = (const float*)d_in[11];
  const float* cpb_b2 = (const float*)d_in[12];
  const float* cpb_w3 = (const float*)d_in[13];
  const float* cpb_b3 = (const float*)d_in[14];
  float* out = (float*)d_out;

  float* ws  = (float*)d_ws;
  float* q   = ws;                          // 1048576 f; reused as aoh/aol
  unsigned short* aoh = (unsigned short*)q; // 2048*512 shorts
  unsigned short* aol = aoh + 2048 * 512;   // 2048*512 shorts
  float* qT  = ws + 1048576;                // 1048576 f
  float* kh  = qT + 1048576;                // 65536 f
  float* gkv = kh + 65536;                  // 2048 f
  unsigned short* whP = (unsigned short*)(gkv + 2048);  // 131072 shorts
  unsigned short* wlP = whP + 131072;                   // 131072 shorts
  unsigned short* w2P = wlP + 131072;                   // 4096 shorts
  unsigned short* vPh = w2P + 4096;                     // 65536 shorts
  unsigned short* vPl = vPh + 65536;                    // 65536 shorts

  k_prep_w<<<513, 256, 0, stream>>>(out_w, cpb_w2, whP, wlP, w2P);
  k_qconv<<<256, 256, 0, stream>>>(x, q_w, q, qT);
  k_offset_sample<<<dim3(4, 16), 256, 0, stream>>>(q, off_w1, off_b1, off_w2,
                                                   x, k_w, v_w, gkv, kh, vPh, vPl);
  k_attn<<<dim3(64, 16), 256, 0, stream>>>(qT, kh, vPh, vPl, gkv, cpb_w1, cpb_b1,
                                           w2P, cpb_b2, cpb_w3, cpb_b3,
                                           aoh, aol);
  k_proj_mfma<<<128, 256, 0, stream>>>(aoh, aol, whP, wlP, out_b, out);
}

// Round 12
// 74.150 us; speedup vs baseline: 10.6307x; 1.0801x over previous
//
#include <hip/hip_runtime.h>
#include <math.h>

#define NPX 1024  // H*W = 32*32

using bf16x8 = __attribute__((ext_vector_type(8))) short;  // 8 bf16 in 4 VGPRs
using f32x4  = __attribute__((ext_vector_type(4))) float;
using u32x4  = __attribute__((ext_vector_type(4))) unsigned;

__device__ __forceinline__ float fast_slog1p(float p) {
  // ln(1+|p|) via v_log_f32; 1+|p| in [1,~3] so no catastrophic cancellation
  return copysignf(__logf(1.f + fabsf(p)), p);
}

__device__ __forceinline__ unsigned short f2bf(float f) {
  unsigned u = __builtin_bit_cast(unsigned, f);
  unsigned r = (u + 0x7FFFu + ((u >> 16) & 1u)) >> 16;  // RNE
  return (unsigned short)r;
}
__device__ __forceinline__ float bf2f(unsigned short h) {
  return __builtin_bit_cast(float, (unsigned)h << 16);
}
// HW packed conversion: low16 = bf16(lo), high16 = bf16(hi)
__device__ __forceinline__ unsigned cvt_pk(float lo, float hi) {
  unsigned r;
  asm("v_cvt_pk_bf16_f32 %0, %1, %2" : "=v"(r) : "v"(lo), "v"(hi));
  return r;
}

// ---------------------------------------------------------------------------
// K0: pack out_w into MFMA-fragment-major bf16 hi/lo (blocks 0..511) and
// cpb_w2 into fragment-major bf16 (block 512).
// ---------------------------------------------------------------------------
__global__ __launch_bounds__(256) void k_prep_w(const float* __restrict__ ow,
                                                const float* __restrict__ w2g,
                                                unsigned short* __restrict__ whP,
                                                unsigned short* __restrict__ wlP,
                                                unsigned short* __restrict__ w2P) {
  if (blockIdx.x < 512) {
    int idx = blockIdx.x * 256 + threadIdx.x;  // 0..131071
    int o = idx >> 9, c = idx & 511;
    float v = ow[(size_t)o * 512 + c];
    unsigned short hi = f2bf(v);
    unsigned short lo = f2bf(v - bf2f(hi));
    int kt = c >> 5, lg = (c >> 3) & 3, r = c & 7;
    size_t dst = ((size_t)(kt * 4 + lg) * 256 + o) * 8 + r;
    whP[dst] = hi;
    wlP[dst] = lo;
  } else {
    for (int e = threadIdx.x; e < 4096; e += 256) {
      int r = e & 7;
      int f = (e >> 3) & 7;        // c2t*2+s
      int c2t = f >> 1, s = f & 1;
      int lane = e >> 6;           // lg*16+lm
      int lm = lane & 15, lg = lane >> 4;
      int c2 = c2t * 16 + lm, c = s * 32 + lg * 8 + r;
      w2P[e] = f2bf(w2g[c2 * 64 + c]);
    }
  }
}

// ---------------------------------------------------------------------------
// K1: grouped 1x1 conv  q = x * q_w ; also qT = q*0.125 in (bh,i,d) layout
// ---------------------------------------------------------------------------
__global__ __launch_bounds__(256) void k_qconv(const float* __restrict__ x,
                                               const float* __restrict__ qw,
                                               float* __restrict__ q,
                                               float* __restrict__ qT) {
  const int blk = blockIdx.x;
  const int bg  = blk >> 4;
  const int px0 = (blk & 15) << 6;
  const int g   = bg & 7;
  const int b   = bg >> 3;
  const int tid = threadIdx.x;
  __shared__ float xs[32 * 64];
  __shared__ float wsh[64 * 32];
  __shared__ float ot[64 * 65];

  const float* xb = x + ((size_t)(b * 256 + g * 32)) * NPX + px0;
  for (int idx = tid; idx < 32 * 64; idx += 256) {
    int c = idx >> 6, p = idx & 63;
    xs[idx] = xb[(size_t)c * NPX + p];
  }
  const float* wb = qw + g * 64 * 32;
  for (int idx = tid; idx < 64 * 32; idx += 256) wsh[idx] = wb[idx];
  __syncthreads();

  for (int idx = tid; idx < 64 * 64; idx += 256) {
    int o = idx >> 6, p = idx & 63;
    float a0 = 0.f, a1 = 0.f;
#pragma unroll
    for (int c = 0; c < 32; c += 2) {
      a0 = fmaf(wsh[o * 32 + c],     xs[c * 64 + p],       a0);
      a1 = fmaf(wsh[o * 32 + c + 1], xs[(c + 1) * 64 + p], a1);
    }
    float acc = a0 + a1;
    q[((size_t)(bg * 64 + o)) * NPX + px0 + p] = acc;
    ot[o * 65 + p] = acc * 0.125f;
  }
  __syncthreads();
  float* qTb = qT + ((size_t)bg * NPX + px0) * 64;
  for (int idx = tid; idx < 64 * 64; idx += 256) {
    int p = idx >> 6, o = idx & 63;
    qTb[p * 64 + o] = ot[o * 65 + p];
  }
}

// ---------------------------------------------------------------------------
// K2+K3: offset net + grid_sample + k/v convs, partitioned over px.
// grid: (8 px-chunks of 8, 16 bg), 256 thr. Emits V pre-packed (vPh/vPl).
// ---------------------------------------------------------------------------
__global__ __launch_bounds__(256) void k_offset_sample(
    const float* __restrict__ q, const float* __restrict__ w1,
    const float* __restrict__ b1, const float* __restrict__ w2,
    const float* __restrict__ x, const float* __restrict__ kw,
    const float* __restrict__ vw, float* __restrict__ gkv,
    float* __restrict__ kh,
    unsigned short* __restrict__ vPh, unsigned short* __restrict__ vPl) {
  const int px0 = blockIdx.x << 3;   // 0,8,...,56
  const int bg  = blockIdx.y;
  const int g   = bg & 7;
  const int tid = threadIdx.x;
  __shared__ float ge[64 * 9];       // [c][lp] gelu outs, padded
  __shared__ float w1s[64 * 36];
  __shared__ float b1s[64];
  __shared__ float kws[64 * 33];
  __shared__ float vws[64 * 33];
  __shared__ float smp[32 * 9];      // [c][lj] sampled, padded
  __shared__ float xs_[8], ys_[8];

  for (int idx = tid; idx < 64 * 36; idx += 256) w1s[idx] = w1[idx];
  if (tid < 64) b1s[tid] = b1[tid];
  for (int idx = tid; idx < 2048; idx += 256) {
    int o = idx >> 5, c = idx & 31;
    kws[o * 33 + c] = kw[(g * 64 + o) * 32 + c];
    vws[o * 33 + c] = vw[(g * 64 + o) * 32 + c];
  }
  __syncthreads();

  // depthwise 6x6 s4 + bias + exact GELU: 64 c x 8 px, 2 per thread
  const float* qb = q + (size_t)bg * 64 * NPX;
  for (int idx = tid; idx < 512; idx += 256) {
    int c = idx >> 3, lp = idx & 7;
    int px = px0 + lp;
    int oy = px >> 3, ox = px & 7;
    const float* qc = qb + (size_t)c * NPX;
    float acc = 0.f;
#pragma unroll
    for (int ky = 0; ky < 6; ++ky) {
      int yy = oy * 4 - 1 + ky;
      if (yy < 0 || yy >= 32) continue;
#pragma unroll
      for (int kx = 0; kx < 6; ++kx) {
        int xx = ox * 4 - 1 + kx;
        if (xx < 0 || xx >= 32) continue;
        acc = fmaf(w1s[c * 36 + ky * 6 + kx], qc[yy * 32 + xx], acc);
      }
    }
    acc += b1s[c];
    ge[c * 9 + lp] = 0.5f * acc * (1.f + erff(acc * 0.70710678118654752440f));
  }
  __syncthreads();

  // 1x1 (64->2): 32 lanes per px, 2 channels each, shfl-reduce width 32
  {
    int lp = tid >> 5, sl = tid & 31;
    float s0 = 0.f, s1 = 0.f;
#pragma unroll
    for (int k = 0; k < 2; ++k) {
      int c = sl + k * 32;
      float gv = ge[c * 9 + lp];
      s0 = fmaf(w2[c],      gv, s0);
      s1 = fmaf(w2[64 + c], gv, s1);
    }
#pragma unroll
    for (int off = 16; off > 0; off >>= 1) {
      s0 += __shfl_xor(s0, off, 32);
      s1 += __shfl_xor(s1, off, 32);
    }
    if (sl == 0) {
      float o0 = tanhf(s0) * 4.f;
      float o1 = tanhf(s1) * 4.f;
      int px = px0 + lp;
      int oy = px >> 3, ox = px & 7;
      float g0 = 2.f * ((float)ox + o0) / 7.f - 1.f;
      float g1 = 2.f * ((float)oy + o1) / 7.f - 1.f;
      gkv[(bg * 64 + px) * 2 + 0] = g0;
      gkv[(bg * 64 + px) * 2 + 1] = g1;
      xs_[lp] = (g0 + 1.f) * 16.f - 0.5f;
      ys_[lp] = (g1 + 1.f) * 16.f - 0.5f;
    }
  }
  __syncthreads();

  // bilinear sample: 32 c x 8 j, 1 per thread
  const float* imgb = x + (size_t)bg * 32 * NPX;
  for (int idx = tid; idx < 256; idx += 256) {
    int c = idx >> 3, lj = idx & 7;
    float xx = xs_[lj], yy = ys_[lj];
    float x0f = floorf(xx), y0f = floorf(yy);
    int x0 = (int)x0f, y0 = (int)y0f;
    float wx1 = xx - x0f, wy1 = yy - y0f;
    float wx0 = 1.f - wx1, wy0 = 1.f - wy1;
    int x1 = x0 + 1, y1 = y0 + 1;
    bool vx0 = (x0 >= 0) & (x0 < 32), vx1 = (x1 >= 0) & (x1 < 32);
    bool vy0 = (y0 >= 0) & (y0 < 32), vy1 = (y1 >= 0) & (y1 < 32);
    int cx0 = min(max(x0, 0), 31), cx1 = min(max(x1, 0), 31);
    int cy0 = min(max(y0, 0), 31), cy1 = min(max(y1, 0), 31);
    const float* img = imgb + (size_t)c * NPX;
    float v00 = (vy0 && vx0) ? img[cy0 * 32 + cx0] : 0.f;
    float v01 = (vy0 && vx1) ? img[cy0 * 32 + cx1] : 0.f;
    float v10 = (vy1 && vx0) ? img[cy1 * 32 + cx0] : 0.f;
    float v11 = (vy1 && vx1) ? img[cy1 * 32 + cx1] : 0.f;
    smp[c * 9 + lj] = v00 * wy0 * wx0 + v01 * wy0 * wx1 +
                      v10 * wy1 * wx0 + v11 * wy1 * wx1;
  }
  __syncthreads();

  // k/v 1x1 convs: 8 j x 64 o, 2 per thread
  for (int idx = tid; idx < 512; idx += 256) {
    int lj = idx >> 6, o = idx & 63;
    int j = px0 + lj;
    float ak0 = 0.f, ak1 = 0.f, av0 = 0.f, av1 = 0.f;
#pragma unroll
    for (int c = 0; c < 32; c += 2) {
      float s0 = smp[c * 9 + lj], s1 = smp[(c + 1) * 9 + lj];
      ak0 = fmaf(kws[o * 33 + c],     s0, ak0);
      ak1 = fmaf(kws[o * 33 + c + 1], s1, ak1);
      av0 = fmaf(vws[o * 33 + c],     s0, av0);
      av1 = fmaf(vws[o * 33 + c + 1], s1, av1);
    }
    kh[((size_t)bg * 64 + j) * 64 + o] = ak0 + ak1;
    // V -> bf16 hi/lo in MFMA B-fragment layout:
    float av = av0 + av1;
    unsigned short hi = f2bf(av);
    unsigned short lo = f2bf(av - bf2f(hi));
    int s  = (j >> 5) & 1, lgj = (j >> 3) & 3, r = j & 7;
    int nb = o >> 4, lmo = o & 15;
    size_t dst = (((size_t)(bg * 4 + nb) * 64) + lgj * 16 + lmo) * 16 + s * 8 + r;
    vPh[dst] = hi;
    vPl[dst] = lo;
  }
}

// ---------------------------------------------------------------------------
// K4: fused CPB-MLP + QK^T + softmax + PV, all MFMA; il loop unrolled 2x for
// cross-iteration ILP (iterations independent).
// grid: (64 tiles, 16 bh), 256 thr = 4 waves; wave w owns j-cols [16w,16w+16)
// ---------------------------------------------------------------------------
__global__ __launch_bounds__(256) void k_attn(
    const float* __restrict__ qT, const float* __restrict__ kh,
    const unsigned short* __restrict__ vPh, const unsigned short* __restrict__ vPl,
    const float* __restrict__ gkv,
    const float* __restrict__ w1, const float* __restrict__ b1,
    const unsigned short* __restrict__ w2P, const float* __restrict__ b2,
    const float* __restrict__ w3, const float* __restrict__ b3,
    unsigned short* __restrict__ aoh, unsigned short* __restrict__ aol) {
  const int it  = blockIdx.x;     // 0..63
  const int bh  = blockIdx.y;     // 0..15
  const int i0  = it << 4;
  const int iy  = i0 >> 5;
  const int ixb = i0 & 31;
  const int tid = threadIdx.x;

  __shared__ float utab[16 * 65];
  __shared__ float vtab[64];
  __shared__ float w1xs[64], w1ys[64], b1s[64], b2s[64], w3s[64];
  __shared__ float sim[16 * 65];

  const int w  = tid >> 6;   // wave 0..3
  const int l  = tid & 63;
  const int lm = l & 15;
  const int lg = l >> 4;
  const int jb = w * 16;

  // --- W2 fragments (A-layout: lane holds W2[c2t*16+lm][s*32+lg*8+r]) ---
  bf16x8 bw2[4][2];
  {
    const unsigned short* wp = w2P + (lg * 16 + lm) * 64;
#pragma unroll
    for (int c2t = 0; c2t < 4; ++c2t)
#pragma unroll
      for (int s = 0; s < 2; ++s)
        bw2[c2t][s] = *(const bf16x8*)(wp + (c2t * 2 + s) * 8);
  }
  // --- V B-fragments: 4 coalesced 16B loads from packed global ---
  bf16x8 bvh[2], bvl[2];
  {
    const size_t vbase = (((size_t)(bh * 4 + w) * 64) + l) * 16;
#pragma unroll
    for (int s = 0; s < 2; ++s) {
      bvh[s] = *(const bf16x8*)(vPh + vbase + s * 8);
      bvl[s] = *(const bf16x8*)(vPl + vbase + s * 8);
    }
  }

  // --- stage utab/vtab/params (fast log) ---
  for (int idx = tid; idx < 1024; idx += 256) {
    int il = idx >> 6, j = idx & 63;
    float kxv = gkv[(bh * 64 + j) * 2];
    float qxn = (2.f / 31.f) * (float)(ixb + il) - 1.f;
    utab[il * 65 + j] = fast_slog1p(qxn - kxv);
  }
  if (tid < 64) {
    w1xs[tid] = w1[tid * 2];
    w1ys[tid] = w1[tid * 2 + 1];
    b1s[tid]  = b1[tid];
    b2s[tid]  = b2[tid];
    w3s[tid]  = w3[tid];
    float kyv = gkv[(bh * 64 + tid) * 2 + 1];
    float qyn = (2.f / 31.f) * (float)iy - 1.f;
    vtab[tid] = fast_slog1p(qyn - kyv);
  }
  __syncthreads();

  // --- hoisted il-invariant layer-1 terms ---
  float w1v[16], tc[16];
  {
    float vvj = vtab[jb + lm];
#pragma unroll
    for (int s = 0; s < 2; ++s)
#pragma unroll
      for (int r = 0; r < 8; ++r) {
        int c = s * 32 + lg * 8 + r;
        w1v[s * 8 + r] = w1xs[c];
        tc[s * 8 + r]  = fmaf(w1ys[c], vvj, b1s[c]);
      }
  }
  // per-lane layer-3 constants for swapped layout: c2 = c2t*16 + lg*4 + r
  float b2r[4][4], w3r[4][4];
#pragma unroll
  for (int c2t = 0; c2t < 4; ++c2t)
#pragma unroll
    for (int r = 0; r < 4; ++r) {
      int c2 = c2t * 16 + lg * 4 + r;
      b2r[c2t][r] = b2s[c2];
      w3r[c2t][r] = w3s[c2];
    }
  const float b3v = b3[0];

  // --- CPB pass: swapped operands; lane lm = point j-within-16; unroll 2 ---
#pragma unroll 2
  for (int il = 0; il < 16; ++il) {
    float u = utab[il * 65 + jb + lm];
    float h[16];
#pragma unroll
    for (int e = 0; e < 16; ++e)
      h[e] = fmaxf(fmaf(w1v[e], u, tc[e]), 0.f);
    bf16x8 hf[2];   // B-fragment: col=point=lm, k=c
#pragma unroll
    for (int s = 0; s < 2; ++s) {
      u32x4 wds;
#pragma unroll
      for (int p = 0; p < 4; ++p)
        wds[p] = cvt_pk(h[s * 8 + p * 2], h[s * 8 + p * 2 + 1]);
      hf[s] = __builtin_bit_cast(bf16x8, wds);
    }
    // D[m=c2][n=point]: lane holds point=lm, c2 = c2t*16 + lg*4 + r
    float tot = 0.f;
#pragma unroll
    for (int c2t = 0; c2t < 4; ++c2t) {
      f32x4 acc = (f32x4){b2r[c2t][0], b2r[c2t][1], b2r[c2t][2], b2r[c2t][3]};
      acc = __builtin_amdgcn_mfma_f32_16x16x32_bf16(bw2[c2t][0], hf[0], acc, 0, 0, 0);
      acc = __builtin_amdgcn_mfma_f32_16x16x32_bf16(bw2[c2t][1], hf[1], acc, 0, 0, 0);
#pragma unroll
      for (int r = 0; r < 4; ++r)
        tot = fmaf(fmaxf(acc[r], 0.f), w3r[c2t][r], tot);
    }
    tot += __shfl_xor(tot, 16);
    tot += __shfl_xor(tot, 32);
    if (lg == 0)
      sim[il * 65 + jb + lm] = tot + b3v;
  }

  // --- QK pass: fragments straight from global (L2), packed conversion ---
  {
    bf16x8 aq[2], bk[2];
    const float* qb = qT + ((size_t)bh * NPX + i0 + lm) * 64;
    const float* kb = kh + ((size_t)(bh * 64 + jb + lm)) * 64;
#pragma unroll
    for (int s = 0; s < 2; ++s) {
      float4 q0 = *(const float4*)(qb + s * 32 + lg * 8);
      float4 q1 = *(const float4*)(qb + s * 32 + lg * 8 + 4);
      float4 k0 = *(const float4*)(kb + s * 32 + lg * 8);
      float4 k1 = *(const float4*)(kb + s * 32 + lg * 8 + 4);
      u32x4 wq, wk;
      wq[0] = cvt_pk(q0.x, q0.y); wq[1] = cvt_pk(q0.z, q0.w);
      wq[2] = cvt_pk(q1.x, q1.y); wq[3] = cvt_pk(q1.z, q1.w);
      wk[0] = cvt_pk(k0.x, k0.y); wk[1] = cvt_pk(k0.z, k0.w);
      wk[2] = cvt_pk(k1.x, k1.y); wk[3] = cvt_pk(k1.z, k1.w);
      aq[s] = __builtin_bit_cast(bf16x8, wq);
      bk[s] = __builtin_bit_cast(bf16x8, wk);
    }
    f32x4 qacc = (f32x4){0.f, 0.f, 0.f, 0.f};
    qacc = __builtin_amdgcn_mfma_f32_16x16x32_bf16(aq[0], bk[0], qacc, 0, 0, 0);
    qacc = __builtin_amdgcn_mfma_f32_16x16x32_bf16(aq[1], bk[1], qacc, 0, 0, 0);
#pragma unroll
    for (int r = 0; r < 4; ++r)
      sim[(lg * 4 + r) * 65 + jb + lm] += qacc[r];
  }
  __syncthreads();

  // --- softmax: 16 threads per row of 64 ---
  {
    int r = tid >> 4, sl = tid & 15;
    float sv[4];
    float m = -1e30f;
#pragma unroll
    for (int t = 0; t < 4; ++t) {
      sv[t] = sim[r * 65 + sl + (t << 4)];
      m = fmaxf(m, sv[t]);
    }
#pragma unroll
    for (int off = 8; off > 0; off >>= 1) m = fmaxf(m, __shfl_xor(m, off, 16));
    float ssum = 0.f;
#pragma unroll
    for (int t = 0; t < 4; ++t) { sv[t] = expf(sv[t] - m); ssum += sv[t]; }
#pragma unroll
    for (int off = 8; off > 0; off >>= 1) ssum += __shfl_xor(ssum, off, 16);
    float inv = 1.f / ssum;
#pragma unroll
    for (int t = 0; t < 4; ++t) sim[r * 65 + sl + (t << 4)] = sv[t] * inv;
  }
  __syncthreads();

  // --- PV via MFMA (P bf16 x V hi/lo), direct hi/lo epilogue ---
  {
    bf16x8 ap[2];
#pragma unroll
    for (int s = 0; s < 2; ++s) {
      u32x4 wp;
#pragma unroll
      for (int p = 0; p < 4; ++p)
        wp[p] = cvt_pk(sim[lm * 65 + s * 32 + lg * 8 + p * 2],
                       sim[lm * 65 + s * 32 + lg * 8 + p * 2 + 1]);
      ap[s] = __builtin_bit_cast(bf16x8, wp);
    }
    f32x4 po = (f32x4){0.f, 0.f, 0.f, 0.f};
    po = __builtin_amdgcn_mfma_f32_16x16x32_bf16(ap[0], bvh[0], po, 0, 0, 0);
    po = __builtin_amdgcn_mfma_f32_16x16x32_bf16(ap[1], bvh[1], po, 0, 0, 0);
    po = __builtin_amdgcn_mfma_f32_16x16x32_bf16(ap[0], bvl[0], po, 0, 0, 0);
    po = __builtin_amdgcn_mfma_f32_16x16x32_bf16(ap[1], bvl[1], po, 0, 0, 0);
    const int b = bh >> 3, h = bh & 7;
    size_t base = ((size_t)(b * 1024 + i0 + lg * 4)) * 512 + h * 64 + jb + lm;
#pragma unroll
    for (int r = 0; r < 4; ++r) {
      float v = po[r];
      unsigned short hi = f2bf(v);
      aoh[base + (size_t)r * 512] = hi;
      aol[base + (size_t)r * 512] = f2bf(v - bf2f(hi));
    }
  }
}

// ---------------------------------------------------------------------------
// K5: projection as split-bf16 MFMA GEMM (unchanged)
// ---------------------------------------------------------------------------
__global__ __launch_bounds__(256) void k_proj_mfma(
    const unsigned short* __restrict__ aoh, const unsigned short* __restrict__ aol,
    const unsigned short* __restrict__ whP, const unsigned short* __restrict__ wlP,
    const float* __restrict__ ob, float* __restrict__ out) {
  const int p0 = blockIdx.x << 4;
  const int b  = p0 >> 10;
  const int pb = p0 & 1023;
  const int w  = threadIdx.x >> 6;
  const int l  = threadIdx.x & 63;
  const int lm = l & 15, lg = l >> 4;

  f32x4 acc[4];
#pragma unroll
  for (int nt = 0; nt < 4; ++nt) acc[nt] = (f32x4){0.f, 0.f, 0.f, 0.f};

  const unsigned short* arh = aoh + ((size_t)(p0 + lm)) * 512 + lg * 8;
  const unsigned short* arl = aol + ((size_t)(p0 + lm)) * 512 + lg * 8;
  const int ob0 = w * 64;

#pragma unroll 4
  for (int kt = 0; kt < 16; ++kt) {
    bf16x8 ah = *(const bf16x8*)(arh + kt * 32);
    bf16x8 al = *(const bf16x8*)(arl + kt * 32);
    const size_t wb = ((size_t)(kt * 4 + lg) * 256 + ob0 + lm) * 8;
#pragma unroll
    for (int nt = 0; nt < 4; ++nt) {
      bf16x8 bhf = *(const bf16x8*)(whP + wb + nt * 128);
      bf16x8 blf = *(const bf16x8*)(wlP + wb + nt * 128);
      acc[nt] = __builtin_amdgcn_mfma_f32_16x16x32_bf16(ah, bhf, acc[nt], 0, 0, 0);
      acc[nt] = __builtin_amdgcn_mfma_f32_16x16x32_bf16(ah, blf, acc[nt], 0, 0, 0);
      acc[nt] = __builtin_amdgcn_mfma_f32_16x16x32_bf16(al, bhf, acc[nt], 0, 0, 0);
    }
  }
#pragma unroll
  for (int nt = 0; nt < 4; ++nt) {
    int o = ob0 + nt * 16 + lm;
    float bias = ob[o];
    float4 v;
    v.x = acc[nt][0] + bias;
    v.y = acc[nt][1] + bias;
    v.z = acc[nt][2] + bias;
    v.w = acc[nt][3] + bias;
    *(float4*)(out + ((size_t)(b * 256 + o)) * NPX + pb + lg * 4) = v;
  }
}

// ---------------------------------------------------------------------------
extern "C" void kernel_launch(void* const* d_in, const int* in_sizes, int n_in,
                              void* d_out, int out_size, void* d_ws, size_t ws_size,
                              hipStream_t stream) {
  const float* x      = (const float*)d_in[0];
  const float* q_w    = (const float*)d_in[1];
  const float* k_w    = (const float*)d_in[2];
  const float* v_w    = (const float*)d_in[3];
  const float* out_w  = (const float*)d_in[4];
  const float* out_b  = (const float*)d_in[5];
  const float* off_w1 = (const float*)d_in[6];
  const float* off_b1 = (const float*)d_in[7];
  const float* off_w2 = (const float*)d_in[8];
  const float* cpb_w1 = (const float*)d_in[9];
  const float* cpb_b1 = (const float*)d_in[10];
  const float* cpb_w2 = (const float*)d_in[11];
  const float* cpb_b2 = (const float*)d_in[12];
  const float* cpb_w3 = (const float*)d_in[13];
  const float* cpb_b3 = (const float*)d_in[14];
  float* out = (float*)d_out;

  float* ws  = (float*)d_ws;
  float* q   = ws;                          // 1048576 f; reused as aoh/aol
  unsigned short* aoh = (unsigned short*)q; // 2048*512 shorts
  unsigned short* aol = aoh + 2048 * 512;   // 2048*512 shorts
  float* qT  = ws + 1048576;                // 1048576 f
  float* kh  = qT + 1048576;                // 65536 f
  float* gkv = kh + 65536;                  // 2048 f
  unsigned short* whP = (unsigned short*)(gkv + 2048);  // 131072 shorts
  unsigned short* wlP = whP + 131072;                   // 131072 shorts
  unsigned short* w2P = wlP + 131072;                   // 4096 shorts
  unsigned short* vPh = w2P + 4096;                     // 65536 shorts
  unsigned short* vPl = vPh + 65536;                    // 65536 shorts

  k_prep_w<<<513, 256, 0, stream>>>(out_w, cpb_w2, whP, wlP, w2P);
  k_qconv<<<256, 256, 0, stream>>>(x, q_w, q, qT);
  k_offset_sample<<<dim3(8, 16), 256, 0, stream>>>(q, off_w1, off_b1, off_w2,
                                                   x, k_w, v_w, gkv, kh, vPh, vPl);
  k_attn<<<dim3(64, 16), 256, 0, stream>>>(qT, kh, vPh, vPl, gkv, cpb_w1, cpb_b1,
                                           w2P, cpb_b2, cpb_w3, cpb_b3,
                                           aoh, aol);
  k_proj_mfma<<<128, 256, 0, stream>>>(aoh, aol, whP, wlP, out_b, out);
}